// Round 4
// baseline (1381.608 us; speedup 1.0000x reference)
//
#include <hip/hip_runtime.h>
#include <cmath>

#define NSN 50000
#define NTN 50000
#define EE  500000
#define NBE ((size_t)NSN * 128)

using short8 = __attribute__((ext_vector_type(8))) short;
using f32x4  = __attribute__((ext_vector_type(4))) float;
#define MFMA16(a, b, c) __builtin_amdgcn_mfma_f32_16x16x32_bf16(a, b, c, 0, 0, 0)

__device__ __forceinline__ float  b2f(ushort u) { return __uint_as_float(((uint)u) << 16); }
__device__ __forceinline__ ushort f2b(float f) {
  uint x = __float_as_uint(f);
  uint r = x + 0x7FFFu + ((x >> 16) & 1u);
  return (ushort)(r >> 16);
}
__device__ __forceinline__ float blo(uint x) { return __uint_as_float(x << 16); }
__device__ __forceinline__ float bhi(uint x) { return __uint_as_float(x & 0xFFFF0000u); }
__device__ __forceinline__ uint  pk2(float a, float b) { return (uint)f2b(a) | ((uint)f2b(b) << 16); }

// ------------------------------------------------- all input/weight converts
__global__ void cvtall_k(const float* __restrict__ xs, const float* __restrict__ xt,
                         const float* __restrict__ wl,
                         const float* __restrict__ esw1, const float* __restrict__ esw2,
                         const float* __restrict__ etw1, const float* __restrict__ etw2,
                         ushort* __restrict__ xsB, ushort* __restrict__ xtB,
                         ushort* __restrict__ wlB, ushort* __restrict__ esw1B,
                         ushort* __restrict__ esw2B, ushort* __restrict__ etw1B,
                         ushort* __restrict__ etw2B) {
  int i = blockIdx.x * 256 + threadIdx.x;
  if (i < 3200000) { xsB[i] = f2b(xs[i]); return; }
  i -= 3200000;
  if (i < 3200000) {
    int r = i >> 6, k = i & 63;
    xtB[i] = (k < 48) ? f2b(xt[(size_t)r * 48 + k]) : (ushort)0;
    return;
  }
  i -= 3200000;
  if (i < 196608) { wlB[i] = f2b(wl[i]); return; }
  i -= 196608;
  if (i < 8192) { esw1B[i] = f2b(esw1[i]); return; }
  i -= 8192;
  if (i < 16384) { esw2B[i] = f2b(esw2[i]); return; }
  i -= 16384;
  if (i < 8192) {
    int r = i >> 6, k = i & 63;
    etw1B[i] = (k < 48) ? f2b(etw1[(size_t)r * 48 + k]) : (ushort)0;
    return;
  }
  i -= 8192;
  if (i < 16384) { etw2B[i] = f2b(etw2[i]); return; }
}

// ------------------------------------------------- combined wr + bias
__global__ void wrc_k(const float* __restrict__ wr, const float* __restrict__ bl,
                      ushort* __restrict__ wrcB, float* __restrict__ blc) {
  int z = blockIdx.y;
  int l = z >> 1, dd = z & 1;
  int r1 = dd ? 1 : 0, r2 = dd ? 2 : 3;
  int idx = blockIdx.x * 256 + threadIdx.x;
  if (idx < 16384) {
    wrcB[(size_t)z * 16384 + idx] =
        f2b(wr[(size_t)(l * 4 + r1) * 16384 + idx] + wr[(size_t)(l * 4 + r2) * 16384 + idx]);
    if (idx < 128)
      blc[z * 128 + idx] = bl[(l * 4 + r1) * 128 + idx] + bl[(l * 4 + r2) * 128 + idx];
  }
}

// ------------------------------------------------- head weight assembly
// Whead[2][256][128]: z=0 rows0-127=gw1[:,:128], z=1 rows0-127=gw1[:,128:], rows128-255=mw1[:,:128]
// biasHead[2][256]: z0=[gb1|mb1], z1=[0|mb1]
__global__ void headw_k(const float* __restrict__ gw1, const float* __restrict__ mw1,
                        const float* __restrict__ mw2, const float* __restrict__ gb1,
                        const float* __restrict__ mb1,
                        ushort* __restrict__ Whead, float* __restrict__ biasHead,
                        ushort* __restrict__ w1eB, ushort* __restrict__ w2B) {
  int idx = blockIdx.x * 256 + threadIdx.x;
  if (idx < 65536) {
    int z = idx >> 15, rr = (idx >> 7) & 255, c = idx & 127;
    float v = (rr < 128) ? gw1[(size_t)rr * 256 + z * 128 + c]
                         : mw1[(size_t)(rr - 128) * 160 + c];
    Whead[idx] = f2b(v);
  } else if (idx < 69632) {
    int i = idx - 65536;
    w1eB[i] = f2b(mw1[(size_t)(i >> 5) * 160 + 128 + (i & 31)]);
  } else if (idx < 77824) {
    int i = idx - 69632;
    w2B[i] = f2b(mw2[i]);
  } else if (idx < 78336) {
    int i = idx - 77824;
    int z = i >> 8, n = i & 255;
    biasHead[i] = (n < 128) ? (z ? 0.f : gb1[n]) : mb1[n - 128];
  }
}

// --------------------------------------------------------------- CSR build
__global__ void count4_k(const int* __restrict__ e0, const int* __restrict__ e1,
                         const int* __restrict__ e2, const int* __restrict__ e3,
                         int* __restrict__ cnt) {
  int rel = blockIdx.y;
  const int* col = (rel == 0 ? e0 : rel == 1 ? e1 : rel == 2 ? e2 : e3) + EE;
  int i = blockIdx.x * 256 + threadIdx.x;
  if (i < EE) atomicAdd(&cnt[rel * 50000 + col[i]], 1);
}
__global__ void scan_k(const int* __restrict__ cnt, int* __restrict__ off,
                       int* __restrict__ cur) {
  __shared__ int wsum[4];
  __shared__ int runS;
  int rel = blockIdx.x;
  const int* c = cnt + (size_t)rel * 50000;
  int* o = off + (size_t)rel * 50001;
  int* cu = cur + (size_t)rel * 50000;
  int t = threadIdx.x, lane = t & 63, w = t >> 6;
  if (t == 0) { runS = 0; o[0] = 0; }
  __syncthreads();
  for (int base = 0; base < 50000; base += 256) {
    int i = base + t;
    int v = (i < 50000) ? c[i] : 0;
    int x = v;
    #pragma unroll
    for (int d = 1; d < 64; d <<= 1) {
      int y = __shfl_up(x, d, 64);
      if (lane >= d) x += y;
    }
    if (lane == 63) wsum[w] = x;
    __syncthreads();
    int add = runS;
    for (int ww = 0; ww < w; ++ww) add += wsum[ww];
    int incl = add + x;
    if (i < 50000) { cu[i] = incl - v; o[i + 1] = incl; }
    __syncthreads();
    if (t == 255) runS = add + x;
    __syncthreads();
  }
}
__global__ void fill4_k(const int* __restrict__ e0, const int* __restrict__ e1,
                        const int* __restrict__ e2, const int* __restrict__ e3,
                        int* __restrict__ cur, int* __restrict__ adj) {
  int rel = blockIdx.y;
  const int* ei = rel == 0 ? e0 : rel == 1 ? e1 : rel == 2 ? e2 : e3;
  int e = blockIdx.x * 256 + threadIdx.x;
  if (e < EE) {
    int pos = atomicAdd(&cur[rel * 50000 + ei[EE + e]], 1);
    adj[(size_t)rel * EE + pos] = ei[e];
  }
}

// ------------------------------------------------------- shared GEMM body
// C[m0..m0+128][128 cols] = op(A[M][K] @ W[128][K]^T) + bias, out bf16 @ ldc
// MODE 0: acc + bias      MODE 1: relu(acc + bias)
template <int MODE>
__device__ __forceinline__ void gemm_body(
    ushort (*As)[40], ushort (*Ws)[40],
    const ushort* __restrict__ A, const ushort* __restrict__ W,
    const float* __restrict__ bias, ushort* __restrict__ C,
    int M, int K, int ldc, int m0) {
  int t = threadIdx.x;
  int lane = t & 63, w = t >> 6, wm = w >> 1, wn = w & 1;
  f32x4 zz = {0.f, 0.f, 0.f, 0.f};
  f32x4 acc[4][4];
  #pragma unroll
  for (int i = 0; i < 4; ++i)
    #pragma unroll
    for (int j = 0; j < 4; ++j) acc[i][j] = zz;
  for (int kb = 0; kb < K; kb += 32) {
    #pragma unroll
    for (int s = 0; s < 2; ++s) {
      int idx = t + s * 256;
      int r = idx >> 2, c = idx & 3;
      int gm = m0 + r;
      uint4 va = make_uint4(0, 0, 0, 0);
      if (gm < M) va = *(const uint4*)(A + (size_t)gm * K + kb + c * 8);
      *(uint4*)&As[r][c * 8] = va;
      *(uint4*)&Ws[r][c * 8] = *(const uint4*)(W + (size_t)r * K + kb + c * 8);
    }
    __syncthreads();
    short8 af[4], bf[4];
    #pragma unroll
    for (int mf = 0; mf < 4; ++mf)
      af[mf] = *(const short8*)&As[wm * 64 + mf * 16 + (lane & 15)][(lane >> 4) * 8];
    #pragma unroll
    for (int nf = 0; nf < 4; ++nf)
      bf[nf] = *(const short8*)&Ws[wn * 64 + nf * 16 + (lane & 15)][(lane >> 4) * 8];
    #pragma unroll
    for (int mf = 0; mf < 4; ++mf)
      #pragma unroll
      for (int nf = 0; nf < 4; ++nf) acc[mf][nf] = MFMA16(af[mf], bf[nf], acc[mf][nf]);
    __syncthreads();
  }
  int r0 = (lane >> 4) * 4, nin = lane & 15;
  #pragma unroll
  for (int mf = 0; mf < 4; ++mf)
    #pragma unroll
    for (int nf = 0; nf < 4; ++nf) {
      int n = wn * 64 + nf * 16 + nin;
      float bv = bias ? bias[n] : 0.f;
      #pragma unroll
      for (int i = 0; i < 4; ++i) {
        int gm = m0 + wm * 64 + mf * 16 + r0 + i;
        if (gm >= M) continue;
        float v = acc[mf][nf][i] + bv;
        if (MODE == 1) v = fmaxf(v, 0.f);
        C[(size_t)gm * ldc + n] = f2b(v);
      }
    }
}

// encoder stage (grid.y picks source/target config)
template <int MODE>
__global__ __launch_bounds__(256) void enc_k(
    const ushort* A0, const ushort* A1, const ushort* W0, const ushort* W1,
    const float* b0, const float* b1, ushort* C0, ushort* C1, int M, int K) {
  __shared__ alignas(16) ushort As[128][40];
  __shared__ alignas(16) ushort Ws[128][40];
  int y = blockIdx.y;
  gemm_body<MODE>(As, Ws, y ? A1 : A0, y ? W1 : W0, y ? b1 : b0, y ? C1 : C0,
                  M, K, 128, blockIdx.x * 128);
}

// head precompute: z = node set (S/T), ny = N-tile of 256-wide output
__global__ __launch_bounds__(256) void gemmH_k(
    const ushort* Abase, const ushort* Whead, const float* biasHead,
    ushort* pS, ushort* pT) {
  __shared__ alignas(16) ushort As[128][40];
  __shared__ alignas(16) ushort Ws[128][40];
  int z = blockIdx.z, ny = blockIdx.y;
  gemm_body<0>(As, Ws, Abase + (size_t)z * NBE,
               Whead + ((size_t)z * 256 + ny * 128) * 128,
               biasHead + z * 256 + ny * 128,
               (z ? pT : pS) + ny * 128,
               NSN, 128, 256, blockIdx.x * 128);
}

// --------------------------------------- fused layer: gather-means + 3-way GEMM
// blockIdx.y: 0 = dst source (rels ss,ts), 1 = dst target (rels tt,st)
// out = relu(0.5*(meanA@W0^T + meanB@W1^T + self@Wrc^T + bias) [+ self])
template <int RES>
__global__ __launch_bounds__(256) void layer_k(
    const ushort* __restrict__ hs, const ushort* __restrict__ ht,
    const int* __restrict__ off4, const int* __restrict__ adj4,
    const ushort* __restrict__ wlL, const ushort* __restrict__ wrcL,
    const float* __restrict__ blcL,
    ushort* __restrict__ hsOut, ushort* __restrict__ htOut, int M) {
  __shared__ alignas(16) ushort Ms[128 * 128];   // XOR-swizzled A tile (32 KB)
  __shared__ alignas(16) ushort Ws[128][40];     // W k-slice staging
  int t = threadIdx.x;
  int y = blockIdx.y;
  int m0 = blockIdx.x * 128;
  const ushort* srcA = y ? ht : hs;
  const ushort* srcB = y ? hs : ht;
  const ushort* self = y ? ht : hs;
  const int* offA = off4 + (y ? 1 : 0) * 50001;
  const int* offB = off4 + (y ? 2 : 3) * 50001;
  const int* adjA = adj4 + (size_t)(y ? 1 : 0) * EE;
  const int* adjB = adj4 + (size_t)(y ? 2 : 3) * EE;
  const ushort* W0 = wlL + (size_t)(y ? 1 : 0) * 16384;
  const ushort* W1 = wlL + (size_t)(y ? 2 : 3) * 16384;
  const ushort* W2 = wrcL + (size_t)y * 16384;
  const float* bias = blcL + y * 128;
  ushort* C = y ? htOut : hsOut;

  int lane = t & 63, w = t >> 6, wm = w >> 1, wn = w & 1;
  f32x4 zz = {0.f, 0.f, 0.f, 0.f};
  f32x4 acc[4][4];
  #pragma unroll
  for (int i = 0; i < 4; ++i)
    #pragma unroll
    for (int j = 0; j < 4; ++j) acc[i][j] = zz;

  for (int p = 0; p < 3; ++p) {
    if (p < 2) {
      // gather-mean for relation p into Ms (swizzled), 2 nodes per wave
      const ushort* src = p ? srcB : srcA;
      const int* off = p ? offB : offA;
      const int* adj = p ? adjB : adjA;
      int half = lane >> 5, l32 = lane & 31;
      for (int rr = 0; rr < 32; rr += 2) {
        int r = w * 32 + rr + half;
        int n = m0 + r;
        float a0 = 0.f, a1 = 0.f, a2 = 0.f, a3 = 0.f;
        int cnt = 0;
        if (n < M) {
          int s = off[n], e = off[n + 1];
          cnt = e - s;
          int i = s;
          for (; i + 4 <= e; i += 4) {
            int r0 = adj[i], r1 = adj[i + 1], r2 = adj[i + 2], r3 = adj[i + 3];
            ushort4 v0 = *(const ushort4*)(src + (size_t)r0 * 128 + l32 * 4);
            ushort4 v1 = *(const ushort4*)(src + (size_t)r1 * 128 + l32 * 4);
            ushort4 v2 = *(const ushort4*)(src + (size_t)r2 * 128 + l32 * 4);
            ushort4 v3 = *(const ushort4*)(src + (size_t)r3 * 128 + l32 * 4);
            a0 += b2f(v0.x) + b2f(v1.x) + b2f(v2.x) + b2f(v3.x);
            a1 += b2f(v0.y) + b2f(v1.y) + b2f(v2.y) + b2f(v3.y);
            a2 += b2f(v0.z) + b2f(v1.z) + b2f(v2.z) + b2f(v3.z);
            a3 += b2f(v0.w) + b2f(v1.w) + b2f(v2.w) + b2f(v3.w);
          }
          for (; i < e; ++i) {
            ushort4 v = *(const ushort4*)(src + (size_t)adj[i] * 128 + l32 * 4);
            a0 += b2f(v.x); a1 += b2f(v.y); a2 += b2f(v.z); a3 += b2f(v.w);
          }
        }
        float inv = 1.f / (float)max(cnt, 1);
        ushort4 o;
        o.x = f2b(a0 * inv); o.y = f2b(a1 * inv);
        o.z = f2b(a2 * inv); o.w = f2b(a3 * inv);
        *(ushort4*)&Ms[r * 128 + ((((l32 >> 1) ^ (r & 7)) << 3) | ((l32 & 1) << 2))] = o;
      }
    } else {
      // stage self rows (coalesced) into Ms, swizzled
      #pragma unroll
      for (int s2 = 0; s2 < 8; ++s2) {
        int idx = s2 * 256 + t;
        int r = idx >> 4, c8 = idx & 15;
        int gm = m0 + r;
        uint4 v = make_uint4(0, 0, 0, 0);
        if (gm < M) v = *(const uint4*)(self + (size_t)gm * 128 + c8 * 8);
        *(uint4*)&Ms[r * 128 + ((c8 ^ (r & 7)) << 3)] = v;
      }
    }
    __syncthreads();
    const ushort* Wp = p == 0 ? W0 : (p == 1 ? W1 : W2);
    for (int kb = 0; kb < 128; kb += 32) {
      #pragma unroll
      for (int s2 = 0; s2 < 2; ++s2) {
        int idx = s2 * 256 + t;
        int r = idx >> 2, c = idx & 3;
        *(uint4*)&Ws[r][c * 8] = *(const uint4*)(Wp + (size_t)r * 128 + kb + c * 8);
      }
      __syncthreads();
      short8 af[4], bf[4];
      #pragma unroll
      for (int mf = 0; mf < 4; ++mf) {
        int row = wm * 64 + mf * 16 + (lane & 15);
        af[mf] = *(const short8*)&Ms[row * 128 + ((((kb >> 3) + (lane >> 4)) ^ (row & 7)) << 3)];
      }
      #pragma unroll
      for (int nf = 0; nf < 4; ++nf)
        bf[nf] = *(const short8*)&Ws[wn * 64 + nf * 16 + (lane & 15)][(lane >> 4) * 8];
      #pragma unroll
      for (int mf = 0; mf < 4; ++mf)
        #pragma unroll
        for (int nf = 0; nf < 4; ++nf) acc[mf][nf] = MFMA16(af[mf], bf[nf], acc[mf][nf]);
      __syncthreads();
    }
  }
  // epilogue
  int r0 = (lane >> 4) * 4, nin = lane & 15;
  #pragma unroll
  for (int mf = 0; mf < 4; ++mf)
    #pragma unroll
    for (int nf = 0; nf < 4; ++nf) {
      int n = wn * 64 + nf * 16 + nin;
      float bv = bias[n];
      #pragma unroll
      for (int i = 0; i < 4; ++i) {
        int gm = m0 + wm * 64 + mf * 16 + r0 + i;
        if (gm >= M) continue;
        float v = 0.5f * (acc[mf][nf][i] + bv);
        if (RES) v += b2f(self[(size_t)gm * 128 + n]);
        C[(size_t)gm * 128 + n] = f2b(fmaxf(v, 0.f));
      }
    }
}

// ---------------------------------------------------------------- edge head
__global__ __launch_bounds__(256) void head_k(
    const ushort* __restrict__ pS, const ushort* __restrict__ pT,
    const int* __restrict__ ei, const float* __restrict__ ea,
    const ushort* __restrict__ w1eB, const ushort* __restrict__ w2B,
    const float* __restrict__ gw2, const float* __restrict__ gb2p,
    const float* __restrict__ mb2, const float* __restrict__ mw3,
    const float* __restrict__ mb3, float* __restrict__ out, int E) {
  __shared__ alignas(16) ushort eatB[64][136];   // eat (bf16); aliased by h2F after
  __shared__ alignas(16) ushort h1s[64][136];
  __shared__ int er[64], ec[64];
  __shared__ alignas(16) float gw2s[128];
  __shared__ alignas(16) float mw3s[128];
  __shared__ float mb2s[64];
  float (*h2F)[68] = (float(*)[68])&eatB[0][0];

  int t = threadIdx.x;
  int e0 = blockIdx.x * 64;
  if (t < 64) {
    int eg = e0 + t;
    er[t] = (eg < E) ? ei[eg] : 0;
    mb2s[t] = mb2[t];
  } else if (t < 128) {
    int q = t - 64;
    int eg = e0 + q;
    ec[q] = (eg < E) ? ei[E + eg] : 0;
  }
  if (t < 128) gw2s[t] = gw2[t];
  else mw3s[t - 128] = mw3[t - 128];
  __syncthreads();
  int lane = t & 63, w = t >> 6;
  // Phase E: eat = ea @ w1e^T (M=64, N=128, K=32); A-frag straight from global
  {
    int erow = e0 + w * 16 + (lane & 15);
    float4 f0 = make_float4(0, 0, 0, 0), f1 = make_float4(0, 0, 0, 0);
    if (erow < E) {
      f0 = *(const float4*)(ea + (size_t)erow * 32 + (lane >> 4) * 8);
      f1 = *(const float4*)(ea + (size_t)erow * 32 + (lane >> 4) * 8 + 4);
    }
    union { short8 s; uint4 u; } cv;
    cv.u = make_uint4(pk2(f0.x, f0.y), pk2(f0.z, f0.w), pk2(f1.x, f1.y), pk2(f1.z, f1.w));
    short8 a = cv.s;
    int ebase = w * 16 + (lane >> 4) * 4;
    #pragma unroll
    for (int nf = 0; nf < 8; ++nf) {
      short8 b = *(const short8*)(w1eB + (size_t)(nf * 16 + (lane & 15)) * 32 + (lane >> 4) * 8);
      f32x4 cz = {0.f, 0.f, 0.f, 0.f};
      cz = MFMA16(a, b, cz);
      int jj = nf * 16 + (lane & 15);
      #pragma unroll
      for (int i = 0; i < 4; ++i) eatB[ebase + i][jj] = f2b(cz[i]);
    }
  }
  __syncthreads();
  // Phase G: gate + convex combine -> h1 (bf16 LDS)
  {
    int el = lane >> 2, q = lane & 3, e = w * 16 + el;
    int j0 = q * 32;
    const ushort* ps = pS + (size_t)er[e] * 256;
    const ushort* pt = pT + (size_t)ec[e] * 256;
    float dot = 0.f;
    #pragma unroll
    for (int cc = 0; cc < 4; ++cc) {
      int j = j0 + cc * 8;
      uint4 ga = *(const uint4*)(ps + j);
      uint4 gb = *(const uint4*)(pt + j);
      const float* gp = &gw2s[j];
      float h;
      h = fmaxf(blo(ga.x) + blo(gb.x), 0.f); dot = fmaf(h, gp[0], dot);
      h = fmaxf(bhi(ga.x) + bhi(gb.x), 0.f); dot = fmaf(h, gp[1], dot);
      h = fmaxf(blo(ga.y) + blo(gb.y), 0.f); dot = fmaf(h, gp[2], dot);
      h = fmaxf(bhi(ga.y) + bhi(gb.y), 0.f); dot = fmaf(h, gp[3], dot);
      h = fmaxf(blo(ga.z) + blo(gb.z), 0.f); dot = fmaf(h, gp[4], dot);
      h = fmaxf(bhi(ga.z) + bhi(gb.z), 0.f); dot = fmaf(h, gp[5], dot);
      h = fmaxf(blo(ga.w) + blo(gb.w), 0.f); dot = fmaf(h, gp[6], dot);
      h = fmaxf(bhi(ga.w) + bhi(gb.w), 0.f); dot = fmaf(h, gp[7], dot);
    }
    dot += __shfl_xor(dot, 1, 64);
    dot += __shfl_xor(dot, 2, 64);
    float g = 1.f / (1.f + __expf(-(dot + gb2p[0])));
    float om = 1.f - g;
    #pragma unroll
    for (int cc = 0; cc < 4; ++cc) {
      int j = j0 + cc * 8;
      uint4 uu = *(const uint4*)(ps + 128 + j);
      uint4 vv = *(const uint4*)(pt + 128 + j);
      uint4 ee = *(const uint4*)&eatB[e][j];
      uint o0 = pk2(fmaxf(fmaf(g, blo(uu.x), om * blo(vv.x)) + blo(ee.x), 0.f),
                    fmaxf(fmaf(g, bhi(uu.x), om * bhi(vv.x)) + bhi(ee.x), 0.f));
      uint o1 = pk2(fmaxf(fmaf(g, blo(uu.y), om * blo(vv.y)) + blo(ee.y), 0.f),
                    fmaxf(fmaf(g, bhi(uu.y), om * bhi(vv.y)) + bhi(ee.y), 0.f));
      uint o2 = pk2(fmaxf(fmaf(g, blo(uu.z), om * blo(vv.z)) + blo(ee.z), 0.f),
                    fmaxf(fmaf(g, bhi(uu.z), om * bhi(vv.z)) + bhi(ee.z), 0.f));
      uint o3 = pk2(fmaxf(fmaf(g, blo(uu.w), om * blo(vv.w)) + blo(ee.w), 0.f),
                    fmaxf(fmaf(g, bhi(uu.w), om * bhi(vv.w)) + bhi(ee.w), 0.f));
      *(uint4*)&h1s[e][j] = make_uint4(o0, o1, o2, o3);
    }
  }
  __syncthreads();
  // Phase H: h2 = relu(h1 @ w2^T + b2)  (M=64, N=64, K=128)
  {
    f32x4 zz = {0.f, 0.f, 0.f, 0.f};
    f32x4 acc[4] = {zz, zz, zz, zz};
    #pragma unroll
    for (int ks = 0; ks < 4; ++ks) {
      short8 a = *(const short8*)&h1s[w * 16 + (lane & 15)][ks * 32 + (lane >> 4) * 8];
      #pragma unroll
      for (int nf = 0; nf < 4; ++nf) {
        short8 b = *(const short8*)(w2B + (size_t)(nf * 16 + (lane & 15)) * 128 + ks * 32 + (lane >> 4) * 8);
        acc[nf] = MFMA16(a, b, acc[nf]);
      }
    }
    __syncthreads();   // eatB dead; h2F aliases it
    int ebase = w * 16 + (lane >> 4) * 4;
    #pragma unroll
    for (int nf = 0; nf < 4; ++nf) {
      int n = nf * 16 + (lane & 15);
      #pragma unroll
      for (int i = 0; i < 4; ++i)
        h2F[ebase + i][n] = fmaxf(acc[nf][i] + mb2s[n], 0.f);
    }
  }
  __syncthreads();
  // Phase O: out = h2 @ mw3^T + b3
  if (t < 128) {
    int e = t >> 1, o = t & 1;
    int eg = e0 + e;
    if (eg < E) {
      float s = mb3[o];
      #pragma unroll
      for (int kk = 0; kk < 64; kk += 4) {
        float4 hv = *(const float4*)&h2F[e][kk];
        float4 wv = *(const float4*)&mw3s[o * 64 + kk];
        s = fmaf(hv.x, wv.x, s); s = fmaf(hv.y, wv.y, s);
        s = fmaf(hv.z, wv.z, s); s = fmaf(hv.w, wv.w, s);
      }
      out[(size_t)eg * 2 + o] = s;
    }
  }
}

// ------------------------------------------------------------------- launch
extern "C" void kernel_launch(void* const* d_in, const int* in_sizes, int n_in,
                              void* d_out, int out_size, void* d_ws, size_t ws_size,
                              hipStream_t stream) {
  const float* x_source = (const float*)d_in[0];
  const float* x_target = (const float*)d_in[1];
  const float* edge_attr = (const float*)d_in[2];
  const float* enc_s_w1 = (const float*)d_in[3];
  const float* enc_s_b1 = (const float*)d_in[4];
  const float* enc_s_w2 = (const float*)d_in[5];
  const float* enc_s_b2 = (const float*)d_in[6];
  const float* enc_t_w1 = (const float*)d_in[7];
  const float* enc_t_b1 = (const float*)d_in[8];
  const float* enc_t_w2 = (const float*)d_in[9];
  const float* enc_t_b2 = (const float*)d_in[10];
  const float* conv_wl = (const float*)d_in[11];
  const float* conv_bl = (const float*)d_in[12];
  const float* conv_wr = (const float*)d_in[13];
  const float* gate_w1 = (const float*)d_in[14];
  const float* gate_b1 = (const float*)d_in[15];
  const float* gate_w2 = (const float*)d_in[16];
  const float* gate_b2 = (const float*)d_in[17];
  const float* mlp_w1 = (const float*)d_in[18];
  const float* mlp_b1 = (const float*)d_in[19];
  const float* mlp_w2 = (const float*)d_in[20];
  const float* mlp_b2 = (const float*)d_in[21];
  const float* mlp_w3 = (const float*)d_in[22];
  const float* mlp_b3 = (const float*)d_in[23];
  const int* ei[4] = {(const int*)d_in[24], (const int*)d_in[25],
                      (const int*)d_in[26], (const int*)d_in[27]};  // 0=ss,1=tt,2=st,3=ts
  float* out = (float*)d_out;

  char* wsp = (char*)d_ws;
  size_t off = 0;
  auto alloc = [&](size_t bytes) {
    char* p = wsp + off;
    off += (bytes + 255) & ~(size_t)255;
    return p;
  };
  ushort* nbase = (ushort*)alloc(6 * NBE * 2);   // 6 rotating node buffers
  ushort* nb[6];
  for (int i = 0; i < 6; ++i) nb[i] = nbase + (size_t)i * NBE;
  int* adj4 = (int*)alloc((size_t)4 * EE * 4);
  int* off4 = (int*)alloc(4 * 50001 * 4);
  int* cur4 = (int*)alloc(4 * 50000 * 4);
  int* cnt4 = (int*)alloc(4 * 50000 * 4);
  ushort* xsB = (ushort*)alloc((size_t)NSN * 64 * 2);
  ushort* xtB = (ushort*)alloc((size_t)NTN * 64 * 2);
  ushort* esw1B = (ushort*)alloc(128 * 64 * 2);
  ushort* esw2B = (ushort*)alloc(128 * 128 * 2);
  ushort* etw1B = (ushort*)alloc(128 * 64 * 2);
  ushort* etw2B = (ushort*)alloc(128 * 128 * 2);
  ushort* wlB = (ushort*)alloc((size_t)12 * 16384 * 2);
  ushort* wrcB = (ushort*)alloc((size_t)6 * 16384 * 2);
  float* blc = (float*)alloc(6 * 128 * 4);
  ushort* Whead = (ushort*)alloc((size_t)2 * 256 * 128 * 2);
  float* biasHead = (float*)alloc(2 * 256 * 4);
  ushort* w1eB = (ushort*)alloc(128 * 32 * 2);
  ushort* w2B = (ushort*)alloc(64 * 128 * 2);

  // --- CSR build ---
  hipMemsetAsync(cnt4, 0, 4 * 50000 * sizeof(int), stream);
  int cb = (EE + 255) / 256;
  count4_k<<<dim3(cb, 4), 256, 0, stream>>>(ei[0], ei[1], ei[2], ei[3], cnt4);
  scan_k<<<4, 256, 0, stream>>>(cnt4, off4, cur4);
  fill4_k<<<dim3(cb, 4), 256, 0, stream>>>(ei[0], ei[1], ei[2], ei[3], cur4, adj4);

  // --- conversions / weight assembly ---
  cvtall_k<<<(6645760 + 255) / 256, 256, 0, stream>>>(
      x_source, x_target, conv_wl, enc_s_w1, enc_s_w2, enc_t_w1, enc_t_w2,
      xsB, xtB, wlB, esw1B, esw2B, etw1B, etw2B);
  wrc_k<<<dim3(64, 6), 256, 0, stream>>>(conv_wr, conv_bl, wrcB, blc);
  headw_k<<<307, 256, 0, stream>>>(gate_w1, mlp_w1, mlp_w2, gate_b1, mlp_b1,
                                   Whead, biasHead, w1eB, w2B);

  // --- encoders: (xs,xt) -> nb4,nb5 -> nb0,nb1 ---
  int gm = (NSN + 127) / 128;
  enc_k<1><<<dim3(gm, 2), 256, 0, stream>>>(xsB, xtB, esw1B, etw1B,
      enc_s_b1, enc_t_b1, nb[4], nb[5], NSN, 64);
  enc_k<0><<<dim3(gm, 2), 256, 0, stream>>>(nb[4], nb[5], esw2B, etw2B,
      enc_s_b2, enc_t_b2, nb[0], nb[1], NSN, 128);

  // --- 3 fused hetero layers: (0,1)->(2,3)->(4,5)->(2,3) ---
  layer_k<0><<<dim3(gm, 2), 256, 0, stream>>>(nb[0], nb[1], off4, adj4,
      wlB, wrcB, blc, nb[2], nb[3], NSN);
  layer_k<1><<<dim3(gm, 2), 256, 0, stream>>>(nb[2], nb[3], off4, adj4,
      wlB + (size_t)4 * 16384, wrcB + (size_t)2 * 16384, blc + 256, nb[4], nb[5], NSN);
  layer_k<1><<<dim3(gm, 2), 256, 0, stream>>>(nb[4], nb[5], off4, adj4,
      wlB + (size_t)8 * 16384, wrcB + (size_t)4 * 16384, blc + 512, nb[2], nb[3], NSN);
  // h3s = nb2, h3t = nb3

  // --- nodewise head precompute: pS = nb0..1 region, pT = nb4..5 region ---
  ushort* pS = nbase;
  ushort* pT = nbase + 4 * NBE;
  gemmH_k<<<dim3(gm, 2, 2), 256, 0, stream>>>(nbase + 2 * NBE, Whead, biasHead, pS, pT);

  // --- fused edge head ---
  head_k<<<(EE + 63) / 64, 256, 0, stream>>>(pS, pT, ei[2], edge_attr, w1eB, w2B,
      gate_w2, gate_b2, mlp_b2, mlp_w3, mlp_b3, out, EE);
}

// Round 5
// 1024.122 us; speedup vs baseline: 1.3491x; 1.3491x over previous
//
#include <hip/hip_runtime.h>
#include <cmath>

#define NSN 50000
#define NTN 50000
#define EE  500000
#define NBE ((size_t)NSN * 128)

using short8 = __attribute__((ext_vector_type(8))) short;
using f32x4  = __attribute__((ext_vector_type(4))) float;
#define MFMA16(a, b, c) __builtin_amdgcn_mfma_f32_16x16x32_bf16(a, b, c, 0, 0, 0)

__device__ __forceinline__ float  b2f(ushort u) { return __uint_as_float(((uint)u) << 16); }
__device__ __forceinline__ ushort f2b(float f) {
  uint x = __float_as_uint(f);
  uint r = x + 0x7FFFu + ((x >> 16) & 1u);
  return (ushort)(r >> 16);
}
__device__ __forceinline__ float blo(uint x) { return __uint_as_float(x << 16); }
__device__ __forceinline__ float bhi(uint x) { return __uint_as_float(x & 0xFFFF0000u); }
__device__ __forceinline__ uint  pk2(float a, float b) { return (uint)f2b(a) | ((uint)f2b(b) << 16); }

// ------------------------------------------------- all input/weight converts
__global__ void cvtall_k(const float* __restrict__ xs, const float* __restrict__ xt,
                         const float* __restrict__ wl,
                         const float* __restrict__ esw1, const float* __restrict__ esw2,
                         const float* __restrict__ etw1, const float* __restrict__ etw2,
                         ushort* __restrict__ xsB, ushort* __restrict__ xtB,
                         ushort* __restrict__ wlB, ushort* __restrict__ esw1B,
                         ushort* __restrict__ esw2B, ushort* __restrict__ etw1B,
                         ushort* __restrict__ etw2B) {
  int i = blockIdx.x * 256 + threadIdx.x;
  if (i < 3200000) { xsB[i] = f2b(xs[i]); return; }
  i -= 3200000;
  if (i < 3200000) {
    int r = i >> 6, k = i & 63;
    xtB[i] = (k < 48) ? f2b(xt[(size_t)r * 48 + k]) : (ushort)0;
    return;
  }
  i -= 3200000;
  if (i < 196608) { wlB[i] = f2b(wl[i]); return; }
  i -= 196608;
  if (i < 8192) { esw1B[i] = f2b(esw1[i]); return; }
  i -= 8192;
  if (i < 16384) { esw2B[i] = f2b(esw2[i]); return; }
  i -= 16384;
  if (i < 8192) {
    int r = i >> 6, k = i & 63;
    etw1B[i] = (k < 48) ? f2b(etw1[(size_t)r * 48 + k]) : (ushort)0;
    return;
  }
  i -= 8192;
  if (i < 16384) { etw2B[i] = f2b(etw2[i]); return; }
}

// ------------------------------------------------- combined wr + bias
__global__ void wrc_k(const float* __restrict__ wr, const float* __restrict__ bl,
                      ushort* __restrict__ wrcB, float* __restrict__ blc) {
  int z = blockIdx.y;
  int l = z >> 1, dd = z & 1;
  int r1 = dd ? 1 : 0, r2 = dd ? 2 : 3;
  int idx = blockIdx.x * 256 + threadIdx.x;
  if (idx < 16384) {
    wrcB[(size_t)z * 16384 + idx] =
        f2b(wr[(size_t)(l * 4 + r1) * 16384 + idx] + wr[(size_t)(l * 4 + r2) * 16384 + idx]);
    if (idx < 128)
      blc[z * 128 + idx] = bl[(l * 4 + r1) * 128 + idx] + bl[(l * 4 + r2) * 128 + idx];
  }
}

// ------------------------------------------------- head weight assembly
__global__ void headw_k(const float* __restrict__ gw1, const float* __restrict__ mw1,
                        const float* __restrict__ mw2, const float* __restrict__ gb1,
                        const float* __restrict__ mb1,
                        ushort* __restrict__ Whead, float* __restrict__ biasHead,
                        ushort* __restrict__ w1eB, ushort* __restrict__ w2B) {
  int idx = blockIdx.x * 256 + threadIdx.x;
  if (idx < 65536) {
    int z = idx >> 15, rr = (idx >> 7) & 255, c = idx & 127;
    float v = (rr < 128) ? gw1[(size_t)rr * 256 + z * 128 + c]
                         : mw1[(size_t)(rr - 128) * 160 + c];
    Whead[idx] = f2b(v);
  } else if (idx < 69632) {
    int i = idx - 65536;
    w1eB[i] = f2b(mw1[(size_t)(i >> 5) * 160 + 128 + (i & 31)]);
  } else if (idx < 77824) {
    int i = idx - 69632;
    w2B[i] = f2b(mw2[i]);
  } else if (idx < 78336) {
    int i = idx - 77824;
    int z = i >> 8, n = i & 255;
    biasHead[i] = (n < 128) ? (z ? 0.f : gb1[n]) : mb1[n - 128];
  }
}

// --------------------------------------------------------------- CSR build
__global__ void count4_k(const int* __restrict__ e0, const int* __restrict__ e1,
                         const int* __restrict__ e2, const int* __restrict__ e3,
                         int* __restrict__ cnt) {
  int rel = blockIdx.y;
  const int* col = (rel == 0 ? e0 : rel == 1 ? e1 : rel == 2 ? e2 : e3) + EE;
  int i = blockIdx.x * 256 + threadIdx.x;
  if (i < EE) atomicAdd(&cnt[rel * 50000 + col[i]], 1);
}
__global__ void scan_k(const int* __restrict__ cnt, int* __restrict__ off,
                       int* __restrict__ cur) {
  __shared__ int wsum[4];
  __shared__ int runS;
  int rel = blockIdx.x;
  const int* c = cnt + (size_t)rel * 50000;
  int* o = off + (size_t)rel * 50001;
  int* cu = cur + (size_t)rel * 50000;
  int t = threadIdx.x, lane = t & 63, w = t >> 6;
  if (t == 0) { runS = 0; o[0] = 0; }
  __syncthreads();
  for (int base = 0; base < 50000; base += 256) {
    int i = base + t;
    int v = (i < 50000) ? c[i] : 0;
    int x = v;
    #pragma unroll
    for (int d = 1; d < 64; d <<= 1) {
      int y = __shfl_up(x, d, 64);
      if (lane >= d) x += y;
    }
    if (lane == 63) wsum[w] = x;
    __syncthreads();
    int add = runS;
    for (int ww = 0; ww < w; ++ww) add += wsum[ww];
    int incl = add + x;
    if (i < 50000) { cu[i] = incl - v; o[i + 1] = incl; }
    __syncthreads();
    if (t == 255) runS = add + x;
    __syncthreads();
  }
}
__global__ void fill4_k(const int* __restrict__ e0, const int* __restrict__ e1,
                        const int* __restrict__ e2, const int* __restrict__ e3,
                        int* __restrict__ cur, int* __restrict__ adj) {
  int rel = blockIdx.y;
  const int* ei = rel == 0 ? e0 : rel == 1 ? e1 : rel == 2 ? e2 : e3;
  int e = blockIdx.x * 256 + threadIdx.x;
  if (e < EE) {
    int pos = atomicAdd(&cur[rel * 50000 + ei[EE + e]], 1);
    adj[(size_t)rel * EE + pos] = ei[e];
  }
}

// ------------------------------------------------------------- gather-mean
// one wave per node; 4 groups of 16 lanes, each group pulls whole 256B rows
// grid.y = relation (0=ss,1=tt,2=st,3=ts)
__global__ __launch_bounds__(256) void gather4_k(
    const ushort* __restrict__ hs, const ushort* __restrict__ ht,
    const int* __restrict__ off4, const int* __restrict__ adj4,
    ushort* __restrict__ m0, ushort* __restrict__ m1,
    ushort* __restrict__ m2, ushort* __restrict__ m3, int N) {
  int r = blockIdx.y;
  const ushort* src = (r == 0 || r == 2) ? hs : ht;
  ushort* dst = r == 0 ? m0 : (r == 1 ? m1 : (r == 2 ? m2 : m3));
  const int* off = off4 + r * 50001;
  const int* adj = adj4 + (size_t)r * EE;
  int t = threadIdx.x;
  int n = blockIdx.x * 4 + (t >> 6);
  if (n >= N) return;
  int lane = t & 63, g = lane >> 4, i = lane & 15;
  int s = off[n], e = off[n + 1];
  float a[8] = {};
  for (int k = s + g; k < e; k += 4) {
    int row = adj[k];
    uint4 v = *(const uint4*)(src + (size_t)row * 128 + i * 8);
    a[0] += blo(v.x); a[1] += bhi(v.x);
    a[2] += blo(v.y); a[3] += bhi(v.y);
    a[4] += blo(v.z); a[5] += bhi(v.z);
    a[6] += blo(v.w); a[7] += bhi(v.w);
  }
  #pragma unroll
  for (int c = 0; c < 8; ++c) {
    a[c] += __shfl_xor(a[c], 16, 64);
    a[c] += __shfl_xor(a[c], 32, 64);
  }
  if (g == 0) {
    float inv = 1.f / (float)max(e - s, 1);
    uint4 o;
    o.x = pk2(a[0] * inv, a[1] * inv);
    o.y = pk2(a[2] * inv, a[3] * inv);
    o.z = pk2(a[4] * inv, a[5] * inv);
    o.w = pk2(a[6] * inv, a[7] * inv);
    *(uint4*)(dst + (size_t)n * 128 + i * 8) = o;
  }
}

// ------------------------------------------------------- shared GEMM body
template <int MODE>
__device__ __forceinline__ void gemm_body(
    ushort (*As)[40], ushort (*Ws)[40],
    const ushort* __restrict__ A, const ushort* __restrict__ W,
    const float* __restrict__ bias, ushort* __restrict__ C,
    int M, int K, int ldc, int m0) {
  int t = threadIdx.x;
  int lane = t & 63, w = t >> 6, wm = w >> 1, wn = w & 1;
  f32x4 zz = {0.f, 0.f, 0.f, 0.f};
  f32x4 acc[4][4];
  #pragma unroll
  for (int i = 0; i < 4; ++i)
    #pragma unroll
    for (int j = 0; j < 4; ++j) acc[i][j] = zz;
  for (int kb = 0; kb < K; kb += 32) {
    #pragma unroll
    for (int s = 0; s < 2; ++s) {
      int idx = t + s * 256;
      int r = idx >> 2, c = idx & 3;
      int gm = m0 + r;
      uint4 va = make_uint4(0, 0, 0, 0);
      if (gm < M) va = *(const uint4*)(A + (size_t)gm * K + kb + c * 8);
      *(uint4*)&As[r][c * 8] = va;
      *(uint4*)&Ws[r][c * 8] = *(const uint4*)(W + (size_t)r * K + kb + c * 8);
    }
    __syncthreads();
    short8 af[4], bf[4];
    #pragma unroll
    for (int mf = 0; mf < 4; ++mf)
      af[mf] = *(const short8*)&As[wm * 64 + mf * 16 + (lane & 15)][(lane >> 4) * 8];
    #pragma unroll
    for (int nf = 0; nf < 4; ++nf)
      bf[nf] = *(const short8*)&Ws[wn * 64 + nf * 16 + (lane & 15)][(lane >> 4) * 8];
    #pragma unroll
    for (int mf = 0; mf < 4; ++mf)
      #pragma unroll
      for (int nf = 0; nf < 4; ++nf) acc[mf][nf] = MFMA16(af[mf], bf[nf], acc[mf][nf]);
    __syncthreads();
  }
  int r0 = (lane >> 4) * 4, nin = lane & 15;
  #pragma unroll
  for (int mf = 0; mf < 4; ++mf)
    #pragma unroll
    for (int nf = 0; nf < 4; ++nf) {
      int n = wn * 64 + nf * 16 + nin;
      float bv = bias ? bias[n] : 0.f;
      #pragma unroll
      for (int i = 0; i < 4; ++i) {
        int gm = m0 + wm * 64 + mf * 16 + r0 + i;
        if (gm >= M) continue;
        float v = acc[mf][nf][i] + bv;
        if (MODE == 1) v = fmaxf(v, 0.f);
        C[(size_t)gm * ldc + n] = f2b(v);
      }
    }
}

// encoder stage (grid.y picks source/target config)
template <int MODE>
__global__ __launch_bounds__(256) void enc_k(
    const ushort* A0, const ushort* A1, const ushort* W0, const ushort* W1,
    const float* b0, const float* b1, ushort* C0, ushort* C1, int M, int K) {
  __shared__ alignas(16) ushort As[128][40];
  __shared__ alignas(16) ushort Ws[128][40];
  int y = blockIdx.y;
  gemm_body<MODE>(As, Ws, y ? A1 : A0, y ? W1 : W0, y ? b1 : b0, y ? C1 : C0,
                  M, K, 128, blockIdx.x * 128);
}

// head precompute: z = node set (S/T), ny = N-tile of 256-wide output
__global__ __launch_bounds__(256) void gemmH_k(
    const ushort* Abase, const ushort* Whead, const float* biasHead,
    ushort* pS, ushort* pT) {
  __shared__ alignas(16) ushort As[128][40];
  __shared__ alignas(16) ushort Ws[128][40];
  int z = blockIdx.z, ny = blockIdx.y;
  gemm_body<0>(As, Ws, Abase + (size_t)z * NBE,
               Whead + ((size_t)z * 256 + ny * 128) * 128,
               biasHead + z * 256 + ny * 128,
               (z ? pT : pS) + ny * 128,
               NSN, 128, 256, blockIdx.x * 128);
}

// ---------------------------------- layer GEMM: 3 A-panels, both dst types
// out = relu(0.5*(mA@W0^T + mB@W1^T + self@Wrc^T + bias) [+ self])
template <int RES>
__global__ __launch_bounds__(256) void lgemm_k(
    const ushort* __restrict__ hs, const ushort* __restrict__ ht,
    const ushort* __restrict__ m0, const ushort* __restrict__ m1,
    const ushort* __restrict__ m2, const ushort* __restrict__ m3,
    const ushort* __restrict__ wlL, const ushort* __restrict__ wrcL,
    const float* __restrict__ blcL,
    ushort* __restrict__ hsOut, ushort* __restrict__ htOut, int M) {
  __shared__ alignas(16) ushort As[128][40];
  __shared__ alignas(16) ushort Ws[128][40];
  int t = threadIdx.x;
  int y = blockIdx.y;
  int m0i = blockIdx.x * 128;
  const ushort* A0 = y ? m1 : m0;
  const ushort* A1 = y ? m2 : m3;
  const ushort* self = y ? ht : hs;
  const ushort* W0 = wlL + (size_t)(y ? 1 : 0) * 16384;
  const ushort* W1 = wlL + (size_t)(y ? 2 : 3) * 16384;
  const ushort* W2 = wrcL + (size_t)y * 16384;
  const float* bias = blcL + y * 128;
  ushort* C = y ? htOut : hsOut;

  int lane = t & 63, w = t >> 6, wm = w >> 1, wn = w & 1;
  f32x4 zz = {0.f, 0.f, 0.f, 0.f};
  f32x4 acc[4][4];
  #pragma unroll
  for (int i = 0; i < 4; ++i)
    #pragma unroll
    for (int j = 0; j < 4; ++j) acc[i][j] = zz;
  for (int p = 0; p < 3; ++p) {
    const ushort* A = p == 0 ? A0 : (p == 1 ? A1 : self);
    const ushort* Wp = p == 0 ? W0 : (p == 1 ? W1 : W2);
    for (int kb = 0; kb < 128; kb += 32) {
      #pragma unroll
      for (int s = 0; s < 2; ++s) {
        int idx = t + s * 256;
        int r = idx >> 2, c = idx & 3;
        int gm = m0i + r;
        uint4 va = make_uint4(0, 0, 0, 0);
        if (gm < M) va = *(const uint4*)(A + (size_t)gm * 128 + kb + c * 8);
        *(uint4*)&As[r][c * 8] = va;
        *(uint4*)&Ws[r][c * 8] = *(const uint4*)(Wp + (size_t)r * 128 + kb + c * 8);
      }
      __syncthreads();
      short8 af[4], bf[4];
      #pragma unroll
      for (int mf = 0; mf < 4; ++mf)
        af[mf] = *(const short8*)&As[wm * 64 + mf * 16 + (lane & 15)][(lane >> 4) * 8];
      #pragma unroll
      for (int nf = 0; nf < 4; ++nf)
        bf[nf] = *(const short8*)&Ws[wn * 64 + nf * 16 + (lane & 15)][(lane >> 4) * 8];
      #pragma unroll
      for (int mf = 0; mf < 4; ++mf)
        #pragma unroll
        for (int nf = 0; nf < 4; ++nf) acc[mf][nf] = MFMA16(af[mf], bf[nf], acc[mf][nf]);
      __syncthreads();
    }
  }
  int r0 = (lane >> 4) * 4, nin = lane & 15;
  #pragma unroll
  for (int mf = 0; mf < 4; ++mf)
    #pragma unroll
    for (int nf = 0; nf < 4; ++nf) {
      int n = wn * 64 + nf * 16 + nin;
      float bv = bias[n];
      #pragma unroll
      for (int i = 0; i < 4; ++i) {
        int gm = m0i + wm * 64 + mf * 16 + r0 + i;
        if (gm >= M) continue;
        float v = 0.5f * (acc[mf][nf][i] + bv);
        if (RES) v += b2f(self[(size_t)gm * 128 + n]);
        C[(size_t)gm * 128 + n] = f2b(fmaxf(v, 0.f));
      }
    }
}

// ---------------------------------------------------------------- edge head
__global__ __launch_bounds__(256) void head_k(
    const ushort* __restrict__ pS, const ushort* __restrict__ pT,
    const int* __restrict__ ei, const float* __restrict__ ea,
    const ushort* __restrict__ w1eB, const ushort* __restrict__ w2B,
    const float* __restrict__ gw2, const float* __restrict__ gb2p,
    const float* __restrict__ mb2, const float* __restrict__ mw3,
    const float* __restrict__ mb3, float* __restrict__ out, int E) {
  __shared__ alignas(16) ushort eatB[64][136];   // eat (bf16); aliased by h2F after
  __shared__ alignas(16) ushort h1s[64][136];
  __shared__ int er[64], ec[64];
  __shared__ alignas(16) float gw2s[128];
  __shared__ alignas(16) float mw3s[128];
  __shared__ float mb2s[64];
  float (*h2F)[68] = (float(*)[68])&eatB[0][0];

  int t = threadIdx.x;
  int e0 = blockIdx.x * 64;
  if (t < 64) {
    int eg = e0 + t;
    er[t] = (eg < E) ? ei[eg] : 0;
    mb2s[t] = mb2[t];
  } else if (t < 128) {
    int q = t - 64;
    int eg = e0 + q;
    ec[q] = (eg < E) ? ei[E + eg] : 0;
  }
  if (t < 128) gw2s[t] = gw2[t];
  else mw3s[t - 128] = mw3[t - 128];
  __syncthreads();
  int lane = t & 63, w = t >> 6;
  // Phase E: eat = ea @ w1e^T (M=64, N=128, K=32); A-frag straight from global
  {
    int erow = e0 + w * 16 + (lane & 15);
    float4 f0 = make_float4(0, 0, 0, 0), f1 = make_float4(0, 0, 0, 0);
    if (erow < E) {
      f0 = *(const float4*)(ea + (size_t)erow * 32 + (lane >> 4) * 8);
      f1 = *(const float4*)(ea + (size_t)erow * 32 + (lane >> 4) * 8 + 4);
    }
    union { short8 s; uint4 u; } cv;
    cv.u = make_uint4(pk2(f0.x, f0.y), pk2(f0.z, f0.w), pk2(f1.x, f1.y), pk2(f1.z, f1.w));
    short8 a = cv.s;
    int ebase = w * 16 + (lane >> 4) * 4;
    #pragma unroll
    for (int nf = 0; nf < 8; ++nf) {
      short8 b = *(const short8*)(w1eB + (size_t)(nf * 16 + (lane & 15)) * 32 + (lane >> 4) * 8);
      f32x4 cz = {0.f, 0.f, 0.f, 0.f};
      cz = MFMA16(a, b, cz);
      int jj = nf * 16 + (lane & 15);
      #pragma unroll
      for (int i = 0; i < 4; ++i) eatB[ebase + i][jj] = f2b(cz[i]);
    }
  }
  __syncthreads();
  // Phase G: gate + convex combine -> h1 (bf16 LDS)
  {
    int el = lane >> 2, q = lane & 3, e = w * 16 + el;
    int j0 = q * 32;
    const ushort* ps = pS + (size_t)er[e] * 256;
    const ushort* pt = pT + (size_t)ec[e] * 256;
    float dot = 0.f;
    #pragma unroll
    for (int cc = 0; cc < 4; ++cc) {
      int j = j0 + cc * 8;
      uint4 ga = *(const uint4*)(ps + j);
      uint4 gb = *(const uint4*)(pt + j);
      const float* gp = &gw2s[j];
      float h;
      h = fmaxf(blo(ga.x) + blo(gb.x), 0.f); dot = fmaf(h, gp[0], dot);
      h = fmaxf(bhi(ga.x) + bhi(gb.x), 0.f); dot = fmaf(h, gp[1], dot);
      h = fmaxf(blo(ga.y) + blo(gb.y), 0.f); dot = fmaf(h, gp[2], dot);
      h = fmaxf(bhi(ga.y) + bhi(gb.y), 0.f); dot = fmaf(h, gp[3], dot);
      h = fmaxf(blo(ga.z) + blo(gb.z), 0.f); dot = fmaf(h, gp[4], dot);
      h = fmaxf(bhi(ga.z) + bhi(gb.z), 0.f); dot = fmaf(h, gp[5], dot);
      h = fmaxf(blo(ga.w) + blo(gb.w), 0.f); dot = fmaf(h, gp[6], dot);
      h = fmaxf(bhi(ga.w) + bhi(gb.w), 0.f); dot = fmaf(h, gp[7], dot);
    }
    dot += __shfl_xor(dot, 1, 64);
    dot += __shfl_xor(dot, 2, 64);
    float g = 1.f / (1.f + __expf(-(dot + gb2p[0])));
    float om = 1.f - g;
    #pragma unroll
    for (int cc = 0; cc < 4; ++cc) {
      int j = j0 + cc * 8;
      uint4 uu = *(const uint4*)(ps + 128 + j);
      uint4 vv = *(const uint4*)(pt + 128 + j);
      uint4 ee = *(const uint4*)&eatB[e][j];
      uint o0 = pk2(fmaxf(fmaf(g, blo(uu.x), om * blo(vv.x)) + blo(ee.x), 0.f),
                    fmaxf(fmaf(g, bhi(uu.x), om * bhi(vv.x)) + bhi(ee.x), 0.f));
      uint o1 = pk2(fmaxf(fmaf(g, blo(uu.y), om * blo(vv.y)) + blo(ee.y), 0.f),
                    fmaxf(fmaf(g, bhi(uu.y), om * bhi(vv.y)) + bhi(ee.y), 0.f));
      uint o2 = pk2(fmaxf(fmaf(g, blo(uu.z), om * blo(vv.z)) + blo(ee.z), 0.f),
                    fmaxf(fmaf(g, bhi(uu.z), om * bhi(vv.z)) + bhi(ee.z), 0.f));
      uint o3 = pk2(fmaxf(fmaf(g, blo(uu.w), om * blo(vv.w)) + blo(ee.w), 0.f),
                    fmaxf(fmaf(g, bhi(uu.w), om * bhi(vv.w)) + bhi(ee.w), 0.f));
      *(uint4*)&h1s[e][j] = make_uint4(o0, o1, o2, o3);
    }
  }
  __syncthreads();
  // Phase H: h2 = relu(h1 @ w2^T + b2)  (M=64, N=64, K=128)
  {
    f32x4 zz = {0.f, 0.f, 0.f, 0.f};
    f32x4 acc[4] = {zz, zz, zz, zz};
    #pragma unroll
    for (int ks = 0; ks < 4; ++ks) {
      short8 a = *(const short8*)&h1s[w * 16 + (lane & 15)][ks * 32 + (lane >> 4) * 8];
      #pragma unroll
      for (int nf = 0; nf < 4; ++nf) {
        short8 b = *(const short8*)(w2B + (size_t)(nf * 16 + (lane & 15)) * 128 + ks * 32 + (lane >> 4) * 8);
        acc[nf] = MFMA16(a, b, acc[nf]);
      }
    }
    __syncthreads();   // eatB dead; h2F aliases it
    int ebase = w * 16 + (lane >> 4) * 4;
    #pragma unroll
    for (int nf = 0; nf < 4; ++nf) {
      int n = nf * 16 + (lane & 15);
      #pragma unroll
      for (int i = 0; i < 4; ++i)
        h2F[ebase + i][n] = fmaxf(acc[nf][i] + mb2s[n], 0.f);
    }
  }
  __syncthreads();
  // Phase O: out = h2 @ mw3^T + b3
  if (t < 128) {
    int e = t >> 1, o = t & 1;
    int eg = e0 + e;
    if (eg < E) {
      float s = mb3[o];
      #pragma unroll
      for (int kk = 0; kk < 64; kk += 4) {
        float4 hv = *(const float4*)&h2F[e][kk];
        float4 wv = *(const float4*)&mw3s[o * 64 + kk];
        s = fmaf(hv.x, wv.x, s); s = fmaf(hv.y, wv.y, s);
        s = fmaf(hv.z, wv.z, s); s = fmaf(hv.w, wv.w, s);
      }
      out[(size_t)eg * 2 + o] = s;
    }
  }
}

// ------------------------------------------------------------------- launch
extern "C" void kernel_launch(void* const* d_in, const int* in_sizes, int n_in,
                              void* d_out, int out_size, void* d_ws, size_t ws_size,
                              hipStream_t stream) {
  const float* x_source = (const float*)d_in[0];
  const float* x_target = (const float*)d_in[1];
  const float* edge_attr = (const float*)d_in[2];
  const float* enc_s_w1 = (const float*)d_in[3];
  const float* enc_s_b1 = (const float*)d_in[4];
  const float* enc_s_w2 = (const float*)d_in[5];
  const float* enc_s_b2 = (const float*)d_in[6];
  const float* enc_t_w1 = (const float*)d_in[7];
  const float* enc_t_b1 = (const float*)d_in[8];
  const float* enc_t_w2 = (const float*)d_in[9];
  const float* enc_t_b2 = (const float*)d_in[10];
  const float* conv_wl = (const float*)d_in[11];
  const float* conv_bl = (const float*)d_in[12];
  const float* conv_wr = (const float*)d_in[13];
  const float* gate_w1 = (const float*)d_in[14];
  const float* gate_b1 = (const float*)d_in[15];
  const float* gate_w2 = (const float*)d_in[16];
  const float* gate_b2 = (const float*)d_in[17];
  const float* mlp_w1 = (const float*)d_in[18];
  const float* mlp_b1 = (const float*)d_in[19];
  const float* mlp_w2 = (const float*)d_in[20];
  const float* mlp_b2 = (const float*)d_in[21];
  const float* mlp_w3 = (const float*)d_in[22];
  const float* mlp_b3 = (const float*)d_in[23];
  const int* ei[4] = {(const int*)d_in[24], (const int*)d_in[25],
                      (const int*)d_in[26], (const int*)d_in[27]};  // 0=ss,1=tt,2=st,3=ts
  float* out = (float*)d_out;

  char* wsp = (char*)d_ws;
  size_t off = 0;
  auto alloc = [&](size_t bytes) {
    char* p = wsp + off;
    off += (bytes + 255) & ~(size_t)255;
    return p;
  };
  ushort* nbase = (ushort*)alloc(4 * NBE * 2);   // 4 rotating node buffers
  ushort* nb[4];
  for (int i = 0; i < 4; ++i) nb[i] = nbase + (size_t)i * NBE;
  ushort* shared4 = (ushort*)alloc(4 * NBE * 2); // means m0..m3 / later pS,pT
  ushort* mB[4];
  for (int i = 0; i < 4; ++i) mB[i] = shared4 + (size_t)i * NBE;
  int* adj4 = (int*)alloc((size_t)4 * EE * 4);
  int* off4 = (int*)alloc(4 * 50001 * 4);
  int* cur4 = (int*)alloc(4 * 50000 * 4);
  int* cnt4 = (int*)alloc(4 * 50000 * 4);
  ushort* xsB = (ushort*)alloc((size_t)NSN * 64 * 2);
  ushort* xtB = (ushort*)alloc((size_t)NTN * 64 * 2);
  ushort* esw1B = (ushort*)alloc(128 * 64 * 2);
  ushort* esw2B = (ushort*)alloc(128 * 128 * 2);
  ushort* etw1B = (ushort*)alloc(128 * 64 * 2);
  ushort* etw2B = (ushort*)alloc(128 * 128 * 2);
  ushort* wlB = (ushort*)alloc((size_t)12 * 16384 * 2);
  ushort* wrcB = (ushort*)alloc((size_t)6 * 16384 * 2);
  float* blc = (float*)alloc(6 * 128 * 4);
  ushort* Whead = (ushort*)alloc((size_t)2 * 256 * 128 * 2);
  float* biasHead = (float*)alloc(2 * 256 * 4);
  ushort* w1eB = (ushort*)alloc(128 * 32 * 2);
  ushort* w2B = (ushort*)alloc(64 * 128 * 2);

  // --- CSR build ---
  hipMemsetAsync(cnt4, 0, 4 * 50000 * sizeof(int), stream);
  int cb = (EE + 255) / 256;
  count4_k<<<dim3(cb, 4), 256, 0, stream>>>(ei[0], ei[1], ei[2], ei[3], cnt4);
  scan_k<<<4, 256, 0, stream>>>(cnt4, off4, cur4);
  fill4_k<<<dim3(cb, 4), 256, 0, stream>>>(ei[0], ei[1], ei[2], ei[3], cur4, adj4);

  // --- conversions / weight assembly ---
  cvtall_k<<<(6645760 + 255) / 256, 256, 0, stream>>>(
      x_source, x_target, conv_wl, enc_s_w1, enc_s_w2, enc_t_w1, enc_t_w2,
      xsB, xtB, wlB, esw1B, esw2B, etw1B, etw2B);
  wrc_k<<<dim3(64, 6), 256, 0, stream>>>(conv_wr, conv_bl, wrcB, blc);
  headw_k<<<307, 256, 0, stream>>>(gate_w1, mlp_w1, mlp_w2, gate_b1, mlp_b1,
                                   Whead, biasHead, w1eB, w2B);

  // --- encoders: (xs,xt) -> nb2,nb3 (tmp) -> nb0,nb1 ---
  int gm = (NSN + 127) / 128;
  enc_k<1><<<dim3(gm, 2), 256, 0, stream>>>(xsB, xtB, esw1B, etw1B,
      enc_s_b1, enc_t_b1, nb[2], nb[3], NSN, 64);
  enc_k<0><<<dim3(gm, 2), 256, 0, stream>>>(nb[2], nb[3], esw2B, etw2B,
      enc_s_b2, enc_t_b2, nb[0], nb[1], NSN, 128);

  // --- 3 hetero layers: (0,1)->(2,3)->(0,1)->(2,3) ---
  int gb = (NSN + 3) / 4;
  layer_loop:
  {
    // layer 1
    gather4_k<<<dim3(gb, 4), 256, 0, stream>>>(nb[0], nb[1], off4, adj4,
        mB[0], mB[1], mB[2], mB[3], NSN);
    lgemm_k<0><<<dim3(gm, 2), 256, 0, stream>>>(nb[0], nb[1],
        mB[0], mB[1], mB[2], mB[3], wlB, wrcB, blc, nb[2], nb[3], NSN);
    // layer 2
    gather4_k<<<dim3(gb, 4), 256, 0, stream>>>(nb[2], nb[3], off4, adj4,
        mB[0], mB[1], mB[2], mB[3], NSN);
    lgemm_k<1><<<dim3(gm, 2), 256, 0, stream>>>(nb[2], nb[3],
        mB[0], mB[1], mB[2], mB[3], wlB + (size_t)4 * 16384,
        wrcB + (size_t)2 * 16384, blc + 256, nb[0], nb[1], NSN);
    // layer 3
    gather4_k<<<dim3(gb, 4), 256, 0, stream>>>(nb[0], nb[1], off4, adj4,
        mB[0], mB[1], mB[2], mB[3], NSN);
    lgemm_k<1><<<dim3(gm, 2), 256, 0, stream>>>(nb[0], nb[1],
        mB[0], mB[1], mB[2], mB[3], wlB + (size_t)8 * 16384,
        wrcB + (size_t)4 * 16384, blc + 512, nb[2], nb[3], NSN);
  }
  // h3s = nb2, h3t = nb3

  // --- nodewise head precompute: pS/pT overlay the (dead) mean region ---
  ushort* pS = shared4;
  ushort* pT = shared4 + 2 * NBE;
  gemmH_k<<<dim3(gm, 2, 2), 256, 0, stream>>>(nbase + 2 * NBE, Whead, biasHead, pS, pT);

  // --- fused edge head ---
  head_k<<<(EE + 63) / 64, 256, 0, stream>>>(pS, pT, ei[2], edge_attr, w1eB, w2B,
      gate_w2, gate_b2, mlp_b2, mlp_w3, mlp_b3, out, EE);
}

// Round 6
// 843.441 us; speedup vs baseline: 1.6381x; 1.2142x over previous
//
#include <hip/hip_runtime.h>
#include <cmath>

#define NSN 50000
#define NTN 50000
#define EE  500000
#define NBE ((size_t)NSN * 128)
#define NPASS 4
#define PRNG 12500

using short8 = __attribute__((ext_vector_type(8))) short;
using f32x4  = __attribute__((ext_vector_type(4))) float;
#define MFMA16(a, b, c) __builtin_amdgcn_mfma_f32_16x16x32_bf16(a, b, c, 0, 0, 0)

__device__ __forceinline__ float  b2f(ushort u) { return __uint_as_float(((uint)u) << 16); }
__device__ __forceinline__ ushort f2b(float f) {
  uint x = __float_as_uint(f);
  uint r = x + 0x7FFFu + ((x >> 16) & 1u);
  return (ushort)(r >> 16);
}
__device__ __forceinline__ float blo(uint x) { return __uint_as_float(x << 16); }
__device__ __forceinline__ float bhi(uint x) { return __uint_as_float(x & 0xFFFF0000u); }
__device__ __forceinline__ uint  pk2(float a, float b) { return (uint)f2b(a) | ((uint)f2b(b) << 16); }

// ------------------------------------------------- all input/weight converts
__global__ void cvtall_k(const float* __restrict__ xs, const float* __restrict__ xt,
                         const float* __restrict__ wl,
                         const float* __restrict__ esw1, const float* __restrict__ esw2,
                         const float* __restrict__ etw1, const float* __restrict__ etw2,
                         ushort* __restrict__ xsB, ushort* __restrict__ xtB,
                         ushort* __restrict__ wlB, ushort* __restrict__ esw1B,
                         ushort* __restrict__ esw2B, ushort* __restrict__ etw1B,
                         ushort* __restrict__ etw2B) {
  int i = blockIdx.x * 256 + threadIdx.x;
  if (i < 3200000) { xsB[i] = f2b(xs[i]); return; }
  i -= 3200000;
  if (i < 3200000) {
    int r = i >> 6, k = i & 63;
    xtB[i] = (k < 48) ? f2b(xt[(size_t)r * 48 + k]) : (ushort)0;
    return;
  }
  i -= 3200000;
  if (i < 196608) { wlB[i] = f2b(wl[i]); return; }
  i -= 196608;
  if (i < 8192) { esw1B[i] = f2b(esw1[i]); return; }
  i -= 8192;
  if (i < 16384) { esw2B[i] = f2b(esw2[i]); return; }
  i -= 16384;
  if (i < 8192) {
    int r = i >> 6, k = i & 63;
    etw1B[i] = (k < 48) ? f2b(etw1[(size_t)r * 48 + k]) : (ushort)0;
    return;
  }
  i -= 8192;
  if (i < 16384) { etw2B[i] = f2b(etw2[i]); return; }
}

// ------------------------------------------------- combined wr + bias
__global__ void wrc_k(const float* __restrict__ wr, const float* __restrict__ bl,
                      ushort* __restrict__ wrcB, float* __restrict__ blc) {
  int z = blockIdx.y;
  int l = z >> 1, dd = z & 1;
  int r1 = dd ? 1 : 0, r2 = dd ? 2 : 3;
  int idx = blockIdx.x * 256 + threadIdx.x;
  if (idx < 16384) {
    wrcB[(size_t)z * 16384 + idx] =
        f2b(wr[(size_t)(l * 4 + r1) * 16384 + idx] + wr[(size_t)(l * 4 + r2) * 16384 + idx]);
    if (idx < 128)
      blc[z * 128 + idx] = bl[(l * 4 + r1) * 128 + idx] + bl[(l * 4 + r2) * 128 + idx];
  }
}

// ------------------------------------------------- head weight assembly
__global__ void headw_k(const float* __restrict__ gw1, const float* __restrict__ mw1,
                        const float* __restrict__ mw2, const float* __restrict__ gb1,
                        const float* __restrict__ mb1,
                        ushort* __restrict__ Whead, float* __restrict__ biasHead,
                        ushort* __restrict__ w1eB, ushort* __restrict__ w2B) {
  int idx = blockIdx.x * 256 + threadIdx.x;
  if (idx < 65536) {
    int z = idx >> 15, rr = (idx >> 7) & 255, c = idx & 127;
    float v = (rr < 128) ? gw1[(size_t)rr * 256 + z * 128 + c]
                         : mw1[(size_t)(rr - 128) * 160 + c];
    Whead[idx] = f2b(v);
  } else if (idx < 69632) {
    int i = idx - 65536;
    w1eB[i] = f2b(mw1[(size_t)(i >> 5) * 160 + 128 + (i & 31)]);
  } else if (idx < 77824) {
    int i = idx - 69632;
    w2B[i] = f2b(mw2[i]);
  } else if (idx < 78336) {
    int i = idx - 77824;
    int z = i >> 8, n = i & 255;
    biasHead[i] = (n < 128) ? (z ? 0.f : gb1[n]) : mb1[n - 128];
  }
}

// --------------------------------------------------------------- CSR build
__global__ void count4_k(const int* __restrict__ e0, const int* __restrict__ e1,
                         const int* __restrict__ e2, const int* __restrict__ e3,
                         int* __restrict__ cnt) {
  int rel = blockIdx.y;
  const int* col = (rel == 0 ? e0 : rel == 1 ? e1 : rel == 2 ? e2 : e3) + EE;
  int i = blockIdx.x * 256 + threadIdx.x;
  if (i < EE) atomicAdd(&cnt[rel * 50000 + col[i]], 1);
}

// hierarchical scan: A = per-block (2048-chunk) local inclusive scan + totals
__global__ __launch_bounds__(256) void scanA_k(const int* __restrict__ cnt,
                                               int* __restrict__ loc,
                                               int* __restrict__ bsum) {
  __shared__ int ws[4];
  int rel = blockIdx.y, b = blockIdx.x, t = threadIdx.x;
  const int* c = cnt + (size_t)rel * 50000;
  int base = b * 2048 + t * 8;
  int v[8], s = 0;
  #pragma unroll
  for (int i = 0; i < 8; ++i) {
    int idx = base + i;
    v[i] = (idx < 50000) ? c[idx] : 0;
    s += v[i];
  }
  int lane = t & 63, w = t >> 6;
  int x = s;
  #pragma unroll
  for (int d = 1; d < 64; d <<= 1) {
    int y = __shfl_up(x, d, 64);
    if (lane >= d) x += y;
  }
  if (lane == 63) ws[w] = x;
  __syncthreads();
  int add = 0;
  for (int ww = 0; ww < w; ++ww) add += ws[ww];
  int run = add + x - s;   // exclusive prefix for this thread
  #pragma unroll
  for (int i = 0; i < 8; ++i) {
    int idx = base + i;
    run += v[i];
    if (idx < 50000) loc[(size_t)rel * 50000 + idx] = run;
  }
  if (t == 255) bsum[rel * 25 + b] = add + x;
}
__global__ void scanB_k(int* __restrict__ bsum) {
  int t = threadIdx.x;
  if (t < 4) {
    int s = 0;
    for (int b = 0; b < 25; ++b) {
      int v = bsum[t * 25 + b];
      bsum[t * 25 + b] = s;
      s += v;
    }
  }
}
__global__ void scanC_k(const int* __restrict__ cnt, int* __restrict__ loc,
                        const int* __restrict__ bsum, int* __restrict__ off,
                        int* __restrict__ cur) {
  int rel = blockIdx.y;
  int i = blockIdx.x * 256 + threadIdx.x;
  if (i < 50000) {
    int incl = loc[(size_t)rel * 50000 + i] + bsum[rel * 25 + i / 2048];
    off[(size_t)rel * 50001 + i + 1] = incl;
    cur[(size_t)rel * 50000 + i] = incl - cnt[(size_t)rel * 50000 + i];
    if (i == 0) off[(size_t)rel * 50001] = 0;
  }
}

// range-partitioned fill: pass p owns cols [p*PRNG, (p+1)*PRNG) -> adj region L2-resident
__global__ void fillP_k(const int* __restrict__ e0, const int* __restrict__ e1,
                        const int* __restrict__ e2, const int* __restrict__ e3,
                        int* __restrict__ cur, int* __restrict__ adj, int pass) {
  int rel = blockIdx.y;
  const int* ei = rel == 0 ? e0 : rel == 1 ? e1 : rel == 2 ? e2 : e3;
  int e = blockIdx.x * 256 + threadIdx.x;
  if (e < EE) {
    int c = ei[EE + e];
    if (c >= pass * PRNG && c < (pass + 1) * PRNG) {
      int pos = atomicAdd(&cur[rel * 50000 + c], 1);
      adj[(size_t)rel * EE + pos] = ei[e];
    }
  }
}

// ------------------------------------------------------------- gather-mean
// one wave per node; 4 groups of 16 lanes, each group pulls whole 256B rows
__global__ __launch_bounds__(256) void gather4_k(
    const ushort* __restrict__ hs, const ushort* __restrict__ ht,
    const int* __restrict__ off4, const int* __restrict__ adj4,
    ushort* __restrict__ m0, ushort* __restrict__ m1,
    ushort* __restrict__ m2, ushort* __restrict__ m3, int N) {
  int r = blockIdx.y;
  const ushort* src = (r == 0 || r == 2) ? hs : ht;
  ushort* dst = r == 0 ? m0 : (r == 1 ? m1 : (r == 2 ? m2 : m3));
  const int* off = off4 + r * 50001;
  const int* adj = adj4 + (size_t)r * EE;
  int t = threadIdx.x;
  int n = blockIdx.x * 4 + (t >> 6);
  if (n >= N) return;
  int lane = t & 63, g = lane >> 4, i = lane & 15;
  int s = off[n], e = off[n + 1];
  float a[8] = {};
  for (int k = s + g; k < e; k += 4) {
    int row = adj[k];
    uint4 v = *(const uint4*)(src + (size_t)row * 128 + i * 8);
    a[0] += blo(v.x); a[1] += bhi(v.x);
    a[2] += blo(v.y); a[3] += bhi(v.y);
    a[4] += blo(v.z); a[5] += bhi(v.z);
    a[6] += blo(v.w); a[7] += bhi(v.w);
  }
  #pragma unroll
  for (int c = 0; c < 8; ++c) {
    a[c] += __shfl_xor(a[c], 16, 64);
    a[c] += __shfl_xor(a[c], 32, 64);
  }
  if (g == 0) {
    float inv = 1.f / (float)max(e - s, 1);
    uint4 o;
    o.x = pk2(a[0] * inv, a[1] * inv);
    o.y = pk2(a[2] * inv, a[3] * inv);
    o.z = pk2(a[4] * inv, a[5] * inv);
    o.w = pk2(a[6] * inv, a[7] * inv);
    *(uint4*)(dst + (size_t)n * 128 + i * 8) = o;
  }
}

// ------------------------------------------------------- shared GEMM body
template <int MODE>
__device__ __forceinline__ void gemm_body(
    ushort (*As)[40], ushort (*Ws)[40],
    const ushort* __restrict__ A, const ushort* __restrict__ W,
    const float* __restrict__ bias, ushort* __restrict__ C,
    int M, int K, int ldc, int m0) {
  int t = threadIdx.x;
  int lane = t & 63, w = t >> 6, wm = w >> 1, wn = w & 1;
  f32x4 zz = {0.f, 0.f, 0.f, 0.f};
  f32x4 acc[4][4];
  #pragma unroll
  for (int i = 0; i < 4; ++i)
    #pragma unroll
    for (int j = 0; j < 4; ++j) acc[i][j] = zz;
  for (int kb = 0; kb < K; kb += 32) {
    #pragma unroll
    for (int s = 0; s < 2; ++s) {
      int idx = t + s * 256;
      int r = idx >> 2, c = idx & 3;
      int gm = m0 + r;
      uint4 va = make_uint4(0, 0, 0, 0);
      if (gm < M) va = *(const uint4*)(A + (size_t)gm * K + kb + c * 8);
      *(uint4*)&As[r][c * 8] = va;
      *(uint4*)&Ws[r][c * 8] = *(const uint4*)(W + (size_t)r * K + kb + c * 8);
    }
    __syncthreads();
    short8 af[4], bf[4];
    #pragma unroll
    for (int mf = 0; mf < 4; ++mf)
      af[mf] = *(const short8*)&As[wm * 64 + mf * 16 + (lane & 15)][(lane >> 4) * 8];
    #pragma unroll
    for (int nf = 0; nf < 4; ++nf)
      bf[nf] = *(const short8*)&Ws[wn * 64 + nf * 16 + (lane & 15)][(lane >> 4) * 8];
    #pragma unroll
    for (int mf = 0; mf < 4; ++mf)
      #pragma unroll
      for (int nf = 0; nf < 4; ++nf) acc[mf][nf] = MFMA16(af[mf], bf[nf], acc[mf][nf]);
    __syncthreads();
  }
  int r0 = (lane >> 4) * 4, nin = lane & 15;
  #pragma unroll
  for (int mf = 0; mf < 4; ++mf)
    #pragma unroll
    for (int nf = 0; nf < 4; ++nf) {
      int n = wn * 64 + nf * 16 + nin;
      float bv = bias ? bias[n] : 0.f;
      #pragma unroll
      for (int i = 0; i < 4; ++i) {
        int gm = m0 + wm * 64 + mf * 16 + r0 + i;
        if (gm >= M) continue;
        float v = acc[mf][nf][i] + bv;
        if (MODE == 1) v = fmaxf(v, 0.f);
        C[(size_t)gm * ldc + n] = f2b(v);
      }
    }
}

// encoder stage (grid.y picks source/target config)
template <int MODE>
__global__ __launch_bounds__(256) void enc_k(
    const ushort* A0, const ushort* A1, const ushort* W0, const ushort* W1,
    const float* b0, const float* b1, ushort* C0, ushort* C1, int M, int K) {
  __shared__ alignas(16) ushort As[128][40];
  __shared__ alignas(16) ushort Ws[128][40];
  int y = blockIdx.y;
  gemm_body<MODE>(As, Ws, y ? A1 : A0, y ? W1 : W0, y ? b1 : b0, y ? C1 : C0,
                  M, K, 128, blockIdx.x * 128);
}

// head precompute: z = node set (S/T), ny = N-tile of 256-wide output
__global__ __launch_bounds__(256) void gemmH_k(
    const ushort* Abase, const ushort* Whead, const float* biasHead,
    ushort* pS, ushort* pT) {
  __shared__ alignas(16) ushort As[128][40];
  __shared__ alignas(16) ushort Ws[128][40];
  int z = blockIdx.z, ny = blockIdx.y;
  gemm_body<0>(As, Ws, Abase + (size_t)z * NBE,
               Whead + ((size_t)z * 256 + ny * 128) * 128,
               biasHead + z * 256 + ny * 128,
               (z ? pT : pS) + ny * 128,
               NSN, 128, 256, blockIdx.x * 128);
}

// ---------------------------------- layer GEMM: 3 A-panels, both dst types
template <int RES>
__global__ __launch_bounds__(256) void lgemm_k(
    const ushort* __restrict__ hs, const ushort* __restrict__ ht,
    const ushort* __restrict__ m0, const ushort* __restrict__ m1,
    const ushort* __restrict__ m2, const ushort* __restrict__ m3,
    const ushort* __restrict__ wlL, const ushort* __restrict__ wrcL,
    const float* __restrict__ blcL,
    ushort* __restrict__ hsOut, ushort* __restrict__ htOut, int M) {
  __shared__ alignas(16) ushort As[128][40];
  __shared__ alignas(16) ushort Ws[128][40];
  int t = threadIdx.x;
  int y = blockIdx.y;
  int m0i = blockIdx.x * 128;
  const ushort* A0 = y ? m1 : m0;
  const ushort* A1 = y ? m2 : m3;
  const ushort* self = y ? ht : hs;
  const ushort* W0 = wlL + (size_t)(y ? 1 : 0) * 16384;
  const ushort* W1 = wlL + (size_t)(y ? 2 : 3) * 16384;
  const ushort* W2 = wrcL + (size_t)y * 16384;
  const float* bias = blcL + y * 128;
  ushort* C = y ? htOut : hsOut;

  int lane = t & 63, w = t >> 6, wm = w >> 1, wn = w & 1;
  f32x4 zz = {0.f, 0.f, 0.f, 0.f};
  f32x4 acc[4][4];
  #pragma unroll
  for (int i = 0; i < 4; ++i)
    #pragma unroll
    for (int j = 0; j < 4; ++j) acc[i][j] = zz;
  for (int p = 0; p < 3; ++p) {
    const ushort* A = p == 0 ? A0 : (p == 1 ? A1 : self);
    const ushort* Wp = p == 0 ? W0 : (p == 1 ? W1 : W2);
    for (int kb = 0; kb < 128; kb += 32) {
      #pragma unroll
      for (int s = 0; s < 2; ++s) {
        int idx = t + s * 256;
        int r = idx >> 2, c = idx & 3;
        int gm = m0i + r;
        uint4 va = make_uint4(0, 0, 0, 0);
        if (gm < M) va = *(const uint4*)(A + (size_t)gm * 128 + kb + c * 8);
        *(uint4*)&As[r][c * 8] = va;
        *(uint4*)&Ws[r][c * 8] = *(const uint4*)(Wp + (size_t)r * 128 + kb + c * 8);
      }
      __syncthreads();
      short8 af[4], bf[4];
      #pragma unroll
      for (int mf = 0; mf < 4; ++mf)
        af[mf] = *(const short8*)&As[wm * 64 + mf * 16 + (lane & 15)][(lane >> 4) * 8];
      #pragma unroll
      for (int nf = 0; nf < 4; ++nf)
        bf[nf] = *(const short8*)&Ws[wn * 64 + nf * 16 + (lane & 15)][(lane >> 4) * 8];
      #pragma unroll
      for (int mf = 0; mf < 4; ++mf)
        #pragma unroll
        for (int nf = 0; nf < 4; ++nf) acc[mf][nf] = MFMA16(af[mf], bf[nf], acc[mf][nf]);
      __syncthreads();
    }
  }
  int r0 = (lane >> 4) * 4, nin = lane & 15;
  #pragma unroll
  for (int mf = 0; mf < 4; ++mf)
    #pragma unroll
    for (int nf = 0; nf < 4; ++nf) {
      int n = wn * 64 + nf * 16 + nin;
      float bv = bias[n];
      #pragma unroll
      for (int i = 0; i < 4; ++i) {
        int gm = m0i + wm * 64 + mf * 16 + r0 + i;
        if (gm >= M) continue;
        float v = 0.5f * (acc[mf][nf][i] + bv);
        if (RES) v += b2f(self[(size_t)gm * 128 + n]);
        C[(size_t)gm * 128 + n] = f2b(fmaxf(v, 0.f));
      }
    }
}

// ---------------------------------------------------------------- edge head
// LDS-lean: eat written into h1s (fragment layout), G does in-place combine,
// h2F aliases h1s after phase-H fragment reads. ~19 KB LDS -> 7-8 blocks/CU.
__global__ __launch_bounds__(256) void head_k(
    const ushort* __restrict__ pS, const ushort* __restrict__ pT,
    const int* __restrict__ ei, const float* __restrict__ ea,
    const ushort* __restrict__ w1eB, const ushort* __restrict__ w2B,
    const float* __restrict__ gw2, const float* __restrict__ gb2p,
    const float* __restrict__ mb2, const float* __restrict__ mw3,
    const float* __restrict__ mb3, float* __restrict__ out, int E) {
  __shared__ alignas(16) ushort h1s[64][136];    // eat -> h1 -> (aliased) h2F
  __shared__ int er[64], ec[64];
  __shared__ alignas(16) float gw2s[128];
  __shared__ alignas(16) float mw3s[128];
  __shared__ float mb2s[64];
  float (*h2F)[68] = (float(*)[68])&h1s[0][0];   // 64x68 f32 == 64x136 ush

  int t = threadIdx.x;
  int e0 = blockIdx.x * 64;
  if (t < 64) {
    int eg = e0 + t;
    er[t] = (eg < E) ? ei[eg] : 0;
    mb2s[t] = mb2[t];
  } else if (t < 128) {
    int q = t - 64;
    int eg = e0 + q;
    ec[q] = (eg < E) ? ei[E + eg] : 0;
  }
  if (t < 128) gw2s[t] = gw2[t];
  else mw3s[t - 128] = mw3[t - 128];
  __syncthreads();
  int lane = t & 63, w = t >> 6;
  // Phase E: eat = ea @ w1e^T (M=64, N=128, K=32) -> h1s (no bias/relu yet)
  {
    int erow = e0 + w * 16 + (lane & 15);
    float4 f0 = make_float4(0, 0, 0, 0), f1 = make_float4(0, 0, 0, 0);
    if (erow < E) {
      f0 = *(const float4*)(ea + (size_t)erow * 32 + (lane >> 4) * 8);
      f1 = *(const float4*)(ea + (size_t)erow * 32 + (lane >> 4) * 8 + 4);
    }
    union { short8 s; uint4 u; } cv;
    cv.u = make_uint4(pk2(f0.x, f0.y), pk2(f0.z, f0.w), pk2(f1.x, f1.y), pk2(f1.z, f1.w));
    short8 a = cv.s;
    int ebase = w * 16 + (lane >> 4) * 4;
    #pragma unroll
    for (int nf = 0; nf < 8; ++nf) {
      short8 b = *(const short8*)(w1eB + (size_t)(nf * 16 + (lane & 15)) * 32 + (lane >> 4) * 8);
      f32x4 cz = {0.f, 0.f, 0.f, 0.f};
      cz = MFMA16(a, b, cz);
      int jj = nf * 16 + (lane & 15);
      #pragma unroll
      for (int i = 0; i < 4; ++i) h1s[ebase + i][jj] = f2b(cz[i]);
    }
  }
  __syncthreads();
  // Phase G: gate + convex combine + eat (in-place RMW) + relu -> h1s
  {
    int el = lane >> 2, q = lane & 3, e = w * 16 + el;
    int j0 = q * 32;
    const ushort* ps = pS + (size_t)er[e] * 256;
    const ushort* pt = pT + (size_t)ec[e] * 256;
    float dot = 0.f;
    #pragma unroll
    for (int cc = 0; cc < 4; ++cc) {
      int j = j0 + cc * 8;
      uint4 ga = *(const uint4*)(ps + j);
      uint4 gb = *(const uint4*)(pt + j);
      const float* gp = &gw2s[j];
      float h;
      h = fmaxf(blo(ga.x) + blo(gb.x), 0.f); dot = fmaf(h, gp[0], dot);
      h = fmaxf(bhi(ga.x) + bhi(gb.x), 0.f); dot = fmaf(h, gp[1], dot);
      h = fmaxf(blo(ga.y) + blo(gb.y), 0.f); dot = fmaf(h, gp[2], dot);
      h = fmaxf(bhi(ga.y) + bhi(gb.y), 0.f); dot = fmaf(h, gp[3], dot);
      h = fmaxf(blo(ga.z) + blo(gb.z), 0.f); dot = fmaf(h, gp[4], dot);
      h = fmaxf(bhi(ga.z) + bhi(gb.z), 0.f); dot = fmaf(h, gp[5], dot);
      h = fmaxf(blo(ga.w) + blo(gb.w), 0.f); dot = fmaf(h, gp[6], dot);
      h = fmaxf(bhi(ga.w) + bhi(gb.w), 0.f); dot = fmaf(h, gp[7], dot);
    }
    dot += __shfl_xor(dot, 1, 64);
    dot += __shfl_xor(dot, 2, 64);
    float g = 1.f / (1.f + __expf(-(dot + gb2p[0])));
    float om = 1.f - g;
    #pragma unroll
    for (int cc = 0; cc < 4; ++cc) {
      int j = j0 + cc * 8;
      uint4 uu = *(const uint4*)(ps + 128 + j);
      uint4 vv = *(const uint4*)(pt + 128 + j);
      uint4 ee = *(const uint4*)&h1s[e][j];
      uint o0 = pk2(fmaxf(fmaf(g, blo(uu.x), om * blo(vv.x)) + blo(ee.x), 0.f),
                    fmaxf(fmaf(g, bhi(uu.x), om * bhi(vv.x)) + bhi(ee.x), 0.f));
      uint o1 = pk2(fmaxf(fmaf(g, blo(uu.y), om * blo(vv.y)) + blo(ee.y), 0.f),
                    fmaxf(fmaf(g, bhi(uu.y), om * bhi(vv.y)) + bhi(ee.y), 0.f));
      uint o2 = pk2(fmaxf(fmaf(g, blo(uu.z), om * blo(vv.z)) + blo(ee.z), 0.f),
                    fmaxf(fmaf(g, bhi(uu.z), om * bhi(vv.z)) + bhi(ee.z), 0.f));
      uint o3 = pk2(fmaxf(fmaf(g, blo(uu.w), om * blo(vv.w)) + blo(ee.w), 0.f),
                    fmaxf(fmaf(g, bhi(uu.w), om * bhi(vv.w)) + bhi(ee.w), 0.f));
      *(uint4*)&h1s[e][j] = make_uint4(o0, o1, o2, o3);
    }
  }
  __syncthreads();
  // Phase H: h2 = relu(h1 @ w2^T + b2)  (M=64, N=64, K=128)
  {
    f32x4 zz = {0.f, 0.f, 0.f, 0.f};
    f32x4 acc[4] = {zz, zz, zz, zz};
    #pragma unroll
    for (int ks = 0; ks < 4; ++ks) {
      short8 a = *(const short8*)&h1s[w * 16 + (lane & 15)][ks * 32 + (lane >> 4) * 8];
      #pragma unroll
      for (int nf = 0; nf < 4; ++nf) {
        short8 b = *(const short8*)(w2B + (size_t)(nf * 16 + (lane & 15)) * 128 + ks * 32 + (lane >> 4) * 8);
        acc[nf] = MFMA16(a, b, acc[nf]);
      }
    }
    __syncthreads();   // h1s dead; h2F aliases it
    int ebase = w * 16 + (lane >> 4) * 4;
    #pragma unroll
    for (int nf = 0; nf < 4; ++nf) {
      int n = nf * 16 + (lane & 15);
      #pragma unroll
      for (int i = 0; i < 4; ++i)
        h2F[ebase + i][n] = fmaxf(acc[nf][i] + mb2s[n], 0.f);
    }
  }
  __syncthreads();
  // Phase O: out = h2 @ mw3^T + b3
  if (t < 128) {
    int e = t >> 1, o = t & 1;
    int eg = e0 + e;
    if (eg < E) {
      float s = mb3[o];
      #pragma unroll
      for (int kk = 0; kk < 64; kk += 4) {
        float4 hv = *(const float4*)&h2F[e][kk];
        float4 wv = *(const float4*)&mw3s[o * 64 + kk];
        s = fmaf(hv.x, wv.x, s); s = fmaf(hv.y, wv.y, s);
        s = fmaf(hv.z, wv.z, s); s = fmaf(hv.w, wv.w, s);
      }
      out[(size_t)eg * 2 + o] = s;
    }
  }
}

// ------------------------------------------------------------------- launch
extern "C" void kernel_launch(void* const* d_in, const int* in_sizes, int n_in,
                              void* d_out, int out_size, void* d_ws, size_t ws_size,
                              hipStream_t stream) {
  const float* x_source = (const float*)d_in[0];
  const float* x_target = (const float*)d_in[1];
  const float* edge_attr = (const float*)d_in[2];
  const float* enc_s_w1 = (const float*)d_in[3];
  const float* enc_s_b1 = (const float*)d_in[4];
  const float* enc_s_w2 = (const float*)d_in[5];
  const float* enc_s_b2 = (const float*)d_in[6];
  const float* enc_t_w1 = (const float*)d_in[7];
  const float* enc_t_b1 = (const float*)d_in[8];
  const float* enc_t_w2 = (const float*)d_in[9];
  const float* enc_t_b2 = (const float*)d_in[10];
  const float* conv_wl = (const float*)d_in[11];
  const float* conv_bl = (const float*)d_in[12];
  const float* conv_wr = (const float*)d_in[13];
  const float* gate_w1 = (const float*)d_in[14];
  const float* gate_b1 = (const float*)d_in[15];
  const float* gate_w2 = (const float*)d_in[16];
  const float* gate_b2 = (const float*)d_in[17];
  const float* mlp_w1 = (const float*)d_in[18];
  const float* mlp_b1 = (const float*)d_in[19];
  const float* mlp_w2 = (const float*)d_in[20];
  const float* mlp_b2 = (const float*)d_in[21];
  const float* mlp_w3 = (const float*)d_in[22];
  const float* mlp_b3 = (const float*)d_in[23];
  const int* ei[4] = {(const int*)d_in[24], (const int*)d_in[25],
                      (const int*)d_in[26], (const int*)d_in[27]};  // 0=ss,1=tt,2=st,3=ts
  float* out = (float*)d_out;

  char* wsp = (char*)d_ws;
  size_t off = 0;
  auto alloc = [&](size_t bytes) {
    char* p = wsp + off;
    off += (bytes + 255) & ~(size_t)255;
    return p;
  };
  ushort* nbase = (ushort*)alloc(4 * NBE * 2);   // 4 rotating node buffers
  ushort* nb[4];
  for (int i = 0; i < 4; ++i) nb[i] = nbase + (size_t)i * NBE;
  ushort* shared4 = (ushort*)alloc(4 * NBE * 2); // means m0..m3 / later pS,pT
  ushort* mB[4];
  for (int i = 0; i < 4; ++i) mB[i] = shared4 + (size_t)i * NBE;
  int* adj4 = (int*)alloc((size_t)4 * EE * 4);
  int* off4 = (int*)alloc(4 * 50001 * 4);
  int* cur4 = (int*)alloc(4 * 50000 * 4);
  int* cnt4 = (int*)alloc(4 * 50000 * 4);
  int* bsum = (int*)alloc(128 * 4);
  ushort* xsB = (ushort*)alloc((size_t)NSN * 64 * 2);
  ushort* xtB = (ushort*)alloc((size_t)NTN * 64 * 2);
  ushort* esw1B = (ushort*)alloc(128 * 64 * 2);
  ushort* esw2B = (ushort*)alloc(128 * 128 * 2);
  ushort* etw1B = (ushort*)alloc(128 * 64 * 2);
  ushort* etw2B = (ushort*)alloc(128 * 128 * 2);
  ushort* wlB = (ushort*)alloc((size_t)12 * 16384 * 2);
  ushort* wrcB = (ushort*)alloc((size_t)6 * 16384 * 2);
  float* blc = (float*)alloc(6 * 128 * 4);
  ushort* Whead = (ushort*)alloc((size_t)2 * 256 * 128 * 2);
  float* biasHead = (float*)alloc(2 * 256 * 4);
  ushort* w1eB = (ushort*)alloc(128 * 32 * 2);
  ushort* w2B = (ushort*)alloc(64 * 128 * 2);

  // --- CSR build: count -> hierarchical scan -> range-partitioned fill ---
  hipMemsetAsync(cnt4, 0, 4 * 50000 * sizeof(int), stream);
  int cb = (EE + 255) / 256;
  count4_k<<<dim3(cb, 4), 256, 0, stream>>>(ei[0], ei[1], ei[2], ei[3], cnt4);
  scanA_k<<<dim3(25, 4), 256, 0, stream>>>(cnt4, cur4, bsum);
  scanB_k<<<1, 64, 0, stream>>>(bsum);
  scanC_k<<<dim3((50000 + 255) / 256, 4), 256, 0, stream>>>(cnt4, cur4, bsum, off4, cur4);
  for (int p = 0; p < NPASS; ++p)
    fillP_k<<<dim3(cb, 4), 256, 0, stream>>>(ei[0], ei[1], ei[2], ei[3], cur4, adj4, p);

  // --- conversions / weight assembly ---
  cvtall_k<<<(6645760 + 255) / 256, 256, 0, stream>>>(
      x_source, x_target, conv_wl, enc_s_w1, enc_s_w2, enc_t_w1, enc_t_w2,
      xsB, xtB, wlB, esw1B, esw2B, etw1B, etw2B);
  wrc_k<<<dim3(64, 6), 256, 0, stream>>>(conv_wr, conv_bl, wrcB, blc);
  headw_k<<<307, 256, 0, stream>>>(gate_w1, mlp_w1, mlp_w2, gate_b1, mlp_b1,
                                   Whead, biasHead, w1eB, w2B);

  // --- encoders: (xs,xt) -> nb2,nb3 (tmp) -> nb0,nb1 ---
  int gm = (NSN + 127) / 128;
  enc_k<1><<<dim3(gm, 2), 256, 0, stream>>>(xsB, xtB, esw1B, etw1B,
      enc_s_b1, enc_t_b1, nb[2], nb[3], NSN, 64);
  enc_k<0><<<dim3(gm, 2), 256, 0, stream>>>(nb[2], nb[3], esw2B, etw2B,
      enc_s_b2, enc_t_b2, nb[0], nb[1], NSN, 128);

  // --- 3 hetero layers: (0,1)->(2,3)->(0,1)->(2,3) ---
  int gb = (NSN + 3) / 4;
  {
    gather4_k<<<dim3(gb, 4), 256, 0, stream>>>(nb[0], nb[1], off4, adj4,
        mB[0], mB[1], mB[2], mB[3], NSN);
    lgemm_k<0><<<dim3(gm, 2), 256, 0, stream>>>(nb[0], nb[1],
        mB[0], mB[1], mB[2], mB[3], wlB, wrcB, blc, nb[2], nb[3], NSN);
    gather4_k<<<dim3(gb, 4), 256, 0, stream>>>(nb[2], nb[3], off4, adj4,
        mB[0], mB[1], mB[2], mB[3], NSN);
    lgemm_k<1><<<dim3(gm, 2), 256, 0, stream>>>(nb[2], nb[3],
        mB[0], mB[1], mB[2], mB[3], wlB + (size_t)4 * 16384,
        wrcB + (size_t)2 * 16384, blc + 256, nb[0], nb[1], NSN);
    gather4_k<<<dim3(gb, 4), 256, 0, stream>>>(nb[0], nb[1], off4, adj4,
        mB[0], mB[1], mB[2], mB[3], NSN);
    lgemm_k<1><<<dim3(gm, 2), 256, 0, stream>>>(nb[0], nb[1],
        mB[0], mB[1], mB[2], mB[3], wlB + (size_t)8 * 16384,
        wrcB + (size_t)4 * 16384, blc + 512, nb[2], nb[3], NSN);
  }
  // h3s = nb2, h3t = nb3

  // --- nodewise head precompute: pS/pT overlay the (dead) mean region ---
  ushort* pS = shared4;
  ushort* pT = shared4 + 2 * NBE;
  gemmH_k<<<dim3(gm, 2, 2), 256, 0, stream>>>(nbase + 2 * NBE, Whead, biasHead, pS, pT);

  // --- fused edge head ---
  head_k<<<(EE + 63) / 64, 256, 0, stream>>>(pS, pT, ei[2], edge_attr, w1eB, w2B,
      gate_w2, gate_b2, mlp_b2, mlp_w3, mlp_b3, out, EE);
}

// Round 7
// 834.838 us; speedup vs baseline: 1.6549x; 1.0103x over previous
//
#include <hip/hip_runtime.h>
#include <cmath>

#define NSN 50000
#define NTN 50000
#define EE  500000
#define NBE ((size_t)NSN * 128)
#define NPASS 4
#define PRNG 12500

using short8 = __attribute__((ext_vector_type(8))) short;
using f32x4  = __attribute__((ext_vector_type(4))) float;
#define MFMA16(a, b, c) __builtin_amdgcn_mfma_f32_16x16x32_bf16(a, b, c, 0, 0, 0)

__device__ __forceinline__ float  b2f(ushort u) { return __uint_as_float(((uint)u) << 16); }
__device__ __forceinline__ ushort f2b(float f) {
  uint x = __float_as_uint(f);
  uint r = x + 0x7FFFu + ((x >> 16) & 1u);
  return (ushort)(r >> 16);
}
__device__ __forceinline__ float blo(uint x) { return __uint_as_float(x << 16); }
__device__ __forceinline__ float bhi(uint x) { return __uint_as_float(x & 0xFFFF0000u); }
__device__ __forceinline__ uint  pk2(float a, float b) { return (uint)f2b(a) | ((uint)f2b(b) << 16); }

// ------------------------------------------------- all input/weight converts
__global__ void cvtall_k(const float* __restrict__ xs, const float* __restrict__ xt,
                         const float* __restrict__ wl,
                         const float* __restrict__ esw1, const float* __restrict__ esw2,
                         const float* __restrict__ etw1, const float* __restrict__ etw2,
                         ushort* __restrict__ xsB, ushort* __restrict__ xtB,
                         ushort* __restrict__ wlB, ushort* __restrict__ esw1B,
                         ushort* __restrict__ esw2B, ushort* __restrict__ etw1B,
                         ushort* __restrict__ etw2B) {
  int i = blockIdx.x * 256 + threadIdx.x;
  if (i < 3200000) { xsB[i] = f2b(xs[i]); return; }
  i -= 3200000;
  if (i < 3200000) {
    int r = i >> 6, k = i & 63;
    xtB[i] = (k < 48) ? f2b(xt[(size_t)r * 48 + k]) : (ushort)0;
    return;
  }
  i -= 3200000;
  if (i < 196608) { wlB[i] = f2b(wl[i]); return; }
  i -= 196608;
  if (i < 8192) { esw1B[i] = f2b(esw1[i]); return; }
  i -= 8192;
  if (i < 16384) { esw2B[i] = f2b(esw2[i]); return; }
  i -= 16384;
  if (i < 8192) {
    int r = i >> 6, k = i & 63;
    etw1B[i] = (k < 48) ? f2b(etw1[(size_t)r * 48 + k]) : (ushort)0;
    return;
  }
  i -= 8192;
  if (i < 16384) { etw2B[i] = f2b(etw2[i]); return; }
}

// ------------------------------------------------- combined wr + bias
__global__ void wrc_k(const float* __restrict__ wr, const float* __restrict__ bl,
                      ushort* __restrict__ wrcB, float* __restrict__ blc) {
  int z = blockIdx.y;
  int l = z >> 1, dd = z & 1;
  int r1 = dd ? 1 : 0, r2 = dd ? 2 : 3;
  int idx = blockIdx.x * 256 + threadIdx.x;
  if (idx < 16384) {
    wrcB[(size_t)z * 16384 + idx] =
        f2b(wr[(size_t)(l * 4 + r1) * 16384 + idx] + wr[(size_t)(l * 4 + r2) * 16384 + idx]);
    if (idx < 128)
      blc[z * 128 + idx] = bl[(l * 4 + r1) * 128 + idx] + bl[(l * 4 + r2) * 128 + idx];
  }
}

// ------------------------------------------------- head weight assembly
__global__ void headw_k(const float* __restrict__ gw1, const float* __restrict__ mw1,
                        const float* __restrict__ mw2, const float* __restrict__ gb1,
                        const float* __restrict__ mb1,
                        ushort* __restrict__ Whead, float* __restrict__ biasHead,
                        ushort* __restrict__ w1eB, ushort* __restrict__ w2B) {
  int idx = blockIdx.x * 256 + threadIdx.x;
  if (idx < 65536) {
    int z = idx >> 15, rr = (idx >> 7) & 255, c = idx & 127;
    float v = (rr < 128) ? gw1[(size_t)rr * 256 + z * 128 + c]
                         : mw1[(size_t)(rr - 128) * 160 + c];
    Whead[idx] = f2b(v);
  } else if (idx < 69632) {
    int i = idx - 65536;
    w1eB[i] = f2b(mw1[(size_t)(i >> 5) * 160 + 128 + (i & 31)]);
  } else if (idx < 77824) {
    int i = idx - 69632;
    w2B[i] = f2b(mw2[i]);
  } else if (idx < 78336) {
    int i = idx - 77824;
    int z = i >> 8, n = i & 255;
    biasHead[i] = (n < 128) ? (z ? 0.f : gb1[n]) : mb1[n - 128];
  }
}

// --------------------------------------------------------------- CSR build
__global__ void count4_k(const int* __restrict__ e0, const int* __restrict__ e1,
                         const int* __restrict__ e2, const int* __restrict__ e3,
                         int* __restrict__ cnt) {
  int rel = blockIdx.y;
  const int* col = (rel == 0 ? e0 : rel == 1 ? e1 : rel == 2 ? e2 : e3) + EE;
  int i = blockIdx.x * 256 + threadIdx.x;
  if (i < EE) atomicAdd(&cnt[rel * 50000 + col[i]], 1);
}

// hierarchical scan
__global__ __launch_bounds__(256) void scanA_k(const int* __restrict__ cnt,
                                               int* __restrict__ loc,
                                               int* __restrict__ bsum) {
  __shared__ int ws[4];
  int rel = blockIdx.y, b = blockIdx.x, t = threadIdx.x;
  const int* c = cnt + (size_t)rel * 50000;
  int base = b * 2048 + t * 8;
  int v[8], s = 0;
  #pragma unroll
  for (int i = 0; i < 8; ++i) {
    int idx = base + i;
    v[i] = (idx < 50000) ? c[idx] : 0;
    s += v[i];
  }
  int lane = t & 63, w = t >> 6;
  int x = s;
  #pragma unroll
  for (int d = 1; d < 64; d <<= 1) {
    int y = __shfl_up(x, d, 64);
    if (lane >= d) x += y;
  }
  if (lane == 63) ws[w] = x;
  __syncthreads();
  int add = 0;
  for (int ww = 0; ww < w; ++ww) add += ws[ww];
  int run = add + x - s;
  #pragma unroll
  for (int i = 0; i < 8; ++i) {
    int idx = base + i;
    run += v[i];
    if (idx < 50000) loc[(size_t)rel * 50000 + idx] = run;
  }
  if (t == 255) bsum[rel * 25 + b] = add + x;
}
__global__ void scanB_k(int* __restrict__ bsum) {
  int t = threadIdx.x;
  if (t < 4) {
    int s = 0;
    for (int b = 0; b < 25; ++b) {
      int v = bsum[t * 25 + b];
      bsum[t * 25 + b] = s;
      s += v;
    }
  }
}
__global__ void scanC_k(const int* __restrict__ cnt, int* __restrict__ loc,
                        const int* __restrict__ bsum, int* __restrict__ off,
                        int* __restrict__ cur) {
  int rel = blockIdx.y;
  int i = blockIdx.x * 256 + threadIdx.x;
  if (i < 50000) {
    int incl = loc[(size_t)rel * 50000 + i] + bsum[rel * 25 + i / 2048];
    off[(size_t)rel * 50001 + i + 1] = incl;
    cur[(size_t)rel * 50000 + i] = incl - cnt[(size_t)rel * 50000 + i];
    if (i == 0) off[(size_t)rel * 50001] = 0;
  }
}

// range-partitioned fill; rel 2 also records original edge id
__global__ void fillP_k(const int* __restrict__ e0, const int* __restrict__ e1,
                        const int* __restrict__ e2, const int* __restrict__ e3,
                        int* __restrict__ cur, int* __restrict__ adj,
                        int* __restrict__ adjE, int pass) {
  int rel = blockIdx.y;
  const int* ei = rel == 0 ? e0 : rel == 1 ? e1 : rel == 2 ? e2 : e3;
  int e = blockIdx.x * 256 + threadIdx.x;
  if (e < EE) {
    int c = ei[EE + e];
    if (c >= pass * PRNG && c < (pass + 1) * PRNG) {
      int pos = atomicAdd(&cur[rel * 50000 + c], 1);
      adj[(size_t)rel * EE + pos] = ei[e];
      if (rel == 2) adjE[pos] = e;
    }
  }
}

// expand rel-2 offsets -> per-position col
__global__ void colof_k(const int* __restrict__ off, int* __restrict__ colOf, int N) {
  int n = blockIdx.x * 256 + threadIdx.x;
  if (n < N) {
    int s = off[n], e = off[n + 1];
    for (int i = s; i < e; ++i) colOf[i] = n;
  }
}

// ------------------------------------------------------------- gather-mean
__global__ __launch_bounds__(256) void gather4_k(
    const ushort* __restrict__ hs, const ushort* __restrict__ ht,
    const int* __restrict__ off4, const int* __restrict__ adj4,
    ushort* __restrict__ m0, ushort* __restrict__ m1,
    ushort* __restrict__ m2, ushort* __restrict__ m3, int N) {
  int r = blockIdx.y;
  const ushort* src = (r == 0 || r == 2) ? hs : ht;
  ushort* dst = r == 0 ? m0 : (r == 1 ? m1 : (r == 2 ? m2 : m3));
  const int* off = off4 + r * 50001;
  const int* adj = adj4 + (size_t)r * EE;
  int t = threadIdx.x;
  int n = blockIdx.x * 4 + (t >> 6);
  if (n >= N) return;
  int lane = t & 63, g = lane >> 4, i = lane & 15;
  int s = off[n], e = off[n + 1];
  float a[8] = {};
  for (int k = s + g; k < e; k += 4) {
    int row = adj[k];
    uint4 v = *(const uint4*)(src + (size_t)row * 128 + i * 8);
    a[0] += blo(v.x); a[1] += bhi(v.x);
    a[2] += blo(v.y); a[3] += bhi(v.y);
    a[4] += blo(v.z); a[5] += bhi(v.z);
    a[6] += blo(v.w); a[7] += bhi(v.w);
  }
  #pragma unroll
  for (int c = 0; c < 8; ++c) {
    a[c] += __shfl_xor(a[c], 16, 64);
    a[c] += __shfl_xor(a[c], 32, 64);
  }
  if (g == 0) {
    float inv = 1.f / (float)max(e - s, 1);
    uint4 o;
    o.x = pk2(a[0] * inv, a[1] * inv);
    o.y = pk2(a[2] * inv, a[3] * inv);
    o.z = pk2(a[4] * inv, a[5] * inv);
    o.w = pk2(a[6] * inv, a[7] * inv);
    *(uint4*)(dst + (size_t)n * 128 + i * 8) = o;
  }
}

// ------------------------------------------------------- shared GEMM body
template <int MODE>
__device__ __forceinline__ void gemm_body(
    ushort (*As)[40], ushort (*Ws)[40],
    const ushort* __restrict__ A, const ushort* __restrict__ W,
    const float* __restrict__ bias, ushort* __restrict__ C,
    int M, int K, int ldc, int m0) {
  int t = threadIdx.x;
  int lane = t & 63, w = t >> 6, wm = w >> 1, wn = w & 1;
  f32x4 zz = {0.f, 0.f, 0.f, 0.f};
  f32x4 acc[4][4];
  #pragma unroll
  for (int i = 0; i < 4; ++i)
    #pragma unroll
    for (int j = 0; j < 4; ++j) acc[i][j] = zz;
  for (int kb = 0; kb < K; kb += 32) {
    #pragma unroll
    for (int s = 0; s < 2; ++s) {
      int idx = t + s * 256;
      int r = idx >> 2, c = idx & 3;
      int gm = m0 + r;
      uint4 va = make_uint4(0, 0, 0, 0);
      if (gm < M) va = *(const uint4*)(A + (size_t)gm * K + kb + c * 8);
      *(uint4*)&As[r][c * 8] = va;
      *(uint4*)&Ws[r][c * 8] = *(const uint4*)(W + (size_t)r * K + kb + c * 8);
    }
    __syncthreads();
    short8 af[4], bf[4];
    #pragma unroll
    for (int mf = 0; mf < 4; ++mf)
      af[mf] = *(const short8*)&As[wm * 64 + mf * 16 + (lane & 15)][(lane >> 4) * 8];
    #pragma unroll
    for (int nf = 0; nf < 4; ++nf)
      bf[nf] = *(const short8*)&Ws[wn * 64 + nf * 16 + (lane & 15)][(lane >> 4) * 8];
    #pragma unroll
    for (int mf = 0; mf < 4; ++mf)
      #pragma unroll
      for (int nf = 0; nf < 4; ++nf) acc[mf][nf] = MFMA16(af[mf], bf[nf], acc[mf][nf]);
    __syncthreads();
  }
  int r0 = (lane >> 4) * 4, nin = lane & 15;
  #pragma unroll
  for (int mf = 0; mf < 4; ++mf)
    #pragma unroll
    for (int nf = 0; nf < 4; ++nf) {
      int n = wn * 64 + nf * 16 + nin;
      float bv = bias ? bias[n] : 0.f;
      #pragma unroll
      for (int i = 0; i < 4; ++i) {
        int gm = m0 + wm * 64 + mf * 16 + r0 + i;
        if (gm >= M) continue;
        float v = acc[mf][nf][i] + bv;
        if (MODE == 1) v = fmaxf(v, 0.f);
        C[(size_t)gm * ldc + n] = f2b(v);
      }
    }
}

template <int MODE>
__global__ __launch_bounds__(256) void enc_k(
    const ushort* A0, const ushort* A1, const ushort* W0, const ushort* W1,
    const float* b0, const float* b1, ushort* C0, ushort* C1, int M, int K) {
  __shared__ alignas(16) ushort As[128][40];
  __shared__ alignas(16) ushort Ws[128][40];
  int y = blockIdx.y;
  gemm_body<MODE>(As, Ws, y ? A1 : A0, y ? W1 : W0, y ? b1 : b0, y ? C1 : C0,
                  M, K, 128, blockIdx.x * 128);
}

__global__ __launch_bounds__(256) void gemmH_k(
    const ushort* Abase, const ushort* Whead, const float* biasHead,
    ushort* pS, ushort* pT) {
  __shared__ alignas(16) ushort As[128][40];
  __shared__ alignas(16) ushort Ws[128][40];
  int z = blockIdx.z, ny = blockIdx.y;
  gemm_body<0>(As, Ws, Abase + (size_t)z * NBE,
               Whead + ((size_t)z * 256 + ny * 128) * 128,
               biasHead + z * 256 + ny * 128,
               (z ? pT : pS) + ny * 128,
               NSN, 128, 256, blockIdx.x * 128);
}

// ---------------------------------- layer GEMM: 3 A-panels, both dst types
template <int RES>
__global__ __launch_bounds__(256) void lgemm_k(
    const ushort* __restrict__ hs, const ushort* __restrict__ ht,
    const ushort* __restrict__ m0, const ushort* __restrict__ m1,
    const ushort* __restrict__ m2, const ushort* __restrict__ m3,
    const ushort* __restrict__ wlL, const ushort* __restrict__ wrcL,
    const float* __restrict__ blcL,
    ushort* __restrict__ hsOut, ushort* __restrict__ htOut, int M) {
  __shared__ alignas(16) ushort As[128][40];
  __shared__ alignas(16) ushort Ws[128][40];
  int t = threadIdx.x;
  int y = blockIdx.y;
  int m0i = blockIdx.x * 128;
  const ushort* A0 = y ? m1 : m0;
  const ushort* A1 = y ? m2 : m3;
  const ushort* self = y ? ht : hs;
  const ushort* W0 = wlL + (size_t)(y ? 1 : 0) * 16384;
  const ushort* W1 = wlL + (size_t)(y ? 2 : 3) * 16384;
  const ushort* W2 = wrcL + (size_t)y * 16384;
  const float* bias = blcL + y * 128;
  ushort* C = y ? htOut : hsOut;

  int lane = t & 63, w = t >> 6, wm = w >> 1, wn = w & 1;
  f32x4 zz = {0.f, 0.f, 0.f, 0.f};
  f32x4 acc[4][4];
  #pragma unroll
  for (int i = 0; i < 4; ++i)
    #pragma unroll
    for (int j = 0; j < 4; ++j) acc[i][j] = zz;
  for (int p = 0; p < 3; ++p) {
    const ushort* A = p == 0 ? A0 : (p == 1 ? A1 : self);
    const ushort* Wp = p == 0 ? W0 : (p == 1 ? W1 : W2);
    for (int kb = 0; kb < 128; kb += 32) {
      #pragma unroll
      for (int s = 0; s < 2; ++s) {
        int idx = t + s * 256;
        int r = idx >> 2, c = idx & 3;
        int gm = m0i + r;
        uint4 va = make_uint4(0, 0, 0, 0);
        if (gm < M) va = *(const uint4*)(A + (size_t)gm * 128 + kb + c * 8);
        *(uint4*)&As[r][c * 8] = va;
        *(uint4*)&Ws[r][c * 8] = *(const uint4*)(Wp + (size_t)r * 128 + kb + c * 8);
      }
      __syncthreads();
      short8 af[4], bf[4];
      #pragma unroll
      for (int mf = 0; mf < 4; ++mf)
        af[mf] = *(const short8*)&As[wm * 64 + mf * 16 + (lane & 15)][(lane >> 4) * 8];
      #pragma unroll
      for (int nf = 0; nf < 4; ++nf)
        bf[nf] = *(const short8*)&Ws[wn * 64 + nf * 16 + (lane & 15)][(lane >> 4) * 8];
      #pragma unroll
      for (int mf = 0; mf < 4; ++mf)
        #pragma unroll
        for (int nf = 0; nf < 4; ++nf) acc[mf][nf] = MFMA16(af[mf], bf[nf], acc[mf][nf]);
      __syncthreads();
    }
  }
  int r0 = (lane >> 4) * 4, nin = lane & 15;
  #pragma unroll
  for (int mf = 0; mf < 4; ++mf)
    #pragma unroll
    for (int nf = 0; nf < 4; ++nf) {
      int n = wn * 64 + nf * 16 + nin;
      float bv = bias[n];
      #pragma unroll
      for (int i = 0; i < 4; ++i) {
        int gm = m0i + wm * 64 + mf * 16 + r0 + i;
        if (gm >= M) continue;
        float v = 0.5f * (acc[mf][nf][i] + bv);
        if (RES) v += b2f(self[(size_t)gm * 128 + n]);
        C[(size_t)gm * 128 + n] = f2b(fmaxf(v, 0.f));
      }
    }
}

// ---------------------------------------------------------------- edge head
// CSR-ordered edges (sorted by target col): pT rows reused ~10x within block.
// XCD-bijective block swizzle keeps adjacent col-windows on one XCD L2.
__global__ __launch_bounds__(256) void head_k(
    const ushort* __restrict__ pS, const ushort* __restrict__ pT,
    const int* __restrict__ erowA, const int* __restrict__ ecolA,
    const int* __restrict__ eidA, const float* __restrict__ ea,
    const ushort* __restrict__ w1eB, const ushort* __restrict__ w2B,
    const float* __restrict__ gw2, const float* __restrict__ gb2p,
    const float* __restrict__ mb2, const float* __restrict__ mw3,
    const float* __restrict__ mb3, float* __restrict__ out, int E) {
  __shared__ alignas(16) ushort h1s[64][136];    // eat -> h1 -> (aliased) h2F
  __shared__ int er[64], ec[64], eidS[64];
  __shared__ alignas(16) float gw2s[128];
  __shared__ alignas(16) float mw3s[128];
  __shared__ float mb2s[64];
  float (*h2F)[68] = (float(*)[68])&h1s[0][0];

  // bijective XCD swizzle (nwg % 8 != 0 safe)
  int nwg = gridDim.x;
  int bid = blockIdx.x;
  int q = nwg >> 3, r = nwg & 7;
  int xcd = bid & 7, sub = bid >> 3;
  int swz = (xcd < r ? xcd * (q + 1) : r * (q + 1) + (xcd - r) * q) + sub;
  int e0 = swz * 64;

  int t = threadIdx.x;
  if (t < 64) {
    int p = e0 + t;
    er[t] = (p < E) ? erowA[p] : 0;
    eidS[t] = (p < E) ? eidA[p] : -1;
    mb2s[t] = mb2[t];
  } else if (t < 128) {
    int p = e0 + (t - 64);
    ec[t - 64] = (p < E) ? ecolA[p] : 0;
  }
  if (t < 128) gw2s[t] = gw2[t];
  else mw3s[t - 128] = mw3[t - 128];
  __syncthreads();
  int lane = t & 63, w = t >> 6;
  // Phase E: eat = ea @ w1e^T (M=64, N=128, K=32) -> h1s
  {
    int eid = eidS[w * 16 + (lane & 15)];
    float4 f0 = make_float4(0, 0, 0, 0), f1 = make_float4(0, 0, 0, 0);
    if (eid >= 0) {
      f0 = *(const float4*)(ea + (size_t)eid * 32 + (lane >> 4) * 8);
      f1 = *(const float4*)(ea + (size_t)eid * 32 + (lane >> 4) * 8 + 4);
    }
    union { short8 s; uint4 u; } cv;
    cv.u = make_uint4(pk2(f0.x, f0.y), pk2(f0.z, f0.w), pk2(f1.x, f1.y), pk2(f1.z, f1.w));
    short8 a = cv.s;
    int ebase = w * 16 + (lane >> 4) * 4;
    #pragma unroll
    for (int nf = 0; nf < 8; ++nf) {
      short8 b = *(const short8*)(w1eB + (size_t)(nf * 16 + (lane & 15)) * 32 + (lane >> 4) * 8);
      f32x4 cz = {0.f, 0.f, 0.f, 0.f};
      cz = MFMA16(a, b, cz);
      int jj = nf * 16 + (lane & 15);
      #pragma unroll
      for (int i = 0; i < 4; ++i) h1s[ebase + i][jj] = f2b(cz[i]);
    }
  }
  __syncthreads();
  // Phase G: gate + convex combine + eat (in-place RMW) + relu -> h1s
  {
    int el = lane >> 2, qq = lane & 3, e = w * 16 + el;
    int j0 = qq * 32;
    const ushort* ps = pS + (size_t)er[e] * 256;
    const ushort* pt = pT + (size_t)ec[e] * 256;
    float dot = 0.f;
    #pragma unroll
    for (int cc = 0; cc < 4; ++cc) {
      int j = j0 + cc * 8;
      uint4 ga = *(const uint4*)(ps + j);
      uint4 gb = *(const uint4*)(pt + j);
      const float* gp = &gw2s[j];
      float h;
      h = fmaxf(blo(ga.x) + blo(gb.x), 0.f); dot = fmaf(h, gp[0], dot);
      h = fmaxf(bhi(ga.x) + bhi(gb.x), 0.f); dot = fmaf(h, gp[1], dot);
      h = fmaxf(blo(ga.y) + blo(gb.y), 0.f); dot = fmaf(h, gp[2], dot);
      h = fmaxf(bhi(ga.y) + bhi(gb.y), 0.f); dot = fmaf(h, gp[3], dot);
      h = fmaxf(blo(ga.z) + blo(gb.z), 0.f); dot = fmaf(h, gp[4], dot);
      h = fmaxf(bhi(ga.z) + bhi(gb.z), 0.f); dot = fmaf(h, gp[5], dot);
      h = fmaxf(blo(ga.w) + blo(gb.w), 0.f); dot = fmaf(h, gp[6], dot);
      h = fmaxf(bhi(ga.w) + bhi(gb.w), 0.f); dot = fmaf(h, gp[7], dot);
    }
    dot += __shfl_xor(dot, 1, 64);
    dot += __shfl_xor(dot, 2, 64);
    float g = 1.f / (1.f + __expf(-(dot + gb2p[0])));
    float om = 1.f - g;
    #pragma unroll
    for (int cc = 0; cc < 4; ++cc) {
      int j = j0 + cc * 8;
      uint4 uu = *(const uint4*)(ps + 128 + j);
      uint4 vv = *(const uint4*)(pt + 128 + j);
      uint4 ee = *(const uint4*)&h1s[e][j];
      uint o0 = pk2(fmaxf(fmaf(g, blo(uu.x), om * blo(vv.x)) + blo(ee.x), 0.f),
                    fmaxf(fmaf(g, bhi(uu.x), om * bhi(vv.x)) + bhi(ee.x), 0.f));
      uint o1 = pk2(fmaxf(fmaf(g, blo(uu.y), om * blo(vv.y)) + blo(ee.y), 0.f),
                    fmaxf(fmaf(g, bhi(uu.y), om * bhi(vv.y)) + bhi(ee.y), 0.f));
      uint o2 = pk2(fmaxf(fmaf(g, blo(uu.z), om * blo(vv.z)) + blo(ee.z), 0.f),
                    fmaxf(fmaf(g, bhi(uu.z), om * bhi(vv.z)) + bhi(ee.z), 0.f));
      uint o3 = pk2(fmaxf(fmaf(g, blo(uu.w), om * blo(vv.w)) + blo(ee.w), 0.f),
                    fmaxf(fmaf(g, bhi(uu.w), om * bhi(vv.w)) + bhi(ee.w), 0.f));
      *(uint4*)&h1s[e][j] = make_uint4(o0, o1, o2, o3);
    }
  }
  __syncthreads();
  // Phase H: h2 = relu(h1 @ w2^T + b2)
  {
    f32x4 zz = {0.f, 0.f, 0.f, 0.f};
    f32x4 acc[4] = {zz, zz, zz, zz};
    #pragma unroll
    for (int ks = 0; ks < 4; ++ks) {
      short8 a = *(const short8*)&h1s[w * 16 + (lane & 15)][ks * 32 + (lane >> 4) * 8];
      #pragma unroll
      for (int nf = 0; nf < 4; ++nf) {
        short8 b = *(const short8*)(w2B + (size_t)(nf * 16 + (lane & 15)) * 128 + ks * 32 + (lane >> 4) * 8);
        acc[nf] = MFMA16(a, b, acc[nf]);
      }
    }
    __syncthreads();
    int ebase = w * 16 + (lane >> 4) * 4;
    #pragma unroll
    for (int nf = 0; nf < 4; ++nf) {
      int n = nf * 16 + (lane & 15);
      #pragma unroll
      for (int i = 0; i < 4; ++i)
        h2F[ebase + i][n] = fmaxf(acc[nf][i] + mb2s[n], 0.f);
    }
  }
  __syncthreads();
  // Phase O: out scattered by original edge id
  if (t < 128) {
    int e = t >> 1, o = t & 1;
    int eid = eidS[e];
    if (eid >= 0) {
      float s = mb3[o];
      #pragma unroll
      for (int kk = 0; kk < 64; kk += 4) {
        float4 hv = *(const float4*)&h2F[e][kk];
        float4 wv = *(const float4*)&mw3s[o * 64 + kk];
        s = fmaf(hv.x, wv.x, s); s = fmaf(hv.y, wv.y, s);
        s = fmaf(hv.z, wv.z, s); s = fmaf(hv.w, wv.w, s);
      }
      out[(size_t)eid * 2 + o] = s;
    }
  }
}

// ------------------------------------------------------------------- launch
extern "C" void kernel_launch(void* const* d_in, const int* in_sizes, int n_in,
                              void* d_out, int out_size, void* d_ws, size_t ws_size,
                              hipStream_t stream) {
  const float* x_source = (const float*)d_in[0];
  const float* x_target = (const float*)d_in[1];
  const float* edge_attr = (const float*)d_in[2];
  const float* enc_s_w1 = (const float*)d_in[3];
  const float* enc_s_b1 = (const float*)d_in[4];
  const float* enc_s_w2 = (const float*)d_in[5];
  const float* enc_s_b2 = (const float*)d_in[6];
  const float* enc_t_w1 = (const float*)d_in[7];
  const float* enc_t_b1 = (const float*)d_in[8];
  const float* enc_t_w2 = (const float*)d_in[9];
  const float* enc_t_b2 = (const float*)d_in[10];
  const float* conv_wl = (const float*)d_in[11];
  const float* conv_bl = (const float*)d_in[12];
  const float* conv_wr = (const float*)d_in[13];
  const float* gate_w1 = (const float*)d_in[14];
  const float* gate_b1 = (const float*)d_in[15];
  const float* gate_w2 = (const float*)d_in[16];
  const float* gate_b2 = (const float*)d_in[17];
  const float* mlp_w1 = (const float*)d_in[18];
  const float* mlp_b1 = (const float*)d_in[19];
  const float* mlp_w2 = (const float*)d_in[20];
  const float* mlp_b2 = (const float*)d_in[21];
  const float* mlp_w3 = (const float*)d_in[22];
  const float* mlp_b3 = (const float*)d_in[23];
  const int* ei[4] = {(const int*)d_in[24], (const int*)d_in[25],
                      (const int*)d_in[26], (const int*)d_in[27]};  // 0=ss,1=tt,2=st,3=ts
  float* out = (float*)d_out;

  char* wsp = (char*)d_ws;
  size_t off = 0;
  auto alloc = [&](size_t bytes) {
    char* p = wsp + off;
    off += (bytes + 255) & ~(size_t)255;
    return p;
  };
  ushort* nbase = (ushort*)alloc(4 * NBE * 2);
  ushort* nb[4];
  for (int i = 0; i < 4; ++i) nb[i] = nbase + (size_t)i * NBE;
  ushort* shared4 = (ushort*)alloc(4 * NBE * 2);
  ushort* mB[4];
  for (int i = 0; i < 4; ++i) mB[i] = shared4 + (size_t)i * NBE;
  int* adj4 = (int*)alloc((size_t)4 * EE * 4);
  int* off4 = (int*)alloc(4 * 50001 * 4);
  int* cur4 = (int*)alloc(4 * 50000 * 4);
  int* cnt4 = (int*)alloc(4 * 50000 * 4);
  int* bsum = (int*)alloc(128 * 4);
  ushort* xsB = (ushort*)alloc((size_t)NSN * 64 * 2);   // dead after enc1 -> adjE
  ushort* xtB = (ushort*)alloc((size_t)NTN * 64 * 2);   // dead after enc1 -> colOf
  ushort* esw1B = (ushort*)alloc(128 * 64 * 2);
  ushort* esw2B = (ushort*)alloc(128 * 128 * 2);
  ushort* etw1B = (ushort*)alloc(128 * 64 * 2);
  ushort* etw2B = (ushort*)alloc(128 * 128 * 2);
  ushort* wlB = (ushort*)alloc((size_t)12 * 16384 * 2);
  ushort* wrcB = (ushort*)alloc((size_t)6 * 16384 * 2);
  float* blc = (float*)alloc(6 * 128 * 4);
  ushort* Whead = (ushort*)alloc((size_t)2 * 256 * 128 * 2);
  float* biasHead = (float*)alloc(2 * 256 * 4);
  ushort* w1eB = (ushort*)alloc(128 * 32 * 2);
  ushort* w2B = (ushort*)alloc(64 * 128 * 2);

  // --- conversions / weight assembly / encoders FIRST (frees xsB/xtB) ---
  cvtall_k<<<(6645760 + 255) / 256, 256, 0, stream>>>(
      x_source, x_target, conv_wl, enc_s_w1, enc_s_w2, enc_t_w1, enc_t_w2,
      xsB, xtB, wlB, esw1B, esw2B, etw1B, etw2B);
  wrc_k<<<dim3(64, 6), 256, 0, stream>>>(conv_wr, conv_bl, wrcB, blc);
  headw_k<<<307, 256, 0, stream>>>(gate_w1, mlp_w1, mlp_w2, gate_b1, mlp_b1,
                                   Whead, biasHead, w1eB, w2B);
  int gm = (NSN + 127) / 128;
  enc_k<1><<<dim3(gm, 2), 256, 0, stream>>>(xsB, xtB, esw1B, etw1B,
      enc_s_b1, enc_t_b1, nb[2], nb[3], NSN, 64);
  enc_k<0><<<dim3(gm, 2), 256, 0, stream>>>(nb[2], nb[3], esw2B, etw2B,
      enc_s_b2, enc_t_b2, nb[0], nb[1], NSN, 128);

  // --- CSR build (adjE/colOf overlay dead xsB/xtB) ---
  int* adjE = (int*)xsB;
  int* colOf = (int*)xtB;
  hipMemsetAsync(cnt4, 0, 4 * 50000 * sizeof(int), stream);
  int cb = (EE + 255) / 256;
  count4_k<<<dim3(cb, 4), 256, 0, stream>>>(ei[0], ei[1], ei[2], ei[3], cnt4);
  scanA_k<<<dim3(25, 4), 256, 0, stream>>>(cnt4, cur4, bsum);
  scanB_k<<<1, 64, 0, stream>>>(bsum);
  scanC_k<<<dim3((50000 + 255) / 256, 4), 256, 0, stream>>>(cnt4, cur4, bsum, off4, cur4);
  for (int p = 0; p < NPASS; ++p)
    fillP_k<<<dim3(cb, 4), 256, 0, stream>>>(ei[0], ei[1], ei[2], ei[3], cur4, adj4, adjE, p);
  colof_k<<<(50000 + 255) / 256, 256, 0, stream>>>(off4 + 2 * 50001, colOf, NTN);

  // --- 3 hetero layers: (0,1)->(2,3)->(0,1)->(2,3) ---
  int gb = (NSN + 3) / 4;
  {
    gather4_k<<<dim3(gb, 4), 256, 0, stream>>>(nb[0], nb[1], off4, adj4,
        mB[0], mB[1], mB[2], mB[3], NSN);
    lgemm_k<0><<<dim3(gm, 2), 256, 0, stream>>>(nb[0], nb[1],
        mB[0], mB[1], mB[2], mB[3], wlB, wrcB, blc, nb[2], nb[3], NSN);
    gather4_k<<<dim3(gb, 4), 256, 0, stream>>>(nb[2], nb[3], off4, adj4,
        mB[0], mB[1], mB[2], mB[3], NSN);
    lgemm_k<1><<<dim3(gm, 2), 256, 0, stream>>>(nb[2], nb[3],
        mB[0], mB[1], mB[2], mB[3], wlB + (size_t)4 * 16384,
        wrcB + (size_t)2 * 16384, blc + 256, nb[0], nb[1], NSN);
    gather4_k<<<dim3(gb, 4), 256, 0, stream>>>(nb[0], nb[1], off4, adj4,
        mB[0], mB[1], mB[2], mB[3], NSN);
    lgemm_k<1><<<dim3(gm, 2), 256, 0, stream>>>(nb[0], nb[1],
        mB[0], mB[1], mB[2], mB[3], wlB + (size_t)8 * 16384,
        wrcB + (size_t)4 * 16384, blc + 512, nb[2], nb[3], NSN);
  }
  // h3s = nb2, h3t = nb3

  // --- nodewise head precompute ---
  ushort* pS = shared4;
  ushort* pT = shared4 + 2 * NBE;
  gemmH_k<<<dim3(gm, 2, 2), 256, 0, stream>>>(nbase + 2 * NBE, Whead, biasHead, pS, pT);

  // --- fused edge head (CSR-ordered) ---
  head_k<<<(EE + 63) / 64, 256, 0, stream>>>(pS, pT,
      adj4 + (size_t)2 * EE, colOf, adjE, edge_attr, w1eB, w2B,
      gate_w2, gate_b2, mlp_b2, mlp_w3, mlp_b3, out, EE);
}

// Round 8
// 821.123 us; speedup vs baseline: 1.6826x; 1.0167x over previous
//
#include <hip/hip_runtime.h>
#include <cmath>

#define NSN 50000
#define NTN 50000
#define EE  500000
#define NBE ((size_t)NSN * 128)
#define NPASS 4
#define PRNG 12500

using short8 = __attribute__((ext_vector_type(8))) short;
using f32x4  = __attribute__((ext_vector_type(4))) float;
#define MFMA16(a, b, c) __builtin_amdgcn_mfma_f32_16x16x32_bf16(a, b, c, 0, 0, 0)

__device__ __forceinline__ float  b2f(ushort u) { return __uint_as_float(((uint)u) << 16); }
__device__ __forceinline__ ushort f2b(float f) {
  uint x = __float_as_uint(f);
  uint r = x + 0x7FFFu + ((x >> 16) & 1u);
  return (ushort)(r >> 16);
}
__device__ __forceinline__ float blo(uint x) { return __uint_as_float(x << 16); }
__device__ __forceinline__ float bhi(uint x) { return __uint_as_float(x & 0xFFFF0000u); }
__device__ __forceinline__ uint  pk2(float a, float b) { return (uint)f2b(a) | ((uint)f2b(b) << 16); }

// ------------------------------------------------- all input/weight converts
__global__ void cvtall_k(const float* __restrict__ xs, const float* __restrict__ xt,
                         const float* __restrict__ wl,
                         const float* __restrict__ esw1, const float* __restrict__ esw2,
                         const float* __restrict__ etw1, const float* __restrict__ etw2,
                         ushort* __restrict__ xsB, ushort* __restrict__ xtB,
                         ushort* __restrict__ wlB, ushort* __restrict__ esw1B,
                         ushort* __restrict__ esw2B, ushort* __restrict__ etw1B,
                         ushort* __restrict__ etw2B) {
  int i = blockIdx.x * 256 + threadIdx.x;
  if (i < 3200000) { xsB[i] = f2b(xs[i]); return; }
  i -= 3200000;
  if (i < 3200000) {
    int r = i >> 6, k = i & 63;
    xtB[i] = (k < 48) ? f2b(xt[(size_t)r * 48 + k]) : (ushort)0;
    return;
  }
  i -= 3200000;
  if (i < 196608) { wlB[i] = f2b(wl[i]); return; }
  i -= 196608;
  if (i < 8192) { esw1B[i] = f2b(esw1[i]); return; }
  i -= 8192;
  if (i < 16384) { esw2B[i] = f2b(esw2[i]); return; }
  i -= 16384;
  if (i < 8192) {
    int r = i >> 6, k = i & 63;
    etw1B[i] = (k < 48) ? f2b(etw1[(size_t)r * 48 + k]) : (ushort)0;
    return;
  }
  i -= 8192;
  if (i < 16384) { etw2B[i] = f2b(etw2[i]); return; }
}

// ------------------------------------------------- combined wr + bias
__global__ void wrc_k(const float* __restrict__ wr, const float* __restrict__ bl,
                      ushort* __restrict__ wrcB, float* __restrict__ blc) {
  int z = blockIdx.y;
  int l = z >> 1, dd = z & 1;
  int r1 = dd ? 1 : 0, r2 = dd ? 2 : 3;
  int idx = blockIdx.x * 256 + threadIdx.x;
  if (idx < 16384) {
    wrcB[(size_t)z * 16384 + idx] =
        f2b(wr[(size_t)(l * 4 + r1) * 16384 + idx] + wr[(size_t)(l * 4 + r2) * 16384 + idx]);
    if (idx < 128)
      blc[z * 128 + idx] = bl[(l * 4 + r1) * 128 + idx] + bl[(l * 4 + r2) * 128 + idx];
  }
}

// ------------------------------------------------- head weight assembly
__global__ void headw_k(const float* __restrict__ gw1, const float* __restrict__ mw1,
                        const float* __restrict__ mw2, const float* __restrict__ gb1,
                        const float* __restrict__ mb1,
                        ushort* __restrict__ Whead, float* __restrict__ biasHead,
                        ushort* __restrict__ w1eB, ushort* __restrict__ w2B) {
  int idx = blockIdx.x * 256 + threadIdx.x;
  if (idx < 65536) {
    int z = idx >> 15, rr = (idx >> 7) & 255, c = idx & 127;
    float v = (rr < 128) ? gw1[(size_t)rr * 256 + z * 128 + c]
                         : mw1[(size_t)(rr - 128) * 160 + c];
    Whead[idx] = f2b(v);
  } else if (idx < 69632) {
    int i = idx - 65536;
    w1eB[i] = f2b(mw1[(size_t)(i >> 5) * 160 + 128 + (i & 31)]);
  } else if (idx < 77824) {
    int i = idx - 69632;
    w2B[i] = f2b(mw2[i]);
  } else if (idx < 78336) {
    int i = idx - 77824;
    int z = i >> 8, n = i & 255;
    biasHead[i] = (n < 128) ? (z ? 0.f : gb1[n]) : mb1[n - 128];
  }
}

// --------------------------------------------------------------- CSR build
__global__ void count4_k(const int* __restrict__ e0, const int* __restrict__ e1,
                         const int* __restrict__ e2, const int* __restrict__ e3,
                         int* __restrict__ cnt) {
  int rel = blockIdx.y;
  const int* col = (rel == 0 ? e0 : rel == 1 ? e1 : rel == 2 ? e2 : e3) + EE;
  int i = blockIdx.x * 256 + threadIdx.x;
  if (i < EE) atomicAdd(&cnt[rel * 50000 + col[i]], 1);
}

// hierarchical scan
__global__ __launch_bounds__(256) void scanA_k(const int* __restrict__ cnt,
                                               int* __restrict__ loc,
                                               int* __restrict__ bsum) {
  __shared__ int ws[4];
  int rel = blockIdx.y, b = blockIdx.x, t = threadIdx.x;
  const int* c = cnt + (size_t)rel * 50000;
  int base = b * 2048 + t * 8;
  int v[8], s = 0;
  #pragma unroll
  for (int i = 0; i < 8; ++i) {
    int idx = base + i;
    v[i] = (idx < 50000) ? c[idx] : 0;
    s += v[i];
  }
  int lane = t & 63, w = t >> 6;
  int x = s;
  #pragma unroll
  for (int d = 1; d < 64; d <<= 1) {
    int y = __shfl_up(x, d, 64);
    if (lane >= d) x += y;
  }
  if (lane == 63) ws[w] = x;
  __syncthreads();
  int add = 0;
  for (int ww = 0; ww < w; ++ww) add += ws[ww];
  int run = add + x - s;
  #pragma unroll
  for (int i = 0; i < 8; ++i) {
    int idx = base + i;
    run += v[i];
    if (idx < 50000) loc[(size_t)rel * 50000 + idx] = run;
  }
  if (t == 255) bsum[rel * 25 + b] = add + x;
}
__global__ void scanB_k(int* __restrict__ bsum) {
  int t = threadIdx.x;
  if (t < 4) {
    int s = 0;
    for (int b = 0; b < 25; ++b) {
      int v = bsum[t * 25 + b];
      bsum[t * 25 + b] = s;
      s += v;
    }
  }
}
__global__ void scanC_k(const int* __restrict__ cnt, int* __restrict__ loc,
                        const int* __restrict__ bsum, int* __restrict__ off,
                        int* __restrict__ cur) {
  int rel = blockIdx.y;
  int i = blockIdx.x * 256 + threadIdx.x;
  if (i < 50000) {
    int incl = loc[(size_t)rel * 50000 + i] + bsum[rel * 25 + i / 2048];
    off[(size_t)rel * 50001 + i + 1] = incl;
    cur[(size_t)rel * 50000 + i] = incl - cnt[(size_t)rel * 50000 + i];
    if (i == 0) off[(size_t)rel * 50001] = 0;
  }
}

// range-partitioned fill; rel 2 also records original edge id
__global__ void fillP_k(const int* __restrict__ e0, const int* __restrict__ e1,
                        const int* __restrict__ e2, const int* __restrict__ e3,
                        int* __restrict__ cur, int* __restrict__ adj,
                        int* __restrict__ adjE, int pass) {
  int rel = blockIdx.y;
  const int* ei = rel == 0 ? e0 : rel == 1 ? e1 : rel == 2 ? e2 : e3;
  int e = blockIdx.x * 256 + threadIdx.x;
  if (e < EE) {
    int c = ei[EE + e];
    if (c >= pass * PRNG && c < (pass + 1) * PRNG) {
      int pos = atomicAdd(&cur[rel * 50000 + c], 1);
      adj[(size_t)rel * EE + pos] = ei[e];
      if (rel == 2) adjE[pos] = e;
    }
  }
}

// expand rel-2 offsets -> per-position col
__global__ void colof_k(const int* __restrict__ off, int* __restrict__ colOf, int N) {
  int n = blockIdx.x * 256 + threadIdx.x;
  if (n < N) {
    int s = off[n], e = off[n + 1];
    for (int i = s; i < e; ++i) colOf[i] = n;
  }
}

// -------------------------------- permute ea into CSR order (+bf16 convert)
__global__ void eaperm_k(const float* __restrict__ ea, const int* __restrict__ adjE,
                         ushort* __restrict__ eaB, int E) {
  int idx = blockIdx.x * 256 + threadIdx.x;
  int pos = idx >> 3, q = idx & 7;   // 8 lanes per edge (32 floats)
  if (pos < E) {
    int eid = adjE[pos];
    float4 v = *(const float4*)(ea + (size_t)eid * 32 + q * 4);
    ushort4 o;
    o.x = f2b(v.x); o.y = f2b(v.y); o.z = f2b(v.z); o.w = f2b(v.w);
    *(ushort4*)(eaB + (size_t)pos * 32 + q * 4) = o;
  }
}

// ------------------------------------------------------------- gather-mean
__global__ __launch_bounds__(256) void gather4_k(
    const ushort* __restrict__ hs, const ushort* __restrict__ ht,
    const int* __restrict__ off4, const int* __restrict__ adj4,
    ushort* __restrict__ m0, ushort* __restrict__ m1,
    ushort* __restrict__ m2, ushort* __restrict__ m3, int N) {
  int r = blockIdx.y;
  const ushort* src = (r == 0 || r == 2) ? hs : ht;
  ushort* dst = r == 0 ? m0 : (r == 1 ? m1 : (r == 2 ? m2 : m3));
  const int* off = off4 + r * 50001;
  const int* adj = adj4 + (size_t)r * EE;
  int t = threadIdx.x;
  int n = blockIdx.x * 4 + (t >> 6);
  if (n >= N) return;
  int lane = t & 63, g = lane >> 4, i = lane & 15;
  int s = off[n], e = off[n + 1];
  float a[8] = {};
  int k = s + g;
  for (; k + 4 < e; k += 8) {
    int r0 = adj[k], r1 = adj[k + 4];
    uint4 v0 = *(const uint4*)(src + (size_t)r0 * 128 + i * 8);
    uint4 v1 = *(const uint4*)(src + (size_t)r1 * 128 + i * 8);
    a[0] += blo(v0.x) + blo(v1.x); a[1] += bhi(v0.x) + bhi(v1.x);
    a[2] += blo(v0.y) + blo(v1.y); a[3] += bhi(v0.y) + bhi(v1.y);
    a[4] += blo(v0.z) + blo(v1.z); a[5] += bhi(v0.z) + bhi(v1.z);
    a[6] += blo(v0.w) + blo(v1.w); a[7] += bhi(v0.w) + bhi(v1.w);
  }
  if (k < e) {
    int r0 = adj[k];
    uint4 v = *(const uint4*)(src + (size_t)r0 * 128 + i * 8);
    a[0] += blo(v.x); a[1] += bhi(v.x);
    a[2] += blo(v.y); a[3] += bhi(v.y);
    a[4] += blo(v.z); a[5] += bhi(v.z);
    a[6] += blo(v.w); a[7] += bhi(v.w);
  }
  #pragma unroll
  for (int c = 0; c < 8; ++c) {
    a[c] += __shfl_xor(a[c], 16, 64);
    a[c] += __shfl_xor(a[c], 32, 64);
  }
  if (g == 0) {
    float inv = 1.f / (float)max(e - s, 1);
    uint4 o;
    o.x = pk2(a[0] * inv, a[1] * inv);
    o.y = pk2(a[2] * inv, a[3] * inv);
    o.z = pk2(a[4] * inv, a[5] * inv);
    o.w = pk2(a[6] * inv, a[7] * inv);
    *(uint4*)(dst + (size_t)n * 128 + i * 8) = o;
  }
}

// ------------------------------------------------------- shared GEMM body
template <int MODE>
__device__ __forceinline__ void gemm_body(
    ushort (*As)[40], ushort (*Ws)[40],
    const ushort* __restrict__ A, const ushort* __restrict__ W,
    const float* __restrict__ bias, ushort* __restrict__ C,
    int M, int K, int ldc, int m0) {
  int t = threadIdx.x;
  int lane = t & 63, w = t >> 6, wm = w >> 1, wn = w & 1;
  f32x4 zz = {0.f, 0.f, 0.f, 0.f};
  f32x4 acc[4][4];
  #pragma unroll
  for (int i = 0; i < 4; ++i)
    #pragma unroll
    for (int j = 0; j < 4; ++j) acc[i][j] = zz;
  for (int kb = 0; kb < K; kb += 32) {
    #pragma unroll
    for (int s = 0; s < 2; ++s) {
      int idx = t + s * 256;
      int r = idx >> 2, c = idx & 3;
      int gm = m0 + r;
      uint4 va = make_uint4(0, 0, 0, 0);
      if (gm < M) va = *(const uint4*)(A + (size_t)gm * K + kb + c * 8);
      *(uint4*)&As[r][c * 8] = va;
      *(uint4*)&Ws[r][c * 8] = *(const uint4*)(W + (size_t)r * K + kb + c * 8);
    }
    __syncthreads();
    short8 af[4], bf[4];
    #pragma unroll
    for (int mf = 0; mf < 4; ++mf)
      af[mf] = *(const short8*)&As[wm * 64 + mf * 16 + (lane & 15)][(lane >> 4) * 8];
    #pragma unroll
    for (int nf = 0; nf < 4; ++nf)
      bf[nf] = *(const short8*)&Ws[wn * 64 + nf * 16 + (lane & 15)][(lane >> 4) * 8];
    #pragma unroll
    for (int mf = 0; mf < 4; ++mf)
      #pragma unroll
      for (int nf = 0; nf < 4; ++nf) acc[mf][nf] = MFMA16(af[mf], bf[nf], acc[mf][nf]);
    __syncthreads();
  }
  int r0 = (lane >> 4) * 4, nin = lane & 15;
  #pragma unroll
  for (int mf = 0; mf < 4; ++mf)
    #pragma unroll
    for (int nf = 0; nf < 4; ++nf) {
      int n = wn * 64 + nf * 16 + nin;
      float bv = bias ? bias[n] : 0.f;
      #pragma unroll
      for (int i = 0; i < 4; ++i) {
        int gm = m0 + wm * 64 + mf * 16 + r0 + i;
        if (gm >= M) continue;
        float v = acc[mf][nf][i] + bv;
        if (MODE == 1) v = fmaxf(v, 0.f);
        C[(size_t)gm * ldc + n] = f2b(v);
      }
    }
}

template <int MODE>
__global__ __launch_bounds__(256) void enc_k(
    const ushort* A0, const ushort* A1, const ushort* W0, const ushort* W1,
    const float* b0, const float* b1, ushort* C0, ushort* C1, int M, int K) {
  __shared__ alignas(16) ushort As[128][40];
  __shared__ alignas(16) ushort Ws[128][40];
  int y = blockIdx.y;
  gemm_body<MODE>(As, Ws, y ? A1 : A0, y ? W1 : W0, y ? b1 : b0, y ? C1 : C0,
                  M, K, 128, blockIdx.x * 128);
}

__global__ __launch_bounds__(256) void gemmH_k(
    const ushort* Abase, const ushort* Whead, const float* biasHead,
    ushort* pS, ushort* pT) {
  __shared__ alignas(16) ushort As[128][40];
  __shared__ alignas(16) ushort Ws[128][40];
  int z = blockIdx.z, ny = blockIdx.y;
  gemm_body<0>(As, Ws, Abase + (size_t)z * NBE,
               Whead + ((size_t)z * 256 + ny * 128) * 128,
               biasHead + z * 256 + ny * 128,
               (z ? pT : pS) + ny * 128,
               NSN, 128, 256, blockIdx.x * 128);
}

// ---------------------------------- layer GEMM: 3 A-panels, both dst types
template <int RES>
__global__ __launch_bounds__(256) void lgemm_k(
    const ushort* __restrict__ hs, const ushort* __restrict__ ht,
    const ushort* __restrict__ m0, const ushort* __restrict__ m1,
    const ushort* __restrict__ m2, const ushort* __restrict__ m3,
    const ushort* __restrict__ wlL, const ushort* __restrict__ wrcL,
    const float* __restrict__ blcL,
    ushort* __restrict__ hsOut, ushort* __restrict__ htOut, int M) {
  __shared__ alignas(16) ushort As[128][40];
  __shared__ alignas(16) ushort Ws[128][40];
  int t = threadIdx.x;
  int y = blockIdx.y;
  int m0i = blockIdx.x * 128;
  const ushort* A0 = y ? m1 : m0;
  const ushort* A1 = y ? m2 : m3;
  const ushort* self = y ? ht : hs;
  const ushort* W0 = wlL + (size_t)(y ? 1 : 0) * 16384;
  const ushort* W1 = wlL + (size_t)(y ? 2 : 3) * 16384;
  const ushort* W2 = wrcL + (size_t)y * 16384;
  const float* bias = blcL + y * 128;
  ushort* C = y ? htOut : hsOut;

  int lane = t & 63, w = t >> 6, wm = w >> 1, wn = w & 1;
  f32x4 zz = {0.f, 0.f, 0.f, 0.f};
  f32x4 acc[4][4];
  #pragma unroll
  for (int i = 0; i < 4; ++i)
    #pragma unroll
    for (int j = 0; j < 4; ++j) acc[i][j] = zz;
  for (int p = 0; p < 3; ++p) {
    const ushort* A = p == 0 ? A0 : (p == 1 ? A1 : self);
    const ushort* Wp = p == 0 ? W0 : (p == 1 ? W1 : W2);
    for (int kb = 0; kb < 128; kb += 32) {
      #pragma unroll
      for (int s = 0; s < 2; ++s) {
        int idx = t + s * 256;
        int r = idx >> 2, c = idx & 3;
        int gm = m0i + r;
        uint4 va = make_uint4(0, 0, 0, 0);
        if (gm < M) va = *(const uint4*)(A + (size_t)gm * 128 + kb + c * 8);
        *(uint4*)&As[r][c * 8] = va;
        *(uint4*)&Ws[r][c * 8] = *(const uint4*)(Wp + (size_t)r * 128 + kb + c * 8);
      }
      __syncthreads();
      short8 af[4], bf[4];
      #pragma unroll
      for (int mf = 0; mf < 4; ++mf)
        af[mf] = *(const short8*)&As[wm * 64 + mf * 16 + (lane & 15)][(lane >> 4) * 8];
      #pragma unroll
      for (int nf = 0; nf < 4; ++nf)
        bf[nf] = *(const short8*)&Ws[wn * 64 + nf * 16 + (lane & 15)][(lane >> 4) * 8];
      #pragma unroll
      for (int mf = 0; mf < 4; ++mf)
        #pragma unroll
        for (int nf = 0; nf < 4; ++nf) acc[mf][nf] = MFMA16(af[mf], bf[nf], acc[mf][nf]);
      __syncthreads();
    }
  }
  int r0 = (lane >> 4) * 4, nin = lane & 15;
  #pragma unroll
  for (int mf = 0; mf < 4; ++mf)
    #pragma unroll
    for (int nf = 0; nf < 4; ++nf) {
      int n = wn * 64 + nf * 16 + nin;
      float bv = bias[n];
      #pragma unroll
      for (int i = 0; i < 4; ++i) {
        int gm = m0i + wm * 64 + mf * 16 + r0 + i;
        if (gm >= M) continue;
        float v = 0.5f * (acc[mf][nf][i] + bv);
        if (RES) v += b2f(self[(size_t)gm * 128 + n]);
        C[(size_t)gm * 128 + n] = f2b(fmaxf(v, 0.f));
      }
    }
}

// ---------------------------------------------------------------- edge head
// CSR-ordered edges; ea pre-permuted to CSR order (sequential bf16 loads).
__global__ __launch_bounds__(256) void head_k(
    const ushort* __restrict__ pS, const ushort* __restrict__ pT,
    const int* __restrict__ erowA, const int* __restrict__ ecolA,
    const int* __restrict__ eidA, const ushort* __restrict__ eaB,
    const ushort* __restrict__ w1eB, const ushort* __restrict__ w2B,
    const float* __restrict__ gw2, const float* __restrict__ gb2p,
    const float* __restrict__ mb2, const float* __restrict__ mw3,
    const float* __restrict__ mb3, float* __restrict__ out, int E) {
  __shared__ alignas(16) ushort h1s[64][136];    // eat -> h1 -> (aliased) h2F
  __shared__ int er[64], ec[64], eidS[64];
  __shared__ alignas(16) float gw2s[128];
  __shared__ alignas(16) float mw3s[128];
  __shared__ float mb2s[64];
  float (*h2F)[68] = (float(*)[68])&h1s[0][0];

  // bijective XCD swizzle (nwg % 8 != 0 safe)
  int nwg = gridDim.x;
  int bid = blockIdx.x;
  int q = nwg >> 3, r = nwg & 7;
  int xcd = bid & 7, sub = bid >> 3;
  int swz = (xcd < r ? xcd * (q + 1) : r * (q + 1) + (xcd - r) * q) + sub;
  int e0 = swz * 64;

  int t = threadIdx.x;
  if (t < 64) {
    int p = e0 + t;
    er[t] = (p < E) ? erowA[p] : 0;
    eidS[t] = (p < E) ? eidA[p] : -1;
    mb2s[t] = mb2[t];
  } else if (t < 128) {
    int p = e0 + (t - 64);
    ec[t - 64] = (p < E) ? ecolA[p] : 0;
  }
  if (t < 128) gw2s[t] = gw2[t];
  else mw3s[t - 128] = mw3[t - 128];
  __syncthreads();
  int lane = t & 63, w = t >> 6;
  // Phase E: eat = ea @ w1e^T (M=64, N=128, K=32) -> h1s; A straight from eaB
  {
    int p = e0 + w * 16 + (lane & 15);
    short8 a = {};
    if (p < E) a = *(const short8*)(eaB + (size_t)p * 32 + (lane >> 4) * 8);
    int ebase = w * 16 + (lane >> 4) * 4;
    #pragma unroll
    for (int nf = 0; nf < 8; ++nf) {
      short8 b = *(const short8*)(w1eB + (size_t)(nf * 16 + (lane & 15)) * 32 + (lane >> 4) * 8);
      f32x4 cz = {0.f, 0.f, 0.f, 0.f};
      cz = MFMA16(a, b, cz);
      int jj = nf * 16 + (lane & 15);
      #pragma unroll
      for (int i = 0; i < 4; ++i) h1s[ebase + i][jj] = f2b(cz[i]);
    }
  }
  __syncthreads();
  // Phase G: gate + convex combine + eat (in-place RMW) + relu -> h1s
  {
    int el = lane >> 2, qq = lane & 3, e = w * 16 + el;
    int j0 = qq * 32;
    const ushort* ps = pS + (size_t)er[e] * 256;
    const ushort* pt = pT + (size_t)ec[e] * 256;
    float dot = 0.f;
    #pragma unroll
    for (int cc = 0; cc < 4; ++cc) {
      int j = j0 + cc * 8;
      uint4 ga = *(const uint4*)(ps + j);
      uint4 gb = *(const uint4*)(pt + j);
      const float* gp = &gw2s[j];
      float h;
      h = fmaxf(blo(ga.x) + blo(gb.x), 0.f); dot = fmaf(h, gp[0], dot);
      h = fmaxf(bhi(ga.x) + bhi(gb.x), 0.f); dot = fmaf(h, gp[1], dot);
      h = fmaxf(blo(ga.y) + blo(gb.y), 0.f); dot = fmaf(h, gp[2], dot);
      h = fmaxf(bhi(ga.y) + bhi(gb.y), 0.f); dot = fmaf(h, gp[3], dot);
      h = fmaxf(blo(ga.z) + blo(gb.z), 0.f); dot = fmaf(h, gp[4], dot);
      h = fmaxf(bhi(ga.z) + bhi(gb.z), 0.f); dot = fmaf(h, gp[5], dot);
      h = fmaxf(blo(ga.w) + blo(gb.w), 0.f); dot = fmaf(h, gp[6], dot);
      h = fmaxf(bhi(ga.w) + bhi(gb.w), 0.f); dot = fmaf(h, gp[7], dot);
    }
    dot += __shfl_xor(dot, 1, 64);
    dot += __shfl_xor(dot, 2, 64);
    float g = 1.f / (1.f + __expf(-(dot + gb2p[0])));
    float om = 1.f - g;
    #pragma unroll
    for (int cc = 0; cc < 4; ++cc) {
      int j = j0 + cc * 8;
      uint4 uu = *(const uint4*)(ps + 128 + j);
      uint4 vv = *(const uint4*)(pt + 128 + j);
      uint4 ee = *(const uint4*)&h1s[e][j];
      uint o0 = pk2(fmaxf(fmaf(g, blo(uu.x), om * blo(vv.x)) + blo(ee.x), 0.f),
                    fmaxf(fmaf(g, bhi(uu.x), om * bhi(vv.x)) + bhi(ee.x), 0.f));
      uint o1 = pk2(fmaxf(fmaf(g, blo(uu.y), om * blo(vv.y)) + blo(ee.y), 0.f),
                    fmaxf(fmaf(g, bhi(uu.y), om * bhi(vv.y)) + bhi(ee.y), 0.f));
      uint o2 = pk2(fmaxf(fmaf(g, blo(uu.z), om * blo(vv.z)) + blo(ee.z), 0.f),
                    fmaxf(fmaf(g, bhi(uu.z), om * bhi(vv.z)) + bhi(ee.z), 0.f));
      uint o3 = pk2(fmaxf(fmaf(g, blo(uu.w), om * blo(vv.w)) + blo(ee.w), 0.f),
                    fmaxf(fmaf(g, bhi(uu.w), om * bhi(vv.w)) + bhi(ee.w), 0.f));
      *(uint4*)&h1s[e][j] = make_uint4(o0, o1, o2, o3);
    }
  }
  __syncthreads();
  // Phase H: h2 = relu(h1 @ w2^T + b2)
  {
    f32x4 zz = {0.f, 0.f, 0.f, 0.f};
    f32x4 acc[4] = {zz, zz, zz, zz};
    #pragma unroll
    for (int ks = 0; ks < 4; ++ks) {
      short8 a = *(const short8*)&h1s[w * 16 + (lane & 15)][ks * 32 + (lane >> 4) * 8];
      #pragma unroll
      for (int nf = 0; nf < 4; ++nf) {
        short8 b = *(const short8*)(w2B + (size_t)(nf * 16 + (lane & 15)) * 128 + ks * 32 + (lane >> 4) * 8);
        acc[nf] = MFMA16(a, b, acc[nf]);
      }
    }
    __syncthreads();
    int ebase = w * 16 + (lane >> 4) * 4;
    #pragma unroll
    for (int nf = 0; nf < 4; ++nf) {
      int n = nf * 16 + (lane & 15);
      #pragma unroll
      for (int i = 0; i < 4; ++i)
        h2F[ebase + i][n] = fmaxf(acc[nf][i] + mb2s[n], 0.f);
    }
  }
  __syncthreads();
  // Phase O: out scattered by original edge id
  if (t < 128) {
    int e = t >> 1, o = t & 1;
    int eid = eidS[e];
    if (eid >= 0) {
      float s = mb3[o];
      #pragma unroll
      for (int kk = 0; kk < 64; kk += 4) {
        float4 hv = *(const float4*)&h2F[e][kk];
        float4 wv = *(const float4*)&mw3s[o * 64 + kk];
        s = fmaf(hv.x, wv.x, s); s = fmaf(hv.y, wv.y, s);
        s = fmaf(hv.z, wv.z, s); s = fmaf(hv.w, wv.w, s);
      }
      out[(size_t)eid * 2 + o] = s;
    }
  }
}

// ------------------------------------------------------------------- launch
extern "C" void kernel_launch(void* const* d_in, const int* in_sizes, int n_in,
                              void* d_out, int out_size, void* d_ws, size_t ws_size,
                              hipStream_t stream) {
  const float* x_source = (const float*)d_in[0];
  const float* x_target = (const float*)d_in[1];
  const float* edge_attr = (const float*)d_in[2];
  const float* enc_s_w1 = (const float*)d_in[3];
  const float* enc_s_b1 = (const float*)d_in[4];
  const float* enc_s_w2 = (const float*)d_in[5];
  const float* enc_s_b2 = (const float*)d_in[6];
  const float* enc_t_w1 = (const float*)d_in[7];
  const float* enc_t_b1 = (const float*)d_in[8];
  const float* enc_t_w2 = (const float*)d_in[9];
  const float* enc_t_b2 = (const float*)d_in[10];
  const float* conv_wl = (const float*)d_in[11];
  const float* conv_bl = (const float*)d_in[12];
  const float* conv_wr = (const float*)d_in[13];
  const float* gate_w1 = (const float*)d_in[14];
  const float* gate_b1 = (const float*)d_in[15];
  const float* gate_w2 = (const float*)d_in[16];
  const float* gate_b2 = (const float*)d_in[17];
  const float* mlp_w1 = (const float*)d_in[18];
  const float* mlp_b1 = (const float*)d_in[19];
  const float* mlp_w2 = (const float*)d_in[20];
  const float* mlp_b2 = (const float*)d_in[21];
  const float* mlp_w3 = (const float*)d_in[22];
  const float* mlp_b3 = (const float*)d_in[23];
  const int* ei[4] = {(const int*)d_in[24], (const int*)d_in[25],
                      (const int*)d_in[26], (const int*)d_in[27]};  // 0=ss,1=tt,2=st,3=ts
  float* out = (float*)d_out;

  char* wsp = (char*)d_ws;
  size_t off = 0;
  auto alloc = [&](size_t bytes) {
    char* p = wsp + off;
    off += (bytes + 255) & ~(size_t)255;
    return p;
  };
  ushort* nbase = (ushort*)alloc(4 * NBE * 2);
  ushort* nb[4];
  for (int i = 0; i < 4; ++i) nb[i] = nbase + (size_t)i * NBE;
  ushort* shared4 = (ushort*)alloc(4 * NBE * 2);
  ushort* mB[4];
  for (int i = 0; i < 4; ++i) mB[i] = shared4 + (size_t)i * NBE;
  int* adj4 = (int*)alloc((size_t)4 * EE * 4);
  int* off4 = (int*)alloc(4 * 50001 * 4);
  int* cur4 = (int*)alloc(4 * 50000 * 4);
  int* cnt4 = (int*)alloc(4 * 50000 * 4);
  int* bsum = (int*)alloc(128 * 4);
  ushort* xsB = (ushort*)alloc((size_t)NSN * 64 * 2);   // dead after enc1 -> adjE
  ushort* xtB = (ushort*)alloc((size_t)NTN * 64 * 2);   // dead after enc1 -> colOf
  ushort* esw1B = (ushort*)alloc(128 * 64 * 2);
  ushort* esw2B = (ushort*)alloc(128 * 128 * 2);
  ushort* etw1B = (ushort*)alloc(128 * 64 * 2);
  ushort* etw2B = (ushort*)alloc(128 * 128 * 2);
  ushort* wlB = (ushort*)alloc((size_t)12 * 16384 * 2);
  ushort* wrcB = (ushort*)alloc((size_t)6 * 16384 * 2);
  float* blc = (float*)alloc(6 * 128 * 4);
  ushort* Whead = (ushort*)alloc((size_t)2 * 256 * 128 * 2);
  float* biasHead = (float*)alloc(2 * 256 * 4);
  ushort* w1eB = (ushort*)alloc(128 * 32 * 2);
  ushort* w2B = (ushort*)alloc(64 * 128 * 2);

  // --- conversions / weight assembly / encoders FIRST (frees xsB/xtB) ---
  cvtall_k<<<(6645760 + 255) / 256, 256, 0, stream>>>(
      x_source, x_target, conv_wl, enc_s_w1, enc_s_w2, enc_t_w1, enc_t_w2,
      xsB, xtB, wlB, esw1B, esw2B, etw1B, etw2B);
  wrc_k<<<dim3(64, 6), 256, 0, stream>>>(conv_wr, conv_bl, wrcB, blc);
  headw_k<<<307, 256, 0, stream>>>(gate_w1, mlp_w1, mlp_w2, gate_b1, mlp_b1,
                                   Whead, biasHead, w1eB, w2B);
  int gm = (NSN + 127) / 128;
  enc_k<1><<<dim3(gm, 2), 256, 0, stream>>>(xsB, xtB, esw1B, etw1B,
      enc_s_b1, enc_t_b1, nb[2], nb[3], NSN, 64);
  enc_k<0><<<dim3(gm, 2), 256, 0, stream>>>(nb[2], nb[3], esw2B, etw2B,
      enc_s_b2, enc_t_b2, nb[0], nb[1], NSN, 128);

  // --- CSR build (adjE/colOf overlay dead xsB/xtB) ---
  int* adjE = (int*)xsB;
  int* colOf = (int*)xtB;
  hipMemsetAsync(cnt4, 0, 4 * 50000 * sizeof(int), stream);
  int cb = (EE + 255) / 256;
  count4_k<<<dim3(cb, 4), 256, 0, stream>>>(ei[0], ei[1], ei[2], ei[3], cnt4);
  scanA_k<<<dim3(25, 4), 256, 0, stream>>>(cnt4, cur4, bsum);
  scanB_k<<<1, 64, 0, stream>>>(bsum);
  scanC_k<<<dim3((50000 + 255) / 256, 4), 256, 0, stream>>>(cnt4, cur4, bsum, off4, cur4);
  for (int p = 0; p < NPASS; ++p)
    fillP_k<<<dim3(cb, 4), 256, 0, stream>>>(ei[0], ei[1], ei[2], ei[3], cur4, adj4, adjE, p);
  colof_k<<<(50000 + 255) / 256, 256, 0, stream>>>(off4 + 2 * 50001, colOf, NTN);

  // --- 3 hetero layers: (0,1)->(2,3)->(0,1)->(2,3) ---
  int gb = (NSN + 3) / 4;
  {
    gather4_k<<<dim3(gb, 4), 256, 0, stream>>>(nb[0], nb[1], off4, adj4,
        mB[0], mB[1], mB[2], mB[3], NSN);
    lgemm_k<0><<<dim3(gm, 2), 256, 0, stream>>>(nb[0], nb[1],
        mB[0], mB[1], mB[2], mB[3], wlB, wrcB, blc, nb[2], nb[3], NSN);
    gather4_k<<<dim3(gb, 4), 256, 0, stream>>>(nb[2], nb[3], off4, adj4,
        mB[0], mB[1], mB[2], mB[3], NSN);
    lgemm_k<1><<<dim3(gm, 2), 256, 0, stream>>>(nb[2], nb[3],
        mB[0], mB[1], mB[2], mB[3], wlB + (size_t)4 * 16384,
        wrcB + (size_t)2 * 16384, blc + 256, nb[0], nb[1], NSN);
    gather4_k<<<dim3(gb, 4), 256, 0, stream>>>(nb[0], nb[1], off4, adj4,
        mB[0], mB[1], mB[2], mB[3], NSN);
    lgemm_k<1><<<dim3(gm, 2), 256, 0, stream>>>(nb[0], nb[1],
        mB[0], mB[1], mB[2], mB[3], wlB + (size_t)8 * 16384,
        wrcB + (size_t)4 * 16384, blc + 512, nb[2], nb[3], NSN);
  }
  // h3s = nb2, h3t = nb3

  // --- nodewise head precompute (consumes nb2,nb3) ---
  ushort* pS = shared4;
  ushort* pT = shared4 + 2 * NBE;
  gemmH_k<<<dim3(gm, 2, 2), 256, 0, stream>>>(nbase + 2 * NBE, Whead, biasHead, pS, pT);

  // --- permute ea into CSR order (nbase region dead after gemmH) ---
  ushort* eaB = nbase;   // 32 MB < 4*NBE*2 = 51.2 MB
  eaperm_k<<<((EE * 8) + 255) / 256, 256, 0, stream>>>(edge_attr, adjE, eaB, EE);

  // --- fused edge head (CSR-ordered, sequential eaB) ---
  head_k<<<(EE + 63) / 64, 256, 0, stream>>>(pS, pT,
      adj4 + (size_t)2 * EE, colOf, adjE, eaB, w1eB, w2B,
      gate_w2, gate_b2, mlp_b2, mlp_w3, mlp_b3, out, EE);
}

// Round 9
// 790.016 us; speedup vs baseline: 1.7488x; 1.0394x over previous
//
#include <hip/hip_runtime.h>
#include <cmath>

#define NSN 50000
#define NTN 50000
#define EE  500000
#define NBE ((size_t)NSN * 128)
#define NPASS 2
#define PRNG 25000

using short8 = __attribute__((ext_vector_type(8))) short;
using f32x4  = __attribute__((ext_vector_type(4))) float;
#define MFMA16(a, b, c) __builtin_amdgcn_mfma_f32_16x16x32_bf16(a, b, c, 0, 0, 0)

__device__ __forceinline__ float  b2f(ushort u) { return __uint_as_float(((uint)u) << 16); }
__device__ __forceinline__ ushort f2b(float f) {
  uint x = __float_as_uint(f);
  uint r = x + 0x7FFFu + ((x >> 16) & 1u);
  return (ushort)(r >> 16);
}
__device__ __forceinline__ float blo(uint x) { return __uint_as_float(x << 16); }
__device__ __forceinline__ float bhi(uint x) { return __uint_as_float(x & 0xFFFF0000u); }
__device__ __forceinline__ uint  pk2(float a, float b) { return (uint)f2b(a) | ((uint)f2b(b) << 16); }

// ------------------------------------------------- all input/weight converts
__global__ void cvtall_k(const float* __restrict__ xs, const float* __restrict__ xt,
                         const float* __restrict__ wl,
                         const float* __restrict__ esw1, const float* __restrict__ esw2,
                         const float* __restrict__ etw1, const float* __restrict__ etw2,
                         ushort* __restrict__ xsB, ushort* __restrict__ xtB,
                         ushort* __restrict__ wlB, ushort* __restrict__ esw1B,
                         ushort* __restrict__ esw2B, ushort* __restrict__ etw1B,
                         ushort* __restrict__ etw2B) {
  int i = blockIdx.x * 256 + threadIdx.x;
  if (i < 3200000) { xsB[i] = f2b(xs[i]); return; }
  i -= 3200000;
  if (i < 3200000) {
    int r = i >> 6, k = i & 63;
    xtB[i] = (k < 48) ? f2b(xt[(size_t)r * 48 + k]) : (ushort)0;
    return;
  }
  i -= 3200000;
  if (i < 196608) { wlB[i] = f2b(wl[i]); return; }
  i -= 196608;
  if (i < 8192) { esw1B[i] = f2b(esw1[i]); return; }
  i -= 8192;
  if (i < 16384) { esw2B[i] = f2b(esw2[i]); return; }
  i -= 16384;
  if (i < 8192) {
    int r = i >> 6, k = i & 63;
    etw1B[i] = (k < 48) ? f2b(etw1[(size_t)r * 48 + k]) : (ushort)0;
    return;
  }
  i -= 8192;
  if (i < 16384) { etw2B[i] = f2b(etw2[i]); return; }
}

// ------------------------------------------------- combined wr + bias
__global__ void wrc_k(const float* __restrict__ wr, const float* __restrict__ bl,
                      ushort* __restrict__ wrcB, float* __restrict__ blc) {
  int z = blockIdx.y;
  int l = z >> 1, dd = z & 1;
  int r1 = dd ? 1 : 0, r2 = dd ? 2 : 3;
  int idx = blockIdx.x * 256 + threadIdx.x;
  if (idx < 16384) {
    wrcB[(size_t)z * 16384 + idx] =
        f2b(wr[(size_t)(l * 4 + r1) * 16384 + idx] + wr[(size_t)(l * 4 + r2) * 16384 + idx]);
    if (idx < 128)
      blc[z * 128 + idx] = bl[(l * 4 + r1) * 128 + idx] + bl[(l * 4 + r2) * 128 + idx];
  }
}

// ------------------------------------------------- head weight assembly
__global__ void headw_k(const float* __restrict__ gw1, const float* __restrict__ mw1,
                        const float* __restrict__ mw2, const float* __restrict__ gb1,
                        const float* __restrict__ mb1,
                        ushort* __restrict__ Whead, float* __restrict__ biasHead,
                        ushort* __restrict__ w1eB, ushort* __restrict__ w2B) {
  int idx = blockIdx.x * 256 + threadIdx.x;
  if (idx < 65536) {
    int z = idx >> 15, rr = (idx >> 7) & 255, c = idx & 127;
    float v = (rr < 128) ? gw1[(size_t)rr * 256 + z * 128 + c]
                         : mw1[(size_t)(rr - 128) * 160 + c];
    Whead[idx] = f2b(v);
  } else if (idx < 69632) {
    int i = idx - 65536;
    w1eB[i] = f2b(mw1[(size_t)(i >> 5) * 160 + 128 + (i & 31)]);
  } else if (idx < 77824) {
    int i = idx - 69632;
    w2B[i] = f2b(mw2[i]);
  } else if (idx < 78336) {
    int i = idx - 77824;
    int z = i >> 8, n = i & 255;
    biasHead[i] = (n < 128) ? (z ? 0.f : gb1[n]) : mb1[n - 128];
  }
}

// --------------------------------------------------------------- CSR build
__global__ void count4_k(const int* __restrict__ e0, const int* __restrict__ e1,
                         const int* __restrict__ e2, const int* __restrict__ e3,
                         int* __restrict__ cnt) {
  int rel = blockIdx.y;
  const int* col = (rel == 0 ? e0 : rel == 1 ? e1 : rel == 2 ? e2 : e3) + EE;
  int i = blockIdx.x * 256 + threadIdx.x;
  if (i < EE) atomicAdd(&cnt[rel * 50000 + col[i]], 1);
}

// hierarchical scan
__global__ __launch_bounds__(256) void scanA_k(const int* __restrict__ cnt,
                                               int* __restrict__ loc,
                                               int* __restrict__ bsum) {
  __shared__ int ws[4];
  int rel = blockIdx.y, b = blockIdx.x, t = threadIdx.x;
  const int* c = cnt + (size_t)rel * 50000;
  int base = b * 2048 + t * 8;
  int v[8], s = 0;
  #pragma unroll
  for (int i = 0; i < 8; ++i) {
    int idx = base + i;
    v[i] = (idx < 50000) ? c[idx] : 0;
    s += v[i];
  }
  int lane = t & 63, w = t >> 6;
  int x = s;
  #pragma unroll
  for (int d = 1; d < 64; d <<= 1) {
    int y = __shfl_up(x, d, 64);
    if (lane >= d) x += y;
  }
  if (lane == 63) ws[w] = x;
  __syncthreads();
  int add = 0;
  for (int ww = 0; ww < w; ++ww) add += ws[ww];
  int run = add + x - s;
  #pragma unroll
  for (int i = 0; i < 8; ++i) {
    int idx = base + i;
    run += v[i];
    if (idx < 50000) loc[(size_t)rel * 50000 + idx] = run;
  }
  if (t == 255) bsum[rel * 25 + b] = add + x;
}
__global__ void scanB_k(int* __restrict__ bsum) {
  int t = threadIdx.x;
  if (t < 4) {
    int s = 0;
    for (int b = 0; b < 25; ++b) {
      int v = bsum[t * 25 + b];
      bsum[t * 25 + b] = s;
      s += v;
    }
  }
}
// scanC also expands rel-2 per-position col (folded colof)
__global__ void scanC_k(const int* __restrict__ cnt, const int* __restrict__ loc,
                        const int* __restrict__ bsum, int* __restrict__ off,
                        int* __restrict__ cur, int* __restrict__ colOf) {
  int rel = blockIdx.y;
  int i = blockIdx.x * 256 + threadIdx.x;
  if (i < 50000) {
    int incl = loc[(size_t)rel * 50000 + i] + bsum[rel * 25 + i / 2048];
    int cntv = cnt[(size_t)rel * 50000 + i];
    off[(size_t)rel * 50001 + i + 1] = incl;
    cur[(size_t)rel * 50000 + i] = incl - cntv;
    if (i == 0) off[(size_t)rel * 50001] = 0;
    if (rel == 2) {
      for (int k = incl - cntv; k < incl; ++k) colOf[k] = i;
    }
  }
}

// range-partitioned fill; rel 2 also records original edge id
__global__ void fillP_k(const int* __restrict__ e0, const int* __restrict__ e1,
                        const int* __restrict__ e2, const int* __restrict__ e3,
                        int* __restrict__ cur, int* __restrict__ adj,
                        int* __restrict__ adjE, int pass) {
  int rel = blockIdx.y;
  const int* ei = rel == 0 ? e0 : rel == 1 ? e1 : rel == 2 ? e2 : e3;
  int e = blockIdx.x * 256 + threadIdx.x;
  if (e < EE) {
    int c = ei[EE + e];
    if (c >= pass * PRNG && c < (pass + 1) * PRNG) {
      int pos = atomicAdd(&cur[rel * 50000 + c], 1);
      adj[(size_t)rel * EE + pos] = ei[e];
      if (rel == 2) adjE[pos] = e;
    }
  }
}

// -------------------------------- permute ea into CSR order (+bf16 convert)
__global__ void eaperm_k(const float* __restrict__ ea, const int* __restrict__ adjE,
                         ushort* __restrict__ eaB, int E) {
  int idx = blockIdx.x * 256 + threadIdx.x;
  int pos = idx >> 3, q = idx & 7;
  if (pos < E) {
    int eid = adjE[pos];
    float4 v = *(const float4*)(ea + (size_t)eid * 32 + q * 4);
    ushort4 o;
    o.x = f2b(v.x); o.y = f2b(v.y); o.z = f2b(v.z); o.w = f2b(v.w);
    *(ushort4*)(eaB + (size_t)pos * 32 + q * 4) = o;
  }
}

// ------------------------------------------------------------- gather-mean
__global__ __launch_bounds__(256) void gather4_k(
    const ushort* __restrict__ hs, const ushort* __restrict__ ht,
    const int* __restrict__ off4, const int* __restrict__ adj4,
    ushort* __restrict__ m0, ushort* __restrict__ m1,
    ushort* __restrict__ m2, ushort* __restrict__ m3, int N) {
  int r = blockIdx.y;
  const ushort* src = (r == 0 || r == 2) ? hs : ht;
  ushort* dst = r == 0 ? m0 : (r == 1 ? m1 : (r == 2 ? m2 : m3));
  const int* off = off4 + r * 50001;
  const int* adj = adj4 + (size_t)r * EE;
  int t = threadIdx.x;
  int n = blockIdx.x * 4 + (t >> 6);
  if (n >= N) return;
  int lane = t & 63, g = lane >> 4, i = lane & 15;
  int s = off[n], e = off[n + 1];
  float a[8] = {};
  int k = s + g;
  for (; k + 4 < e; k += 8) {
    int r0 = adj[k], r1 = adj[k + 4];
    uint4 v0 = *(const uint4*)(src + (size_t)r0 * 128 + i * 8);
    uint4 v1 = *(const uint4*)(src + (size_t)r1 * 128 + i * 8);
    a[0] += blo(v0.x) + blo(v1.x); a[1] += bhi(v0.x) + bhi(v1.x);
    a[2] += blo(v0.y) + blo(v1.y); a[3] += bhi(v0.y) + bhi(v1.y);
    a[4] += blo(v0.z) + blo(v1.z); a[5] += bhi(v0.z) + bhi(v1.z);
    a[6] += blo(v0.w) + blo(v1.w); a[7] += bhi(v0.w) + bhi(v1.w);
  }
  if (k < e) {
    int r0 = adj[k];
    uint4 v = *(const uint4*)(src + (size_t)r0 * 128 + i * 8);
    a[0] += blo(v.x); a[1] += bhi(v.x);
    a[2] += blo(v.y); a[3] += bhi(v.y);
    a[4] += blo(v.z); a[5] += bhi(v.z);
    a[6] += blo(v.w); a[7] += bhi(v.w);
  }
  #pragma unroll
  for (int c = 0; c < 8; ++c) {
    a[c] += __shfl_xor(a[c], 16, 64);
    a[c] += __shfl_xor(a[c], 32, 64);
  }
  if (g == 0) {
    float inv = 1.f / (float)max(e - s, 1);
    uint4 o;
    o.x = pk2(a[0] * inv, a[1] * inv);
    o.y = pk2(a[2] * inv, a[3] * inv);
    o.z = pk2(a[4] * inv, a[5] * inv);
    o.w = pk2(a[6] * inv, a[7] * inv);
    *(uint4*)(dst + (size_t)n * 128 + i * 8) = o;
  }
}

// ------------------------------------------------------- shared GEMM body
template <int MODE>
__device__ __forceinline__ void gemm_body(
    ushort (*As)[40], ushort (*Ws)[40],
    const ushort* __restrict__ A, const ushort* __restrict__ W,
    const float* __restrict__ bias, ushort* __restrict__ C,
    int M, int K, int ldc, int m0) {
  int t = threadIdx.x;
  int lane = t & 63, w = t >> 6, wm = w >> 1, wn = w & 1;
  f32x4 zz = {0.f, 0.f, 0.f, 0.f};
  f32x4 acc[4][4];
  #pragma unroll
  for (int i = 0; i < 4; ++i)
    #pragma unroll
    for (int j = 0; j < 4; ++j) acc[i][j] = zz;
  for (int kb = 0; kb < K; kb += 32) {
    #pragma unroll
    for (int s = 0; s < 2; ++s) {
      int idx = t + s * 256;
      int r = idx >> 2, c = idx & 3;
      int gm = m0 + r;
      uint4 va = make_uint4(0, 0, 0, 0);
      if (gm < M) va = *(const uint4*)(A + (size_t)gm * K + kb + c * 8);
      *(uint4*)&As[r][c * 8] = va;
      *(uint4*)&Ws[r][c * 8] = *(const uint4*)(W + (size_t)r * K + kb + c * 8);
    }
    __syncthreads();
    short8 af[4], bf[4];
    #pragma unroll
    for (int mf = 0; mf < 4; ++mf)
      af[mf] = *(const short8*)&As[wm * 64 + mf * 16 + (lane & 15)][(lane >> 4) * 8];
    #pragma unroll
    for (int nf = 0; nf < 4; ++nf)
      bf[nf] = *(const short8*)&Ws[wn * 64 + nf * 16 + (lane & 15)][(lane >> 4) * 8];
    #pragma unroll
    for (int mf = 0; mf < 4; ++mf)
      #pragma unroll
      for (int nf = 0; nf < 4; ++nf) acc[mf][nf] = MFMA16(af[mf], bf[nf], acc[mf][nf]);
    __syncthreads();
  }
  int r0 = (lane >> 4) * 4, nin = lane & 15;
  #pragma unroll
  for (int mf = 0; mf < 4; ++mf)
    #pragma unroll
    for (int nf = 0; nf < 4; ++nf) {
      int n = wn * 64 + nf * 16 + nin;
      float bv = bias ? bias[n] : 0.f;
      #pragma unroll
      for (int i = 0; i < 4; ++i) {
        int gm = m0 + wm * 64 + mf * 16 + r0 + i;
        if (gm >= M) continue;
        float v = acc[mf][nf][i] + bv;
        if (MODE == 1) v = fmaxf(v, 0.f);
        C[(size_t)gm * ldc + n] = f2b(v);
      }
    }
}

// -------------------------------- fused 2-layer encoder (h1 kept in LDS)
__global__ __launch_bounds__(256) void encf_k(
    const ushort* __restrict__ A0, const ushort* __restrict__ A1,
    const ushort* __restrict__ W10, const ushort* __restrict__ W11,
    const ushort* __restrict__ W20, const ushort* __restrict__ W21,
    const float* __restrict__ b10, const float* __restrict__ b11,
    const float* __restrict__ b20, const float* __restrict__ b21,
    ushort* __restrict__ C0, ushort* __restrict__ C1, int M) {
  __shared__ alignas(16) ushort As[128][40];
  __shared__ alignas(16) ushort Ws[128][40];
  __shared__ alignas(16) ushort H1[128][136];
  int y = blockIdx.y;
  const ushort* A  = y ? A1 : A0;
  const ushort* W1 = y ? W11 : W10;
  const ushort* W2 = y ? W21 : W20;
  const float* b1 = y ? b11 : b10;
  const float* b2 = y ? b21 : b20;
  ushort* C = y ? C1 : C0;
  int t = threadIdx.x;
  int m0 = blockIdx.x * 128;
  int lane = t & 63, w = t >> 6, wm = w >> 1, wn = w & 1;
  f32x4 zz = {0.f, 0.f, 0.f, 0.f};
  f32x4 acc[4][4];
  #pragma unroll
  for (int i = 0; i < 4; ++i)
    #pragma unroll
    for (int j = 0; j < 4; ++j) acc[i][j] = zz;
  // stage 1: h1 = relu(x @ W1^T + b1), K=64
  for (int kb = 0; kb < 64; kb += 32) {
    #pragma unroll
    for (int s = 0; s < 2; ++s) {
      int idx = t + s * 256;
      int r = idx >> 2, c = idx & 3;
      int gm = m0 + r;
      uint4 va = make_uint4(0, 0, 0, 0);
      if (gm < M) va = *(const uint4*)(A + (size_t)gm * 64 + kb + c * 8);
      *(uint4*)&As[r][c * 8] = va;
      *(uint4*)&Ws[r][c * 8] = *(const uint4*)(W1 + (size_t)r * 64 + kb + c * 8);
    }
    __syncthreads();
    short8 af[4], bf[4];
    #pragma unroll
    for (int mf = 0; mf < 4; ++mf)
      af[mf] = *(const short8*)&As[wm * 64 + mf * 16 + (lane & 15)][(lane >> 4) * 8];
    #pragma unroll
    for (int nf = 0; nf < 4; ++nf)
      bf[nf] = *(const short8*)&Ws[wn * 64 + nf * 16 + (lane & 15)][(lane >> 4) * 8];
    #pragma unroll
    for (int mf = 0; mf < 4; ++mf)
      #pragma unroll
      for (int nf = 0; nf < 4; ++nf) acc[mf][nf] = MFMA16(af[mf], bf[nf], acc[mf][nf]);
    __syncthreads();
  }
  {
    int r0 = (lane >> 4) * 4, nin = lane & 15;
    #pragma unroll
    for (int mf = 0; mf < 4; ++mf)
      #pragma unroll
      for (int nf = 0; nf < 4; ++nf) {
        int n = wn * 64 + nf * 16 + nin;
        float bv = b1[n];
        #pragma unroll
        for (int i = 0; i < 4; ++i)
          H1[wm * 64 + mf * 16 + r0 + i][n] = f2b(fmaxf(acc[mf][nf][i] + bv, 0.f));
      }
  }
  __syncthreads();
  // stage 2: out = h1 @ W2^T + b2, K=128 (A from LDS H1)
  #pragma unroll
  for (int i = 0; i < 4; ++i)
    #pragma unroll
    for (int j = 0; j < 4; ++j) acc[i][j] = zz;
  for (int kb = 0; kb < 128; kb += 32) {
    #pragma unroll
    for (int s = 0; s < 2; ++s) {
      int idx = t + s * 256;
      int r = idx >> 2, c = idx & 3;
      *(uint4*)&Ws[r][c * 8] = *(const uint4*)(W2 + (size_t)r * 128 + kb + c * 8);
    }
    __syncthreads();
    short8 af[4], bf[4];
    #pragma unroll
    for (int mf = 0; mf < 4; ++mf)
      af[mf] = *(const short8*)&H1[wm * 64 + mf * 16 + (lane & 15)][kb + (lane >> 4) * 8];
    #pragma unroll
    for (int nf = 0; nf < 4; ++nf)
      bf[nf] = *(const short8*)&Ws[wn * 64 + nf * 16 + (lane & 15)][(lane >> 4) * 8];
    #pragma unroll
    for (int mf = 0; mf < 4; ++mf)
      #pragma unroll
      for (int nf = 0; nf < 4; ++nf) acc[mf][nf] = MFMA16(af[mf], bf[nf], acc[mf][nf]);
    __syncthreads();
  }
  {
    int r0 = (lane >> 4) * 4, nin = lane & 15;
    #pragma unroll
    for (int mf = 0; mf < 4; ++mf)
      #pragma unroll
      for (int nf = 0; nf < 4; ++nf) {
        int n = wn * 64 + nf * 16 + nin;
        float bv = b2[n];
        #pragma unroll
        for (int i = 0; i < 4; ++i) {
          int gm = m0 + wm * 64 + mf * 16 + r0 + i;
          if (gm >= M) continue;
          C[(size_t)gm * 128 + n] = f2b(acc[mf][nf][i] + bv);
        }
      }
  }
}

__global__ __launch_bounds__(256) void gemmH_k(
    const ushort* Abase, const ushort* Whead, const float* biasHead,
    ushort* pS, ushort* pT) {
  __shared__ alignas(16) ushort As[128][40];
  __shared__ alignas(16) ushort Ws[128][40];
  int z = blockIdx.z, ny = blockIdx.y;
  gemm_body<0>(As, Ws, Abase + (size_t)z * NBE,
               Whead + ((size_t)z * 256 + ny * 128) * 128,
               biasHead + z * 256 + ny * 128,
               (z ? pT : pS) + ny * 128,
               NSN, 128, 256, blockIdx.x * 128);
}

// ---------------------------------- layer GEMM: 3 A-panels, both dst types
template <int RES>
__global__ __launch_bounds__(256) void lgemm_k(
    const ushort* __restrict__ hs, const ushort* __restrict__ ht,
    const ushort* __restrict__ m0, const ushort* __restrict__ m1,
    const ushort* __restrict__ m2, const ushort* __restrict__ m3,
    const ushort* __restrict__ wlL, const ushort* __restrict__ wrcL,
    const float* __restrict__ blcL,
    ushort* __restrict__ hsOut, ushort* __restrict__ htOut, int M) {
  __shared__ alignas(16) ushort As[128][40];
  __shared__ alignas(16) ushort Ws[128][40];
  int t = threadIdx.x;
  int y = blockIdx.y;
  int m0i = blockIdx.x * 128;
  const ushort* A0 = y ? m1 : m0;
  const ushort* A1 = y ? m2 : m3;
  const ushort* self = y ? ht : hs;
  const ushort* W0 = wlL + (size_t)(y ? 1 : 0) * 16384;
  const ushort* W1 = wlL + (size_t)(y ? 2 : 3) * 16384;
  const ushort* W2 = wrcL + (size_t)y * 16384;
  const float* bias = blcL + y * 128;
  ushort* C = y ? htOut : hsOut;

  int lane = t & 63, w = t >> 6, wm = w >> 1, wn = w & 1;
  f32x4 zz = {0.f, 0.f, 0.f, 0.f};
  f32x4 acc[4][4];
  #pragma unroll
  for (int i = 0; i < 4; ++i)
    #pragma unroll
    for (int j = 0; j < 4; ++j) acc[i][j] = zz;
  for (int p = 0; p < 3; ++p) {
    const ushort* A = p == 0 ? A0 : (p == 1 ? A1 : self);
    const ushort* Wp = p == 0 ? W0 : (p == 1 ? W1 : W2);
    for (int kb = 0; kb < 128; kb += 32) {
      #pragma unroll
      for (int s = 0; s < 2; ++s) {
        int idx = t + s * 256;
        int r = idx >> 2, c = idx & 3;
        int gm = m0i + r;
        uint4 va = make_uint4(0, 0, 0, 0);
        if (gm < M) va = *(const uint4*)(A + (size_t)gm * 128 + kb + c * 8);
        *(uint4*)&As[r][c * 8] = va;
        *(uint4*)&Ws[r][c * 8] = *(const uint4*)(Wp + (size_t)r * 128 + kb + c * 8);
      }
      __syncthreads();
      short8 af[4], bf[4];
      #pragma unroll
      for (int mf = 0; mf < 4; ++mf)
        af[mf] = *(const short8*)&As[wm * 64 + mf * 16 + (lane & 15)][(lane >> 4) * 8];
      #pragma unroll
      for (int nf = 0; nf < 4; ++nf)
        bf[nf] = *(const short8*)&Ws[wn * 64 + nf * 16 + (lane & 15)][(lane >> 4) * 8];
      #pragma unroll
      for (int mf = 0; mf < 4; ++mf)
        #pragma unroll
        for (int nf = 0; nf < 4; ++nf) acc[mf][nf] = MFMA16(af[mf], bf[nf], acc[mf][nf]);
      __syncthreads();
    }
  }
  int r0 = (lane >> 4) * 4, nin = lane & 15;
  #pragma unroll
  for (int mf = 0; mf < 4; ++mf)
    #pragma unroll
    for (int nf = 0; nf < 4; ++nf) {
      int n = wn * 64 + nf * 16 + nin;
      float bv = bias[n];
      #pragma unroll
      for (int i = 0; i < 4; ++i) {
        int gm = m0i + wm * 64 + mf * 16 + r0 + i;
        if (gm >= M) continue;
        float v = 0.5f * (acc[mf][nf][i] + bv);
        if (RES) v += b2f(self[(size_t)gm * 128 + n]);
        C[(size_t)gm * 128 + n] = f2b(fmaxf(v, 0.f));
      }
    }
}

// ---------------------------------------------------------------- edge head
// CSR-ordered edges; ea pre-permuted; Phase-G loads fully prefetched.
__global__ __launch_bounds__(256) void head_k(
    const ushort* __restrict__ pS, const ushort* __restrict__ pT,
    const int* __restrict__ erowA, const int* __restrict__ ecolA,
    const int* __restrict__ eidA, const ushort* __restrict__ eaB,
    const ushort* __restrict__ w1eB, const ushort* __restrict__ w2B,
    const float* __restrict__ gw2, const float* __restrict__ gb2p,
    const float* __restrict__ mb2, const float* __restrict__ mw3,
    const float* __restrict__ mb3, float* __restrict__ out, int E) {
  __shared__ alignas(16) ushort h1s[64][136];    // eat -> h1 -> (aliased) h2F
  __shared__ int er[64], ec[64], eidS[64];
  __shared__ alignas(16) float gw2s[128];
  __shared__ alignas(16) float mw3s[128];
  __shared__ float mb2s[64];
  float (*h2F)[68] = (float(*)[68])&h1s[0][0];

  // bijective XCD swizzle
  int nwg = gridDim.x;
  int bid = blockIdx.x;
  int q = nwg >> 3, r = nwg & 7;
  int xcd = bid & 7, sub = bid >> 3;
  int swz = (xcd < r ? xcd * (q + 1) : r * (q + 1) + (xcd - r) * q) + sub;
  int e0 = swz * 64;

  int t = threadIdx.x;
  if (t < 64) {
    int p = e0 + t;
    er[t] = (p < E) ? erowA[p] : 0;
    eidS[t] = (p < E) ? eidA[p] : -1;
    mb2s[t] = mb2[t];
  } else if (t < 128) {
    int p = e0 + (t - 64);
    ec[t - 64] = (p < E) ? ecolA[p] : 0;
  }
  if (t < 128) gw2s[t] = gw2[t];
  else mw3s[t - 128] = mw3[t - 128];
  __syncthreads();
  int lane = t & 63, w = t >> 6;
  // Phase E: eat = ea @ w1e^T (M=64, N=128, K=32) -> h1s
  {
    int p = e0 + w * 16 + (lane & 15);
    short8 a = {};
    if (p < E) a = *(const short8*)(eaB + (size_t)p * 32 + (lane >> 4) * 8);
    int ebase = w * 16 + (lane >> 4) * 4;
    #pragma unroll
    for (int nf = 0; nf < 8; ++nf) {
      short8 b = *(const short8*)(w1eB + (size_t)(nf * 16 + (lane & 15)) * 32 + (lane >> 4) * 8);
      f32x4 cz = {0.f, 0.f, 0.f, 0.f};
      cz = MFMA16(a, b, cz);
      int jj = nf * 16 + (lane & 15);
      #pragma unroll
      for (int i = 0; i < 4; ++i) h1s[ebase + i][jj] = f2b(cz[i]);
    }
  }
  __syncthreads();
  // Phase G: prefetch ALL node loads, then gate + combine + eat RMW + relu
  {
    int el = lane >> 2, qq = lane & 3, e = w * 16 + el;
    int j0 = qq * 32;
    const ushort* ps = pS + (size_t)er[e] * 256;
    const ushort* pt = pT + (size_t)ec[e] * 256;
    uint4 ga[4], gb[4], uu[4], vv[4];
    #pragma unroll
    for (int cc = 0; cc < 4; ++cc) {
      int j = j0 + cc * 8;
      ga[cc] = *(const uint4*)(ps + j);
      gb[cc] = *(const uint4*)(pt + j);
      uu[cc] = *(const uint4*)(ps + 128 + j);
      vv[cc] = *(const uint4*)(pt + 128 + j);
    }
    float dot = 0.f;
    #pragma unroll
    for (int cc = 0; cc < 4; ++cc) {
      const float* gp = &gw2s[j0 + cc * 8];
      float h;
      h = fmaxf(blo(ga[cc].x) + blo(gb[cc].x), 0.f); dot = fmaf(h, gp[0], dot);
      h = fmaxf(bhi(ga[cc].x) + bhi(gb[cc].x), 0.f); dot = fmaf(h, gp[1], dot);
      h = fmaxf(blo(ga[cc].y) + blo(gb[cc].y), 0.f); dot = fmaf(h, gp[2], dot);
      h = fmaxf(bhi(ga[cc].y) + bhi(gb[cc].y), 0.f); dot = fmaf(h, gp[3], dot);
      h = fmaxf(blo(ga[cc].z) + blo(gb[cc].z), 0.f); dot = fmaf(h, gp[4], dot);
      h = fmaxf(bhi(ga[cc].z) + bhi(gb[cc].z), 0.f); dot = fmaf(h, gp[5], dot);
      h = fmaxf(blo(ga[cc].w) + blo(gb[cc].w), 0.f); dot = fmaf(h, gp[6], dot);
      h = fmaxf(bhi(ga[cc].w) + bhi(gb[cc].w), 0.f); dot = fmaf(h, gp[7], dot);
    }
    dot += __shfl_xor(dot, 1, 64);
    dot += __shfl_xor(dot, 2, 64);
    float g = 1.f / (1.f + __expf(-(dot + gb2p[0])));
    float om = 1.f - g;
    #pragma unroll
    for (int cc = 0; cc < 4; ++cc) {
      int j = j0 + cc * 8;
      uint4 ee = *(const uint4*)&h1s[e][j];
      uint o0 = pk2(fmaxf(fmaf(g, blo(uu[cc].x), om * blo(vv[cc].x)) + blo(ee.x), 0.f),
                    fmaxf(fmaf(g, bhi(uu[cc].x), om * bhi(vv[cc].x)) + bhi(ee.x), 0.f));
      uint o1 = pk2(fmaxf(fmaf(g, blo(uu[cc].y), om * blo(vv[cc].y)) + blo(ee.y), 0.f),
                    fmaxf(fmaf(g, bhi(uu[cc].y), om * bhi(vv[cc].y)) + bhi(ee.y), 0.f));
      uint o2 = pk2(fmaxf(fmaf(g, blo(uu[cc].z), om * blo(vv[cc].z)) + blo(ee.z), 0.f),
                    fmaxf(fmaf(g, bhi(uu[cc].z), om * bhi(vv[cc].z)) + bhi(ee.z), 0.f));
      uint o3 = pk2(fmaxf(fmaf(g, blo(uu[cc].w), om * blo(vv[cc].w)) + blo(ee.w), 0.f),
                    fmaxf(fmaf(g, bhi(uu[cc].w), om * bhi(vv[cc].w)) + bhi(ee.w), 0.f));
      *(uint4*)&h1s[e][j] = make_uint4(o0, o1, o2, o3);
    }
  }
  __syncthreads();
  // Phase H: h2 = relu(h1 @ w2^T + b2)
  {
    f32x4 zz = {0.f, 0.f, 0.f, 0.f};
    f32x4 acc[4] = {zz, zz, zz, zz};
    #pragma unroll
    for (int ks = 0; ks < 4; ++ks) {
      short8 a = *(const short8*)&h1s[w * 16 + (lane & 15)][ks * 32 + (lane >> 4) * 8];
      #pragma unroll
      for (int nf = 0; nf < 4; ++nf) {
        short8 b = *(const short8*)(w2B + (size_t)(nf * 16 + (lane & 15)) * 128 + ks * 32 + (lane >> 4) * 8);
        acc[nf] = MFMA16(a, b, acc[nf]);
      }
    }
    __syncthreads();
    int ebase = w * 16 + (lane >> 4) * 4;
    #pragma unroll
    for (int nf = 0; nf < 4; ++nf) {
      int n = nf * 16 + (lane & 15);
      #pragma unroll
      for (int i = 0; i < 4; ++i)
        h2F[ebase + i][n] = fmaxf(acc[nf][i] + mb2s[n], 0.f);
    }
  }
  __syncthreads();
  // Phase O: out scattered by original edge id
  if (t < 128) {
    int e = t >> 1, o = t & 1;
    int eid = eidS[e];
    if (eid >= 0) {
      float s = mb3[o];
      #pragma unroll
      for (int kk = 0; kk < 64; kk += 4) {
        float4 hv = *(const float4*)&h2F[e][kk];
        float4 wv = *(const float4*)&mw3s[o * 64 + kk];
        s = fmaf(hv.x, wv.x, s); s = fmaf(hv.y, wv.y, s);
        s = fmaf(hv.z, wv.z, s); s = fmaf(hv.w, wv.w, s);
      }
      out[(size_t)eid * 2 + o] = s;
    }
  }
}

// ------------------------------------------------------------------- launch
extern "C" void kernel_launch(void* const* d_in, const int* in_sizes, int n_in,
                              void* d_out, int out_size, void* d_ws, size_t ws_size,
                              hipStream_t stream) {
  const float* x_source = (const float*)d_in[0];
  const float* x_target = (const float*)d_in[1];
  const float* edge_attr = (const float*)d_in[2];
  const float* enc_s_w1 = (const float*)d_in[3];
  const float* enc_s_b1 = (const float*)d_in[4];
  const float* enc_s_w2 = (const float*)d_in[5];
  const float* enc_s_b2 = (const float*)d_in[6];
  const float* enc_t_w1 = (const float*)d_in[7];
  const float* enc_t_b1 = (const float*)d_in[8];
  const float* enc_t_w2 = (const float*)d_in[9];
  const float* enc_t_b2 = (const float*)d_in[10];
  const float* conv_wl = (const float*)d_in[11];
  const float* conv_bl = (const float*)d_in[12];
  const float* conv_wr = (const float*)d_in[13];
  const float* gate_w1 = (const float*)d_in[14];
  const float* gate_b1 = (const float*)d_in[15];
  const float* gate_w2 = (const float*)d_in[16];
  const float* gate_b2 = (const float*)d_in[17];
  const float* mlp_w1 = (const float*)d_in[18];
  const float* mlp_b1 = (const float*)d_in[19];
  const float* mlp_w2 = (const float*)d_in[20];
  const float* mlp_b2 = (const float*)d_in[21];
  const float* mlp_w3 = (const float*)d_in[22];
  const float* mlp_b3 = (const float*)d_in[23];
  const int* ei[4] = {(const int*)d_in[24], (const int*)d_in[25],
                      (const int*)d_in[26], (const int*)d_in[27]};  // 0=ss,1=tt,2=st,3=ts
  float* out = (float*)d_out;

  char* wsp = (char*)d_ws;
  size_t off = 0;
  auto alloc = [&](size_t bytes) {
    char* p = wsp + off;
    off += (bytes + 255) & ~(size_t)255;
    return p;
  };
  ushort* nbase = (ushort*)alloc(4 * NBE * 2);
  ushort* nb[4];
  for (int i = 0; i < 4; ++i) nb[i] = nbase + (size_t)i * NBE;
  ushort* shared4 = (ushort*)alloc(4 * NBE * 2);
  ushort* mB[4];
  for (int i = 0; i < 4; ++i) mB[i] = shared4 + (size_t)i * NBE;
  int* adj4 = (int*)alloc((size_t)4 * EE * 4);
  int* off4 = (int*)alloc(4 * 50001 * 4);
  int* cur4 = (int*)alloc(4 * 50000 * 4);
  int* cnt4 = (int*)alloc(4 * 50000 * 4);
  int* bsum = (int*)alloc(128 * 4);
  ushort* xsB = (ushort*)alloc((size_t)NSN * 64 * 2);   // dead after encf -> adjE
  ushort* xtB = (ushort*)alloc((size_t)NTN * 64 * 2);   // dead after encf -> colOf
  ushort* esw1B = (ushort*)alloc(128 * 64 * 2);
  ushort* esw2B = (ushort*)alloc(128 * 128 * 2);
  ushort* etw1B = (ushort*)alloc(128 * 64 * 2);
  ushort* etw2B = (ushort*)alloc(128 * 128 * 2);
  ushort* wlB = (ushort*)alloc((size_t)12 * 16384 * 2);
  ushort* wrcB = (ushort*)alloc((size_t)6 * 16384 * 2);
  float* blc = (float*)alloc(6 * 128 * 4);
  ushort* Whead = (ushort*)alloc((size_t)2 * 256 * 128 * 2);
  float* biasHead = (float*)alloc(2 * 256 * 4);
  ushort* w1eB = (ushort*)alloc(128 * 32 * 2);
  ushort* w2B = (ushort*)alloc(64 * 128 * 2);

  // --- conversions / weight assembly / fused encoders (frees xsB/xtB) ---
  cvtall_k<<<(6645760 + 255) / 256, 256, 0, stream>>>(
      x_source, x_target, conv_wl, enc_s_w1, enc_s_w2, enc_t_w1, enc_t_w2,
      xsB, xtB, wlB, esw1B, esw2B, etw1B, etw2B);
  wrc_k<<<dim3(64, 6), 256, 0, stream>>>(conv_wr, conv_bl, wrcB, blc);
  headw_k<<<307, 256, 0, stream>>>(gate_w1, mlp_w1, mlp_w2, gate_b1, mlp_b1,
                                   Whead, biasHead, w1eB, w2B);
  int gm = (NSN + 127) / 128;
  encf_k<<<dim3(gm, 2), 256, 0, stream>>>(xsB, xtB, esw1B, etw1B, esw2B, etw2B,
      enc_s_b1, enc_t_b1, enc_s_b2, enc_t_b2, nb[0], nb[1], NSN);

  // --- CSR build (adjE/colOf overlay dead xsB/xtB) ---
  int* adjE = (int*)xsB;
  int* colOf = (int*)xtB;
  hipMemsetAsync(cnt4, 0, 4 * 50000 * sizeof(int), stream);
  int cb = (EE + 255) / 256;
  count4_k<<<dim3(cb, 4), 256, 0, stream>>>(ei[0], ei[1], ei[2], ei[3], cnt4);
  scanA_k<<<dim3(25, 4), 256, 0, stream>>>(cnt4, cur4, bsum);
  scanB_k<<<1, 64, 0, stream>>>(bsum);
  scanC_k<<<dim3((50000 + 255) / 256, 4), 256, 0, stream>>>(cnt4, cur4, bsum, off4,
                                                            cur4, colOf);
  for (int p = 0; p < NPASS; ++p)
    fillP_k<<<dim3(cb, 4), 256, 0, stream>>>(ei[0], ei[1], ei[2], ei[3], cur4, adj4, adjE, p);

  // --- 3 hetero layers: (0,1)->(2,3)->(0,1)->(2,3) ---
  int gb = (NSN + 3) / 4;
  {
    gather4_k<<<dim3(gb, 4), 256, 0, stream>>>(nb[0], nb[1], off4, adj4,
        mB[0], mB[1], mB[2], mB[3], NSN);
    lgemm_k<0><<<dim3(gm, 2), 256, 0, stream>>>(nb[0], nb[1],
        mB[0], mB[1], mB[2], mB[3], wlB, wrcB, blc, nb[2], nb[3], NSN);
    gather4_k<<<dim3(gb, 4), 256, 0, stream>>>(nb[2], nb[3], off4, adj4,
        mB[0], mB[1], mB[2], mB[3], NSN);
    lgemm_k<1><<<dim3(gm, 2), 256, 0, stream>>>(nb[2], nb[3],
        mB[0], mB[1], mB[2], mB[3], wlB + (size_t)4 * 16384,
        wrcB + (size_t)2 * 16384, blc + 256, nb[0], nb[1], NSN);
    gather4_k<<<dim3(gb, 4), 256, 0, stream>>>(nb[0], nb[1], off4, adj4,
        mB[0], mB[1], mB[2], mB[3], NSN);
    lgemm_k<1><<<dim3(gm, 2), 256, 0, stream>>>(nb[0], nb[1],
        mB[0], mB[1], mB[2], mB[3], wlB + (size_t)8 * 16384,
        wrcB + (size_t)4 * 16384, blc + 512, nb[2], nb[3], NSN);
  }
  // h3s = nb2, h3t = nb3

  // --- nodewise head precompute (consumes nb2,nb3) ---
  ushort* pS = shared4;
  ushort* pT = shared4 + 2 * NBE;
  gemmH_k<<<dim3(gm, 2, 2), 256, 0, stream>>>(nbase + 2 * NBE, Whead, biasHead, pS, pT);

  // --- permute ea into CSR order (nbase region dead after gemmH) ---
  ushort* eaB = nbase;
  eaperm_k<<<((EE * 8) + 255) / 256, 256, 0, stream>>>(edge_attr, adjE, eaB, EE);

  // --- fused edge head (CSR-ordered, sequential eaB) ---
  head_k<<<(EE + 63) / 64, 256, 0, stream>>>(pS, pT,
      adj4 + (size_t)2 * EE, colOf, adjE, eaB, w1eB, w2B,
      gate_w2, gate_b2, mlp_b2, mlp_w3, mlp_b3, out, EE);
}